// Round 3
// baseline (7677.477 us; speedup 1.0000x reference)
//
#include <hip/hip_runtime.h>

#define T_STEPS 1024
#define BATCH   64
#define NDIM    256
#define HID     256
#define G4      1024   // 4*H

typedef short bf16x8 __attribute__((ext_vector_type(8)));
typedef float f32x4  __attribute__((ext_vector_type(4)));
typedef unsigned short u16;

#define XW_ELEMS ((size_t)2 * T_STEPS * BATCH * G4)   // 134217728 u16 (256 MiB)
#define UT_ELEMS ((size_t)2 * 4 * 65536)              // 524288 u16 (1 MiB)

__device__ __forceinline__ float b2f(u16 v) {
  union { unsigned u; float f; } c; c.u = ((unsigned)v) << 16; return c.f;
}
__device__ __forceinline__ u16 f2b(float f) {
  union { float f; unsigned u; } c; c.f = f;
  unsigned u = c.u;
  u += 0x7fffu + ((u >> 16) & 1u);   // round-to-nearest-even
  return (u16)(u >> 16);
}
__device__ __forceinline__ float sigm(float x) {
  float e = __expf(-x);
  return __builtin_amdgcn_rcpf(1.0f + e);
}
__device__ __forceinline__ float tanh_f(float x) {
  return 2.0f * sigm(2.0f * x) - 1.0f;
}

// ---------------------------------------------------------------------------
// build_ut: pre-transpose U (f32) into bf16 MFMA B-fragment order.
// UT elem idx: ((d*4+g)*65536) + ((w*8+kf)*64 + lane)*8 + j
// ---------------------------------------------------------------------------
__global__ __launch_bounds__(1024) void build_ut(
    const float* __restrict__ U0, const float* __restrict__ U1,
    u16* __restrict__ UT)
{
  const int d = blockIdx.x >> 2;
  const int g = blockIdx.x & 3;
  const float* __restrict__ U = d ? U1 : U0;
  const int w = threadIdx.x >> 6, lane = threadIdx.x & 63;
  const int q = lane >> 4, c15 = lane & 15;
  u16* dst = UT + ((size_t)d * 4 + g) * 65536;
  #pragma unroll
  for (int kf = 0; kf < 8; ++kf) {
    bf16x8 v;
    #pragma unroll
    for (int j = 0; j < 8; ++j)
      v[j] = (short)f2b(U[(size_t)(kf * 32 + q * 8 + j) * G4 + g * 256 + w * 16 + c15]);
    ((bf16x8*)dst)[((w * 8 + kf) << 6) + lane] = v;
  }
}

// ---------------------------------------------------------------------------
// Phase 1: xw = x @ W_d + b_d, bf16, scan-consumption order:
//   elem idx = (((d*T + t)*4 + bt)*1024 + tid)*16 + gate*4 + r
// 64-col N-tiles (uf = 128 VGPRs), t-chunk 32 -> grid 1024 blocks, 2 blk/CU.
// ---------------------------------------------------------------------------
__global__ __launch_bounds__(256, 2) void xw_gemm(
    const float* __restrict__ x,
    const float* __restrict__ W0, const float* __restrict__ W1,
    const float* __restrict__ b0, const float* __restrict__ b1,
    u16* __restrict__ xw)
{
  const int d  = blockIdx.y >> 4;
  const int n0 = (blockIdx.y & 15) * 64;
  const int t0 = blockIdx.x * 32;
  const float* __restrict__ W    = d ? W1 : W0;
  const float* __restrict__ bias = d ? b1 : b0;
  const int lane = threadIdx.x & 63;
  const int wv   = threadIdx.x >> 6;
  const int q    = lane >> 4;
  const int c15  = lane & 15;

  bf16x8 uf[4][8];
  #pragma unroll
  for (int ct = 0; ct < 4; ++ct) {
    const int col = n0 + ct * 16 + c15;
    #pragma unroll
    for (int kf = 0; kf < 8; ++kf) {
      #pragma unroll
      for (int j = 0; j < 8; ++j)
        uf[ct][kf][j] = (short)f2b(W[(size_t)(kf * 32 + q * 8 + j) * G4 + col]);
    }
  }
  float bc[4];
  #pragma unroll
  for (int ct = 0; ct < 4; ++ct) bc[ct] = bias[n0 + ct * 16 + c15];

  __shared__ __align__(16) u16 Alds[64 * 256];

  for (int t = t0; t < t0 + 32; ++t) {
    __syncthreads();
    const float* xt = x + (size_t)t * BATCH * NDIM;
    #pragma unroll
    for (int i = 0; i < 8; ++i) {
      int g = (int)threadIdx.x + 256 * i;
      int r = g >> 5, c = g & 31;
      const float* src = xt + r * 256 + c * 8;
      bf16x8 v;
      #pragma unroll
      for (int j = 0; j < 8; ++j) v[j] = (short)f2b(src[j]);
      int cs = (c & 16) | ((c ^ (r & 15)) & 15);
      ((bf16x8*)Alds)[r * 32 + cs] = v;
    }
    __syncthreads();

    bf16x8 af[8];
    const int arow = wv * 16 + c15;
    #pragma unroll
    for (int kf = 0; kf < 8; ++kf) {
      int c = kf * 4 + q;
      int cs = (c & 16) | ((c ^ c15) & 15);
      af[kf] = ((const bf16x8*)Alds)[arow * 32 + cs];
    }

    f32x4 acc[4];
    #pragma unroll
    for (int ct = 0; ct < 4; ++ct) acc[ct] = (f32x4){0.f, 0.f, 0.f, 0.f};
    #pragma unroll
    for (int kf = 0; kf < 8; ++kf) {
      #pragma unroll
      for (int ct = 0; ct < 4; ++ct)
        acc[ct] = __builtin_amdgcn_mfma_f32_16x16x32_bf16(af[kf], uf[ct][kf], acc[ct], 0, 0, 0);
    }

    u16* dst = xw + (((size_t)d * T_STEPS + t) * 4 + wv) * 16384;
    #pragma unroll
    for (int ct = 0; ct < 4; ++ct) {
      int ncol = n0 + ct * 16;
      int g2 = ncol >> 8, w2 = (ncol >> 4) & 15;
      union { u16 s[4]; uint2 v; } pk;
      #pragma unroll
      for (int r = 0; r < 4; ++r) pk.s[r] = f2b(acc[ct][r] + bc[ct]);
      *(uint2*)(dst + (size_t)(w2 * 64 + q * 16 + c15) * 16 + g2 * 4) = pk.v;
    }
  }
}

// ---------------------------------------------------------------------------
// Phase 2 (fast): grid 8 = (d, bt). 16 waves; wave w owns h-cols [w*16,+16).
// U by gate: f,g in 64 VGPRs; i in 128 KB LDS; o streamed from L2 (rolling
// buffer crossing the step boundary). acc seeded with xw pre-activations
// (prefetched one step ahead). Walking pointers for out/xw.
// Dynamic LDS 147456 B: [0,16384) h ping-pong (8 KB each), [16384,..) U_i.
//
// S1 (this round's single change): the per-step __syncthreads is replaced by
//   s_waitcnt lgkmcnt(0)  +  raw s_barrier.
// Cross-wave correctness needs only the LDS h-writes drained (lgkmcnt); the
// out-stores / xw prefetch / o-refills are thread-private, so the compiler's
// vmcnt(0) drain that __syncthreads implies is pure overhead. Memory-clobber
// asm on both sides pins memory ops to their side of the barrier (m201
// pattern; rule #18 analog).
// ---------------------------------------------------------------------------
__global__ __launch_bounds__(1024) void lstm_scan_fast(
    const u16* __restrict__ xw, const u16* __restrict__ UT,
    float* __restrict__ out)
{
  extern __shared__ __align__(16) u16 dynlds[];
  const int d  = blockIdx.x >> 2;
  const int bt = blockIdx.x & 3;
  const int tid  = threadIdx.x;
  const int w    = tid >> 6;
  const int lane = tid & 63;
  const int q    = lane >> 4;
  const int c15  = lane & 15;

  const u16* __restrict__ UTd = UT + (size_t)d * 4 * 65536;

  // persistent register fragments for gates f(0), g(1)
  bf16x8 uf0[8], uf1[8];
  const bf16x8* UTf = (const bf16x8*)UTd;
  #pragma unroll
  for (int kf = 0; kf < 8; ++kf) {
    uf0[kf] = UTf[       ((w * 8 + kf) << 6) + lane];
    uf1[kf] = UTf[8192 + ((w * 8 + kf) << 6) + lane];
  }

  // stage i-gate into LDS + zero both h buffers
  {
    const int4* src = (const int4*)(UTd + 2 * 65536);
    int4* dstl = (int4*)(dynlds + 8192);
    for (int i = tid; i < 8192; i += 1024) dstl[i] = src[i];
    for (int i = tid; i < 8192; i += 1024) dynlds[i] = 0;
  }

  const int4* __restrict__ Uo4 = (const int4*)(UTd + 3 * 65536);
  const int obase = (w << 9) | lane;
  const char* uib_base = (const char*)(dynlds + 8192) + (size_t)obase * 16;  // +kf*1024 imm

  // precomputed LDS byte offsets; h buffer selected by XOR 8192
  int afo[8];
  #pragma unroll
  for (int kf = 0; kf < 8; ++kf) {
    int cc = kf * 4 + q;
    int cs = (cc & 16) | ((cc ^ c15) & 15);
    afo[kf] = (c15 * 32 + cs) * 16;
  }
  const int colv = w * 16 + c15;
  int hwo[4];
  #pragma unroll
  for (int r = 0; r < 4; ++r) {
    int row = q * 4 + r;
    int cch = colv >> 3;
    int cs = (cch & 16) | ((cch ^ row) & 15);
    hwo[r] = ((row * 32 + cs) * 8 + (colv & 7)) * 2;
  }

  float cst[4] = {0.f, 0.f, 0.f, 0.f};
  __syncthreads();   // one full barrier after init (cheap, once)

  const int rowbase = bt * 16;
  const size_t hlast_base = (size_t)T_STEPS * BATCH * (2 * HID) + (size_t)d * BATCH * HID;
  const int t_first = d ? (T_STEPS - 1) : 0;

  // xw walking pointer; prefetch step 0
  const long xw_stride = d ? -(long)(4 * 16384) : (long)(4 * 16384);
  const u16* xwp = xw + (((size_t)d * T_STEPS + t_first) * 4 + bt) * 16384 + (size_t)tid * 16;
  union I4x2 { int4 v[2]; u16 s[16]; };
  I4x2 xn;
  xn.v[0] = ((const int4*)xwp)[0];
  xn.v[1] = ((const int4*)xwp)[1];
  xwp += xw_stride;

  // o-gate rolling L2 stream (persistent across the step boundary)
  int4 ofr[3];
  ofr[0] = Uo4[obase];
  ofr[1] = Uo4[obase + 64];

  // out walking pointer
  float* outp = out + (size_t)(t_first * BATCH + rowbase + q * 4) * (2 * HID)
              + (size_t)d * HID + colv;
  const long out_stride = d ? -(long)(BATCH * 2 * HID) : (long)(BATCH * 2 * HID);

  int curoff = 0;
  for (int it = 0; it < T_STEPS; ++it) {
    // seed accumulators with current step's pre-activations
    f32x4 acc0 = { b2f(xn.s[0]),  b2f(xn.s[1]),  b2f(xn.s[2]),  b2f(xn.s[3])  };
    f32x4 acc1 = { b2f(xn.s[4]),  b2f(xn.s[5]),  b2f(xn.s[6]),  b2f(xn.s[7])  };
    f32x4 acc2 = { b2f(xn.s[8]),  b2f(xn.s[9]),  b2f(xn.s[10]), b2f(xn.s[11]) };
    f32x4 acc3 = { b2f(xn.s[12]), b2f(xn.s[13]), b2f(xn.s[14]), b2f(xn.s[15]) };

    // prefetch next step's xw (hidden under this step's MFMA+gates; with the
    // vmcnt drain gone it can also ride across the barrier)
    if (it + 1 < T_STEPS) {
      xn.v[0] = ((const int4*)xwp)[0];
      xn.v[1] = ((const int4*)xwp)[1];
      xwp += xw_stride;
    }

    const char* hcb = (const char*)dynlds + curoff;
    bf16x8 afb[2], uib[2];
    afb[0] = *(const bf16x8*)(hcb + afo[0]);
    uib[0] = *(const bf16x8*)(uib_base);
    #pragma unroll
    for (int kf = 0; kf < 8; ++kf) {
      if (kf < 7) {
        afb[(kf + 1) & 1] = *(const bf16x8*)(hcb + afo[kf + 1]);
        uib[(kf + 1) & 1] = *(const bf16x8*)(uib_base + (kf + 1) * 1024);
      }
      if (kf < 6) ofr[(kf + 2) % 3] = Uo4[obase + ((kf + 2) << 6)];
      bf16x8 af = afb[kf & 1];
      union { int4 v; bf16x8 b; } oc; oc.v = ofr[kf % 3];
      acc0 = __builtin_amdgcn_mfma_f32_16x16x32_bf16(af, uf0[kf],     acc0, 0, 0, 0);
      acc1 = __builtin_amdgcn_mfma_f32_16x16x32_bf16(af, uf1[kf],     acc1, 0, 0, 0);
      acc2 = __builtin_amdgcn_mfma_f32_16x16x32_bf16(af, uib[kf & 1], acc2, 0, 0, 0);
      acc3 = __builtin_amdgcn_mfma_f32_16x16x32_bf16(af, oc.b,        acc3, 0, 0, 0);
    }
    // refill o-stream head for NEXT step now; latency hides under the gates
    ofr[0] = Uo4[obase];
    ofr[1] = Uo4[obase + 64];

    u16 hb[4]; float hv[4];
    #pragma unroll
    for (int r = 0; r < 4; ++r) {
      float fg = sigm(acc0[r]);
      float gg = tanh_f(acc1[r]);
      float ig = sigm(acc2[r]);
      float og = sigm(acc3[r]);
      float cn = cst[r] * fg + gg * ig;
      cst[r] = cn;
      hv[r] = og * tanh_f(cn);
      hb[r] = f2b(hv[r]);
    }

    const int nxtoff = curoff ^ 8192;
    char* hwp = (char*)dynlds + nxtoff;
    #pragma unroll
    for (int r = 0; r < 4; ++r) {
      *(u16*)(hwp + hwo[r]) = hb[r];
      outp[r * (2 * HID)] = hv[r];          // imm offsets 0/2048/4096/6144 B
    }
    outp += out_stride;
    if (it == T_STEPS - 1) {
      #pragma unroll
      for (int r = 0; r < 4; ++r)
        out[hlast_base + (size_t)(rowbase + q * 4 + r) * HID + colv] = hv[r];
    }
    curoff = nxtoff;

    // S1: LDS-only drain + raw barrier (no vmcnt(0) drain).
    asm volatile("s_waitcnt lgkmcnt(0)" ::: "memory");
    __builtin_amdgcn_s_barrier();
    asm volatile("" ::: "memory");   // pin post-barrier LDS reads below the barrier
  }
}

// ---------------------------------------------------------------------------
// Phase 2 (safe fallback if ws too small for UT): correct but slow.
// ---------------------------------------------------------------------------
__global__ __launch_bounds__(1024) void lstm_scan_safe(
    const u16* __restrict__ xw,
    const float* __restrict__ U0, const float* __restrict__ U1,
    float* __restrict__ out)
{
  const int d  = blockIdx.x >> 2;
  const int bt = blockIdx.x & 3;
  const int tid  = threadIdx.x;
  const int w    = tid >> 6;
  const int lane = tid & 63;
  const int q    = lane >> 4;
  const int c15  = lane & 15;
  const float* __restrict__ U = d ? U1 : U0;

  bf16x8 uf[4][8];
  #pragma unroll
  for (int g = 0; g < 4; ++g) {
    const int col2 = g * 256 + w * 16 + c15;
    #pragma unroll
    for (int kf = 0; kf < 8; ++kf) {
      #pragma unroll
      for (int j = 0; j < 8; ++j)
        uf[g][kf][j] = (short)f2b(U[(size_t)(kf * 32 + q * 8 + j) * G4 + col2]);
    }
  }

  __shared__ __align__(16) u16 hbuf[2][16 * 256];
  for (int i = tid; i < 16 * 256; i += 1024) { hbuf[0][i] = 0; hbuf[1][i] = 0; }
  float cst[4] = {0.f, 0.f, 0.f, 0.f};
  __syncthreads();

  const int rowbase = bt * 16;
  const int col = w * 16 + c15;
  const size_t hlast_base = (size_t)T_STEPS * BATCH * (2 * HID) + (size_t)d * BATCH * HID;

  for (int it = 0; it < T_STEPS; ++it) {
    const int t = d ? (T_STEPS - 1 - it) : it;
    union { int4 v[2]; u16 s[16]; } xv;
    {
      const int4* xwt = (const int4*)(xw + ((((size_t)d * T_STEPS + t) * 4 + bt) * 1024 + tid) * 16);
      xv.v[0] = xwt[0]; xv.v[1] = xwt[1];
    }
    const int cur = it & 1;
    bf16x8 af[8];
    #pragma unroll
    for (int kf = 0; kf < 8; ++kf) {
      int cc = kf * 4 + q;
      int cs = (cc & 16) | ((cc ^ c15) & 15);
      af[kf] = ((const bf16x8*)hbuf[cur])[c15 * 32 + cs];
    }
    f32x4 acc[4];
    #pragma unroll
    for (int g = 0; g < 4; ++g) acc[g] = (f32x4){0.f, 0.f, 0.f, 0.f};
    #pragma unroll
    for (int kf = 0; kf < 8; ++kf)
      #pragma unroll
      for (int g = 0; g < 4; ++g)
        acc[g] = __builtin_amdgcn_mfma_f32_16x16x32_bf16(af[kf], uf[g][kf], acc[g], 0, 0, 0);

    u16 hb[4]; float hv[4];
    #pragma unroll
    for (int r = 0; r < 4; ++r) {
      float zf = acc[0][r] + b2f(xv.s[0 * 4 + r]);
      float zg = acc[1][r] + b2f(xv.s[1 * 4 + r]);
      float zi = acc[2][r] + b2f(xv.s[2 * 4 + r]);
      float zo = acc[3][r] + b2f(xv.s[3 * 4 + r]);
      float fg = sigm(zf), gg = tanh_f(zg), ig = sigm(zi), og = sigm(zo);
      float cn = cst[r] * fg + gg * ig;
      cst[r] = cn;
      hv[r] = og * tanh_f(cn);
      hb[r] = f2b(hv[r]);
    }
    const int nxt = cur ^ 1;
    #pragma unroll
    for (int r = 0; r < 4; ++r) {
      const int row = q * 4 + r;
      int cch = col >> 3;
      int cs = (cch & 16) | ((cch ^ row) & 15);
      hbuf[nxt][(row * 32 + cs) * 8 + (col & 7)] = hb[r];
      out[((size_t)t * BATCH + rowbase + row) * (2 * HID) + (size_t)d * HID + col] = hv[r];
    }
    if (it == T_STEPS - 1) {
      #pragma unroll
      for (int r = 0; r < 4; ++r)
        out[hlast_base + (size_t)(rowbase + q * 4 + r) * HID + col] = hv[r];
    }
    __syncthreads();
  }
}

extern "C" void kernel_launch(void* const* d_in, const int* in_sizes, int n_in,
                              void* d_out, int out_size, void* d_ws, size_t ws_size,
                              hipStream_t stream) {
  const float* x  = (const float*)d_in[0];
  const float* fW = (const float*)d_in[1];
  const float* fU = (const float*)d_in[2];
  const float* fb = (const float*)d_in[3];
  const float* bW = (const float*)d_in[4];
  const float* bU = (const float*)d_in[5];
  const float* bb = (const float*)d_in[6];
  u16*   xwbuf = (u16*)d_ws;
  u16*   UT    = (u16*)d_ws + XW_ELEMS;
  float* out   = (float*)d_out;

  const bool fast = ws_size >= (XW_ELEMS + UT_ELEMS) * sizeof(u16);

  dim3 g1(32, 32);
  xw_gemm<<<g1, 256, 0, stream>>>(x, fW, bW, fb, bb, xwbuf);
  if (fast) {
    build_ut<<<8, 1024, 0, stream>>>(fU, bU, UT);
    hipFuncSetAttribute((const void*)lstm_scan_fast,
                        hipFuncAttributeMaxDynamicSharedMemorySize, 147456);
    lstm_scan_fast<<<8, 1024, 147456, stream>>>(xwbuf, UT, out);
  } else {
    lstm_scan_safe<<<8, 1024, 0, stream>>>(xwbuf, fU, bU, out);
  }
}

// Round 4
// 7162.020 us; speedup vs baseline: 1.0720x; 1.0720x over previous
//
#include <hip/hip_runtime.h>

#define T_STEPS 1024
#define BATCH   64
#define NDIM    256
#define HID     256
#define G4      1024   // 4*H

typedef short bf16x8 __attribute__((ext_vector_type(8)));
typedef float f32x4  __attribute__((ext_vector_type(4)));
typedef unsigned short u16;

#define XW_ELEMS ((size_t)2 * T_STEPS * BATCH * G4)   // 134217728 u16 (256 MiB)
#define UT_ELEMS ((size_t)2 * 4 * 65536)              // 524288 u16 (1 MiB)

__device__ __forceinline__ float b2f(u16 v) {
  union { unsigned u; float f; } c; c.u = ((unsigned)v) << 16; return c.f;
}
__device__ __forceinline__ u16 f2b(float f) {
  union { float f; unsigned u; } c; c.f = f;
  unsigned u = c.u;
  u += 0x7fffu + ((u >> 16) & 1u);   // round-to-nearest-even
  return (u16)(u >> 16);
}
__device__ __forceinline__ float sigm(float x) {
  float e = __expf(-x);
  return __builtin_amdgcn_rcpf(1.0f + e);
}
__device__ __forceinline__ float tanh_f(float x) {
  return 2.0f * sigm(2.0f * x) - 1.0f;
}

// ---------------------------------------------------------------------------
// build_ut: pre-transpose U (f32) into bf16 MFMA B-fragment order.
// UT elem idx: ((d*4+g)*65536) + ((w*8+kf)*64 + lane)*8 + j
// ---------------------------------------------------------------------------
__global__ __launch_bounds__(1024) void build_ut(
    const float* __restrict__ U0, const float* __restrict__ U1,
    u16* __restrict__ UT)
{
  const int d = blockIdx.x >> 2;
  const int g = blockIdx.x & 3;
  const float* __restrict__ U = d ? U1 : U0;
  const int w = threadIdx.x >> 6, lane = threadIdx.x & 63;
  const int q = lane >> 4, c15 = lane & 15;
  u16* dst = UT + ((size_t)d * 4 + g) * 65536;
  #pragma unroll
  for (int kf = 0; kf < 8; ++kf) {
    bf16x8 v;
    #pragma unroll
    for (int j = 0; j < 8; ++j)
      v[j] = (short)f2b(U[(size_t)(kf * 32 + q * 8 + j) * G4 + g * 256 + w * 16 + c15]);
    ((bf16x8*)dst)[((w * 8 + kf) << 6) + lane] = v;
  }
}

// ---------------------------------------------------------------------------
// Phase 1: xw = x @ W_d + b_d, bf16, scan-consumption order:
//   elem idx = (((d*T + t)*4 + bt)*1024 + tid)*16 + gate*4 + r
// 64-col N-tiles (uf = 128 VGPRs), t-chunk 32 -> grid 1024 blocks, 2 blk/CU.
// ---------------------------------------------------------------------------
__global__ __launch_bounds__(256, 2) void xw_gemm(
    const float* __restrict__ x,
    const float* __restrict__ W0, const float* __restrict__ W1,
    const float* __restrict__ b0, const float* __restrict__ b1,
    u16* __restrict__ xw)
{
  const int d  = blockIdx.y >> 4;
  const int n0 = (blockIdx.y & 15) * 64;
  const int t0 = blockIdx.x * 32;
  const float* __restrict__ W    = d ? W1 : W0;
  const float* __restrict__ bias = d ? b1 : b0;
  const int lane = threadIdx.x & 63;
  const int wv   = threadIdx.x >> 6;
  const int q    = lane >> 4;
  const int c15  = lane & 15;

  bf16x8 uf[4][8];
  #pragma unroll
  for (int ct = 0; ct < 4; ++ct) {
    const int col = n0 + ct * 16 + c15;
    #pragma unroll
    for (int kf = 0; kf < 8; ++kf) {
      #pragma unroll
      for (int j = 0; j < 8; ++j)
        uf[ct][kf][j] = (short)f2b(W[(size_t)(kf * 32 + q * 8 + j) * G4 + col]);
    }
  }
  float bc[4];
  #pragma unroll
  for (int ct = 0; ct < 4; ++ct) bc[ct] = bias[n0 + ct * 16 + c15];

  __shared__ __align__(16) u16 Alds[64 * 256];

  for (int t = t0; t < t0 + 32; ++t) {
    __syncthreads();
    const float* xt = x + (size_t)t * BATCH * NDIM;
    #pragma unroll
    for (int i = 0; i < 8; ++i) {
      int g = (int)threadIdx.x + 256 * i;
      int r = g >> 5, c = g & 31;
      const float* src = xt + r * 256 + c * 8;
      bf16x8 v;
      #pragma unroll
      for (int j = 0; j < 8; ++j) v[j] = (short)f2b(src[j]);
      int cs = (c & 16) | ((c ^ (r & 15)) & 15);
      ((bf16x8*)Alds)[r * 32 + cs] = v;
    }
    __syncthreads();

    bf16x8 af[8];
    const int arow = wv * 16 + c15;
    #pragma unroll
    for (int kf = 0; kf < 8; ++kf) {
      int c = kf * 4 + q;
      int cs = (c & 16) | ((c ^ c15) & 15);
      af[kf] = ((const bf16x8*)Alds)[arow * 32 + cs];
    }

    f32x4 acc[4];
    #pragma unroll
    for (int ct = 0; ct < 4; ++ct) acc[ct] = (f32x4){0.f, 0.f, 0.f, 0.f};
    #pragma unroll
    for (int kf = 0; kf < 8; ++kf) {
      #pragma unroll
      for (int ct = 0; ct < 4; ++ct)
        acc[ct] = __builtin_amdgcn_mfma_f32_16x16x32_bf16(af[kf], uf[ct][kf], acc[ct], 0, 0, 0);
    }

    u16* dst = xw + (((size_t)d * T_STEPS + t) * 4 + wv) * 16384;
    #pragma unroll
    for (int ct = 0; ct < 4; ++ct) {
      int ncol = n0 + ct * 16;
      int g2 = ncol >> 8, w2 = (ncol >> 4) & 15;
      union { u16 s[4]; uint2 v; } pk;
      #pragma unroll
      for (int r = 0; r < 4; ++r) pk.s[r] = f2b(acc[ct][r] + bc[ct]);
      *(uint2*)(dst + (size_t)(w2 * 64 + q * 16 + c15) * 16 + g2 * 4) = pk.v;
    }
  }
}

// ---------------------------------------------------------------------------
// Phase 2 (fast): grid 8 = (d, bt). 16 waves; wave w owns h-cols [w*16,+16).
// U by gate: f,g in 64 VGPRs; i in 128 KB LDS; o streamed from L2 (rolling
// buffer crossing the step boundary). acc seeded with xw pre-activations
// (prefetched one step ahead). Walking pointers for out/xw.
// Dynamic LDS 147456 B: [0,16384) h ping-pong (8 KB each), [16384,..) U_i.
//
// S2 (this round's single change vs the 3537 us baseline): out-stores for
// step t are DEFERRED to the top of step t+1 (hv kept in registers across
// the barrier). Rationale: __syncthreads' implied vmcnt(0) drain was waiting
// on store acks issued only ~200 cyc earlier (round-2/3 evidence); deferred
// stores have a full step (~8000 cyc) to land before the drain that waits
// on them. Drain still runs every step -> no write-queue pileup (round-3
// failure mode). Same values to same addresses; numerics unchanged.
// ---------------------------------------------------------------------------
__global__ __launch_bounds__(1024) void lstm_scan_fast(
    const u16* __restrict__ xw, const u16* __restrict__ UT,
    float* __restrict__ out)
{
  extern __shared__ __align__(16) u16 dynlds[];
  const int d  = blockIdx.x >> 2;
  const int bt = blockIdx.x & 3;
  const int tid  = threadIdx.x;
  const int w    = tid >> 6;
  const int lane = tid & 63;
  const int q    = lane >> 4;
  const int c15  = lane & 15;

  const u16* __restrict__ UTd = UT + (size_t)d * 4 * 65536;

  // persistent register fragments for gates f(0), g(1)
  bf16x8 uf0[8], uf1[8];
  const bf16x8* UTf = (const bf16x8*)UTd;
  #pragma unroll
  for (int kf = 0; kf < 8; ++kf) {
    uf0[kf] = UTf[       ((w * 8 + kf) << 6) + lane];
    uf1[kf] = UTf[8192 + ((w * 8 + kf) << 6) + lane];
  }

  // stage i-gate into LDS + zero both h buffers
  {
    const int4* src = (const int4*)(UTd + 2 * 65536);
    int4* dstl = (int4*)(dynlds + 8192);
    for (int i = tid; i < 8192; i += 1024) dstl[i] = src[i];
    for (int i = tid; i < 8192; i += 1024) dynlds[i] = 0;
  }

  const int4* __restrict__ Uo4 = (const int4*)(UTd + 3 * 65536);
  const int obase = (w << 9) | lane;
  const char* uib_base = (const char*)(dynlds + 8192) + (size_t)obase * 16;  // +kf*1024 imm

  // precomputed LDS byte offsets; h buffer selected by XOR 8192
  int afo[8];
  #pragma unroll
  for (int kf = 0; kf < 8; ++kf) {
    int cc = kf * 4 + q;
    int cs = (cc & 16) | ((cc ^ c15) & 15);
    afo[kf] = (c15 * 32 + cs) * 16;
  }
  const int colv = w * 16 + c15;
  int hwo[4];
  #pragma unroll
  for (int r = 0; r < 4; ++r) {
    int row = q * 4 + r;
    int cch = colv >> 3;
    int cs = (cch & 16) | ((cch ^ row) & 15);
    hwo[r] = ((row * 32 + cs) * 8 + (colv & 7)) * 2;
  }

  float cst[4] = {0.f, 0.f, 0.f, 0.f};
  __syncthreads();

  const int rowbase = bt * 16;
  const size_t hlast_base = (size_t)T_STEPS * BATCH * (2 * HID) + (size_t)d * BATCH * HID;
  const int t_first = d ? (T_STEPS - 1) : 0;

  // xw walking pointer; prefetch step 0
  const long xw_stride = d ? -(long)(4 * 16384) : (long)(4 * 16384);
  const u16* xwp = xw + (((size_t)d * T_STEPS + t_first) * 4 + bt) * 16384 + (size_t)tid * 16;
  union I4x2 { int4 v[2]; u16 s[16]; };
  I4x2 xn;
  xn.v[0] = ((const int4*)xwp)[0];
  xn.v[1] = ((const int4*)xwp)[1];
  xwp += xw_stride;

  // o-gate rolling L2 stream (persistent across the step boundary)
  int4 ofr[3];
  ofr[0] = Uo4[obase];
  ofr[1] = Uo4[obase + 64];

  // out walking pointer (points at the slot of the step whose hv is pending)
  float* outp = out + (size_t)(t_first * BATCH + rowbase + q * 4) * (2 * HID)
              + (size_t)d * HID + colv;
  const long out_stride = d ? -(long)(BATCH * 2 * HID) : (long)(BATCH * 2 * HID);

  float hv[4];   // deferred out-store values, live across the barrier
  int curoff = 0;
  for (int it = 0; it < T_STEPS; ++it) {
    // S2: deferred out-store of the PREVIOUS step's h (acks get a full step
    // to land before the next __syncthreads vmcnt drain)
    if (it) {
      #pragma unroll
      for (int r = 0; r < 4; ++r)
        outp[r * (2 * HID)] = hv[r];        // imm offsets 0/2048/4096/6144 B
      outp += out_stride;
    }

    // seed accumulators with current step's pre-activations
    f32x4 acc0 = { b2f(xn.s[0]),  b2f(xn.s[1]),  b2f(xn.s[2]),  b2f(xn.s[3])  };
    f32x4 acc1 = { b2f(xn.s[4]),  b2f(xn.s[5]),  b2f(xn.s[6]),  b2f(xn.s[7])  };
    f32x4 acc2 = { b2f(xn.s[8]),  b2f(xn.s[9]),  b2f(xn.s[10]), b2f(xn.s[11]) };
    f32x4 acc3 = { b2f(xn.s[12]), b2f(xn.s[13]), b2f(xn.s[14]), b2f(xn.s[15]) };

    // prefetch next step's xw (hidden under this step's MFMA+gates)
    if (it + 1 < T_STEPS) {
      xn.v[0] = ((const int4*)xwp)[0];
      xn.v[1] = ((const int4*)xwp)[1];
      xwp += xw_stride;
    }

    const char* hcb = (const char*)dynlds + curoff;
    bf16x8 afb[2], uib[2];
    afb[0] = *(const bf16x8*)(hcb + afo[0]);
    uib[0] = *(const bf16x8*)(uib_base);
    #pragma unroll
    for (int kf = 0; kf < 8; ++kf) {
      if (kf < 7) {
        afb[(kf + 1) & 1] = *(const bf16x8*)(hcb + afo[kf + 1]);
        uib[(kf + 1) & 1] = *(const bf16x8*)(uib_base + (kf + 1) * 1024);
      }
      if (kf < 6) ofr[(kf + 2) % 3] = Uo4[obase + ((kf + 2) << 6)];
      bf16x8 af = afb[kf & 1];
      union { int4 v; bf16x8 b; } oc; oc.v = ofr[kf % 3];
      acc0 = __builtin_amdgcn_mfma_f32_16x16x32_bf16(af, uf0[kf],     acc0, 0, 0, 0);
      acc1 = __builtin_amdgcn_mfma_f32_16x16x32_bf16(af, uf1[kf],     acc1, 0, 0, 0);
      acc2 = __builtin_amdgcn_mfma_f32_16x16x32_bf16(af, uib[kf & 1], acc2, 0, 0, 0);
      acc3 = __builtin_amdgcn_mfma_f32_16x16x32_bf16(af, oc.b,        acc3, 0, 0, 0);
    }
    // refill o-stream head for NEXT step now; latency hides under the gates
    ofr[0] = Uo4[obase];
    ofr[1] = Uo4[obase + 64];

    #pragma unroll
    for (int r = 0; r < 4; ++r) {
      float fg = sigm(acc0[r]);
      float gg = tanh_f(acc1[r]);
      float ig = sigm(acc2[r]);
      float og = sigm(acc3[r]);
      float cn = cst[r] * fg + gg * ig;
      cst[r] = cn;
      hv[r] = og * tanh_f(cn);
    }

    const int nxtoff = curoff ^ 8192;
    char* hwp = (char*)dynlds + nxtoff;
    #pragma unroll
    for (int r = 0; r < 4; ++r)
      *(u16*)(hwp + hwo[r]) = f2b(hv[r]);

    curoff = nxtoff;
    __syncthreads();
  }

  // epilogue: final step's out-store + last-h
  #pragma unroll
  for (int r = 0; r < 4; ++r) {
    outp[r * (2 * HID)] = hv[r];
    out[hlast_base + (size_t)(rowbase + q * 4 + r) * HID + colv] = hv[r];
  }
}

// ---------------------------------------------------------------------------
// Phase 2 (safe fallback if ws too small for UT): correct but slow.
// ---------------------------------------------------------------------------
__global__ __launch_bounds__(1024) void lstm_scan_safe(
    const u16* __restrict__ xw,
    const float* __restrict__ U0, const float* __restrict__ U1,
    float* __restrict__ out)
{
  const int d  = blockIdx.x >> 2;
  const int bt = blockIdx.x & 3;
  const int tid  = threadIdx.x;
  const int w    = tid >> 6;
  const int lane = tid & 63;
  const int q    = lane >> 4;
  const int c15  = lane & 15;
  const float* __restrict__ U = d ? U1 : U0;

  bf16x8 uf[4][8];
  #pragma unroll
  for (int g = 0; g < 4; ++g) {
    const int col2 = g * 256 + w * 16 + c15;
    #pragma unroll
    for (int kf = 0; kf < 8; ++kf) {
      #pragma unroll
      for (int j = 0; j < 8; ++j)
        uf[g][kf][j] = (short)f2b(U[(size_t)(kf * 32 + q * 8 + j) * G4 + col2]);
    }
  }

  __shared__ __align__(16) u16 hbuf[2][16 * 256];
  for (int i = tid; i < 16 * 256; i += 1024) { hbuf[0][i] = 0; hbuf[1][i] = 0; }
  float cst[4] = {0.f, 0.f, 0.f, 0.f};
  __syncthreads();

  const int rowbase = bt * 16;
  const int col = w * 16 + c15;
  const size_t hlast_base = (size_t)T_STEPS * BATCH * (2 * HID) + (size_t)d * BATCH * HID;

  for (int it = 0; it < T_STEPS; ++it) {
    const int t = d ? (T_STEPS - 1 - it) : it;
    union { int4 v[2]; u16 s[16]; } xv;
    {
      const int4* xwt = (const int4*)(xw + ((((size_t)d * T_STEPS + t) * 4 + bt) * 1024 + tid) * 16);
      xv.v[0] = xwt[0]; xv.v[1] = xwt[1];
    }
    const int cur = it & 1;
    bf16x8 af[8];
    #pragma unroll
    for (int kf = 0; kf < 8; ++kf) {
      int cc = kf * 4 + q;
      int cs = (cc & 16) | ((cc ^ c15) & 15);
      af[kf] = ((const bf16x8*)hbuf[cur])[c15 * 32 + cs];
    }
    f32x4 acc[4];
    #pragma unroll
    for (int g = 0; g < 4; ++g) acc[g] = (f32x4){0.f, 0.f, 0.f, 0.f};
    #pragma unroll
    for (int kf = 0; kf < 8; ++kf)
      #pragma unroll
      for (int g = 0; g < 4; ++g)
        acc[g] = __builtin_amdgcn_mfma_f32_16x16x32_bf16(af[kf], uf[g][kf], acc[g], 0, 0, 0);

    u16 hb[4]; float hv[4];
    #pragma unroll
    for (int r = 0; r < 4; ++r) {
      float zf = acc[0][r] + b2f(xv.s[0 * 4 + r]);
      float zg = acc[1][r] + b2f(xv.s[1 * 4 + r]);
      float zi = acc[2][r] + b2f(xv.s[2 * 4 + r]);
      float zo = acc[3][r] + b2f(xv.s[3 * 4 + r]);
      float fg = sigm(zf), gg = tanh_f(zg), ig = sigm(zi), og = sigm(zo);
      float cn = cst[r] * fg + gg * ig;
      cst[r] = cn;
      hv[r] = og * tanh_f(cn);
      hb[r] = f2b(hv[r]);
    }
    const int nxt = cur ^ 1;
    #pragma unroll
    for (int r = 0; r < 4; ++r) {
      const int row = q * 4 + r;
      int cch = col >> 3;
      int cs = (cch & 16) | ((cch ^ row) & 15);
      hbuf[nxt][(row * 32 + cs) * 8 + (col & 7)] = hb[r];
      out[((size_t)t * BATCH + rowbase + row) * (2 * HID) + (size_t)d * HID + col] = hv[r];
    }
    if (it == T_STEPS - 1) {
      #pragma unroll
      for (int r = 0; r < 4; ++r)
        out[hlast_base + (size_t)(rowbase + q * 4 + r) * HID + col] = hv[r];
    }
    __syncthreads();
  }
}

extern "C" void kernel_launch(void* const* d_in, const int* in_sizes, int n_in,
                              void* d_out, int out_size, void* d_ws, size_t ws_size,
                              hipStream_t stream) {
  const float* x  = (const float*)d_in[0];
  const float* fW = (const float*)d_in[1];
  const float* fU = (const float*)d_in[2];
  const float* fb = (const float*)d_in[3];
  const float* bW = (const float*)d_in[4];
  const float* bU = (const float*)d_in[5];
  const float* bb = (const float*)d_in[6];
  u16*   xwbuf = (u16*)d_ws;
  u16*   UT    = (u16*)d_ws + XW_ELEMS;
  float* out   = (float*)d_out;

  const bool fast = ws_size >= (XW_ELEMS + UT_ELEMS) * sizeof(u16);

  dim3 g1(32, 32);
  xw_gemm<<<g1, 256, 0, stream>>>(x, fW, bW, fb, bb, xwbuf);
  if (fast) {
    build_ut<<<8, 1024, 0, stream>>>(fU, bU, UT);
    hipFuncSetAttribute((const void*)lstm_scan_fast,
                        hipFuncAttributeMaxDynamicSharedMemorySize, 147456);
    lstm_scan_fast<<<8, 1024, 147456, stream>>>(xwbuf, UT, out);
  } else {
    lstm_scan_safe<<<8, 1024, 0, stream>>>(xwbuf, fU, bU, out);
  }
}

// Round 5
// 3990.669 us; speedup vs baseline: 1.9239x; 1.7947x over previous
//
#include <hip/hip_runtime.h>

#define T_STEPS 1024
#define BATCH   64
#define NDIM    256
#define HID     256
#define G4      1024   // 4*H

// log2(e) folded into weights/bias so gates use native v_exp_f32 (exp2):
//   f,i,o columns scaled by L2E  -> sigm(z) = 1/(1+exp2(-acc))
//   g column scaled by 2*L2E     -> tanh(z) = 2/(1+exp2(-acc)) - 1
#define L2E  1.4426950408889634f
#define L2E2 2.8853900817779268f

typedef short bf16x8 __attribute__((ext_vector_type(8)));
typedef float f32x4  __attribute__((ext_vector_type(4)));
typedef unsigned short u16;

#define XW_ELEMS ((size_t)2 * T_STEPS * BATCH * G4)   // 134217728 u16 (256 MiB)
#define UT_ELEMS ((size_t)2 * 4 * 65536)              // 524288 u16 (1 MiB)

__device__ __forceinline__ float b2f(u16 v) {
  union { unsigned u; float f; } c; c.u = ((unsigned)v) << 16; return c.f;
}
__device__ __forceinline__ u16 f2b(float f) {
  union { float f; unsigned u; } c; c.f = f;
  unsigned u = c.u;
  u += 0x7fffu + ((u >> 16) & 1u);   // round-to-nearest-even
  return (u16)(u >> 16);
}

// ---------------------------------------------------------------------------
// build_ut: pre-transpose U (f32) into bf16 MFMA B-fragment order, with the
// exp2 gate scaling folded in.
// UT elem idx: ((d*4+g)*65536) + ((w*8+kf)*64 + lane)*8 + j
// ---------------------------------------------------------------------------
__global__ __launch_bounds__(1024) void build_ut(
    const float* __restrict__ U0, const float* __restrict__ U1,
    u16* __restrict__ UT)
{
  const int d = blockIdx.x >> 2;
  const int g = blockIdx.x & 3;
  const float sc = (g == 1) ? L2E2 : L2E;
  const float* __restrict__ U = d ? U1 : U0;
  const int w = threadIdx.x >> 6, lane = threadIdx.x & 63;
  const int q = lane >> 4, c15 = lane & 15;
  u16* dst = UT + ((size_t)d * 4 + g) * 65536;
  #pragma unroll
  for (int kf = 0; kf < 8; ++kf) {
    bf16x8 v;
    #pragma unroll
    for (int j = 0; j < 8; ++j)
      v[j] = (short)f2b(sc * U[(size_t)(kf * 32 + q * 8 + j) * G4 + g * 256 + w * 16 + c15]);
    ((bf16x8*)dst)[((w * 8 + kf) << 6) + lane] = v;
  }
}

// ---------------------------------------------------------------------------
// Phase 1: xw = (x @ W_d + b_d) * gate_scale, bf16, scan-consumption order:
//   elem idx = (((d*T + t)*4 + bt)*1024 + tid)*16 + gate*4 + r
// 64-col N-tiles (uf = 128 VGPRs), t-chunk 32 -> grid 1024 blocks, 2 blk/CU.
// ---------------------------------------------------------------------------
__global__ __launch_bounds__(256, 2) void xw_gemm(
    const float* __restrict__ x,
    const float* __restrict__ W0, const float* __restrict__ W1,
    const float* __restrict__ b0, const float* __restrict__ b1,
    u16* __restrict__ xw)
{
  const int d  = blockIdx.y >> 4;
  const int n0 = (blockIdx.y & 15) * 64;
  const int t0 = blockIdx.x * 32;
  const float* __restrict__ W    = d ? W1 : W0;
  const float* __restrict__ bias = d ? b1 : b0;
  const int lane = threadIdx.x & 63;
  const int wv   = threadIdx.x >> 6;
  const int q    = lane >> 4;
  const int c15  = lane & 15;

  bf16x8 uf[4][8];
  float bc[4];
  #pragma unroll
  for (int ct = 0; ct < 4; ++ct) {
    const int col = n0 + ct * 16 + c15;
    const float sc = (((n0 + ct * 16) >> 8) == 1) ? L2E2 : L2E;
    #pragma unroll
    for (int kf = 0; kf < 8; ++kf) {
      #pragma unroll
      for (int j = 0; j < 8; ++j)
        uf[ct][kf][j] = (short)f2b(sc * W[(size_t)(kf * 32 + q * 8 + j) * G4 + col]);
    }
    bc[ct] = sc * bias[col];
  }

  __shared__ __align__(16) u16 Alds[64 * 256];

  for (int t = t0; t < t0 + 32; ++t) {
    __syncthreads();
    const float* xt = x + (size_t)t * BATCH * NDIM;
    #pragma unroll
    for (int i = 0; i < 8; ++i) {
      int g = (int)threadIdx.x + 256 * i;
      int r = g >> 5, c = g & 31;
      const float* src = xt + r * 256 + c * 8;
      bf16x8 v;
      #pragma unroll
      for (int j = 0; j < 8; ++j) v[j] = (short)f2b(src[j]);
      int cs = (c & 16) | ((c ^ (r & 15)) & 15);
      ((bf16x8*)Alds)[r * 32 + cs] = v;
    }
    __syncthreads();

    bf16x8 af[8];
    const int arow = wv * 16 + c15;
    #pragma unroll
    for (int kf = 0; kf < 8; ++kf) {
      int c = kf * 4 + q;
      int cs = (c & 16) | ((c ^ c15) & 15);
      af[kf] = ((const bf16x8*)Alds)[arow * 32 + cs];
    }

    f32x4 acc[4];
    #pragma unroll
    for (int ct = 0; ct < 4; ++ct) acc[ct] = (f32x4){0.f, 0.f, 0.f, 0.f};
    #pragma unroll
    for (int kf = 0; kf < 8; ++kf) {
      #pragma unroll
      for (int ct = 0; ct < 4; ++ct)
        acc[ct] = __builtin_amdgcn_mfma_f32_16x16x32_bf16(af[kf], uf[ct][kf], acc[ct], 0, 0, 0);
    }

    u16* dst = xw + (((size_t)d * T_STEPS + t) * 4 + wv) * 16384;
    #pragma unroll
    for (int ct = 0; ct < 4; ++ct) {
      int ncol = n0 + ct * 16;
      int g2 = ncol >> 8, w2 = (ncol >> 4) & 15;
      union { u16 s[4]; uint2 v; } pk;
      #pragma unroll
      for (int r = 0; r < 4; ++r) pk.s[r] = f2b(acc[ct][r] + bc[ct]);
      *(uint2*)(dst + (size_t)(w2 * 64 + q * 16 + c15) * 16 + g2 * 4) = pk.v;
    }
  }
}

// ---------------------------------------------------------------------------
// Phase 2 (fast): grid 8 = (d, bt). 16 waves; wave w owns h-cols [w*16,+16).
// Structure is BYTE-IDENTICAL to the 3537us baseline (dist-2 o-stream,
// in-loop uib loads, end-of-step stores, plain __syncthreads). Rounds 2-4
// showed the kf-loop/barrier/store schedule is fragile: in-flight stores
// during the kf loop poison the counted vmcnt waits on the o-stream
// (vmcnt is ordered: waiting on a load also waits on older store acks).
// ONLY change this round: gate math in exp2 domain (weights pre-scaled by
// log2e / 2log2e) with combined reciprocals -> ~7 TRANS + fewer VALU per
// output vs 10 TRANS. Proven numerically in round 2 (absmax 0.0078).
// Dynamic LDS 147456 B: [0,16384) h ping-pong (8 KB each), [16384,..) U_i.
// ---------------------------------------------------------------------------
__global__ __launch_bounds__(1024) void lstm_scan_fast(
    const u16* __restrict__ xw, const u16* __restrict__ UT,
    float* __restrict__ out)
{
  extern __shared__ __align__(16) u16 dynlds[];
  const int d  = blockIdx.x >> 2;
  const int bt = blockIdx.x & 3;
  const int tid  = threadIdx.x;
  const int w    = tid >> 6;
  const int lane = tid & 63;
  const int q    = lane >> 4;
  const int c15  = lane & 15;

  const u16* __restrict__ UTd = UT + (size_t)d * 4 * 65536;

  // persistent register fragments for gates f(0), g(1)
  bf16x8 uf0[8], uf1[8];
  const bf16x8* UTf = (const bf16x8*)UTd;
  #pragma unroll
  for (int kf = 0; kf < 8; ++kf) {
    uf0[kf] = UTf[       ((w * 8 + kf) << 6) + lane];
    uf1[kf] = UTf[8192 + ((w * 8 + kf) << 6) + lane];
  }

  // stage i-gate into LDS + zero both h buffers
  {
    const int4* src = (const int4*)(UTd + 2 * 65536);
    int4* dstl = (int4*)(dynlds + 8192);
    for (int i = tid; i < 8192; i += 1024) dstl[i] = src[i];
    for (int i = tid; i < 8192; i += 1024) dynlds[i] = 0;
  }

  const int4* __restrict__ Uo4 = (const int4*)(UTd + 3 * 65536);
  const int obase = (w << 9) | lane;
  const char* uib_base = (const char*)(dynlds + 8192) + (size_t)obase * 16;  // +kf*1024 imm

  // precomputed LDS byte offsets; h buffer selected by XOR 8192
  int afo[8];
  #pragma unroll
  for (int kf = 0; kf < 8; ++kf) {
    int cc = kf * 4 + q;
    int cs = (cc & 16) | ((cc ^ c15) & 15);
    afo[kf] = (c15 * 32 + cs) * 16;
  }
  const int colv = w * 16 + c15;
  int hwo[4];
  #pragma unroll
  for (int r = 0; r < 4; ++r) {
    int row = q * 4 + r;
    int cch = colv >> 3;
    int cs = (cch & 16) | ((cch ^ row) & 15);
    hwo[r] = ((row * 32 + cs) * 8 + (colv & 7)) * 2;
  }

  float cst[4] = {0.f, 0.f, 0.f, 0.f};
  __syncthreads();

  const int rowbase = bt * 16;
  const size_t hlast_base = (size_t)T_STEPS * BATCH * (2 * HID) + (size_t)d * BATCH * HID;
  const int t_first = d ? (T_STEPS - 1) : 0;

  // xw walking pointer; prefetch step 0
  const long xw_stride = d ? -(long)(4 * 16384) : (long)(4 * 16384);
  const u16* xwp = xw + (((size_t)d * T_STEPS + t_first) * 4 + bt) * 16384 + (size_t)tid * 16;
  union I4x2 { int4 v[2]; u16 s[16]; };
  I4x2 xn;
  xn.v[0] = ((const int4*)xwp)[0];
  xn.v[1] = ((const int4*)xwp)[1];
  xwp += xw_stride;

  // o-gate rolling L2 stream (persistent across the step boundary)
  int4 ofr[3];
  ofr[0] = Uo4[obase];
  ofr[1] = Uo4[obase + 64];

  // out walking pointer
  float* outp = out + (size_t)(t_first * BATCH + rowbase + q * 4) * (2 * HID)
              + (size_t)d * HID + colv;
  const long out_stride = d ? -(long)(BATCH * 2 * HID) : (long)(BATCH * 2 * HID);

  int curoff = 0;
  for (int it = 0; it < T_STEPS; ++it) {
    // seed accumulators with current step's pre-activations (pre-scaled)
    f32x4 acc0 = { b2f(xn.s[0]),  b2f(xn.s[1]),  b2f(xn.s[2]),  b2f(xn.s[3])  };
    f32x4 acc1 = { b2f(xn.s[4]),  b2f(xn.s[5]),  b2f(xn.s[6]),  b2f(xn.s[7])  };
    f32x4 acc2 = { b2f(xn.s[8]),  b2f(xn.s[9]),  b2f(xn.s[10]), b2f(xn.s[11]) };
    f32x4 acc3 = { b2f(xn.s[12]), b2f(xn.s[13]), b2f(xn.s[14]), b2f(xn.s[15]) };

    // prefetch next step's xw (hidden under this step's MFMA+gates)
    if (it + 1 < T_STEPS) {
      xn.v[0] = ((const int4*)xwp)[0];
      xn.v[1] = ((const int4*)xwp)[1];
      xwp += xw_stride;
    }

    const char* hcb = (const char*)dynlds + curoff;
    bf16x8 afb[2], uib[2];
    afb[0] = *(const bf16x8*)(hcb + afo[0]);
    uib[0] = *(const bf16x8*)(uib_base);
    #pragma unroll
    for (int kf = 0; kf < 8; ++kf) {
      if (kf < 7) {
        afb[(kf + 1) & 1] = *(const bf16x8*)(hcb + afo[kf + 1]);
        uib[(kf + 1) & 1] = *(const bf16x8*)(uib_base + (kf + 1) * 1024);
      }
      if (kf < 6) ofr[(kf + 2) % 3] = Uo4[obase + ((kf + 2) << 6)];
      bf16x8 af = afb[kf & 1];
      union { int4 v; bf16x8 b; } oc; oc.v = ofr[kf % 3];
      acc0 = __builtin_amdgcn_mfma_f32_16x16x32_bf16(af, uf0[kf],     acc0, 0, 0, 0);
      acc1 = __builtin_amdgcn_mfma_f32_16x16x32_bf16(af, uf1[kf],     acc1, 0, 0, 0);
      acc2 = __builtin_amdgcn_mfma_f32_16x16x32_bf16(af, uib[kf & 1], acc2, 0, 0, 0);
      acc3 = __builtin_amdgcn_mfma_f32_16x16x32_bf16(af, oc.b,        acc3, 0, 0, 0);
    }
    // refill o-stream head for NEXT step now; latency hides under the gates
    ofr[0] = Uo4[obase];
    ofr[1] = Uo4[obase + 64];

    // gates: exp2 domain, combined reciprocals (5 exp + 2 rcp per r)
    u16 hb[4]; float hv[4];
    #pragma unroll
    for (int r = 0; r < 4; ++r) {
      float ef = __builtin_amdgcn_exp2f(-acc0[r]);
      float eg = __builtin_amdgcn_exp2f(-acc1[r]);
      float ei = __builtin_amdgcn_exp2f(-acc2[r]);
      float eo = __builtin_amdgcn_exp2f(-acc3[r]);
      float A = 1.0f + ef, B = 1.0f + eg, C = 1.0f + ei, D = 1.0f - eg;
      float BC  = B * C;
      float num = cst[r] * BC + D * A;
      float cn  = num * __builtin_amdgcn_rcpf(A * BC);
      cst[r] = cn;
      float ec = __builtin_amdgcn_exp2f(fminf(-L2E2 * cn, 30.0f));
      float E = 1.0f + eo, F = 1.0f + ec, G = 1.0f - ec;
      hv[r] = G * __builtin_amdgcn_rcpf(E * F);   // = sigm(o) * tanh(c)
      hb[r] = f2b(hv[r]);
    }

    const int nxtoff = curoff ^ 8192;
    char* hwp = (char*)dynlds + nxtoff;
    #pragma unroll
    for (int r = 0; r < 4; ++r) {
      *(u16*)(hwp + hwo[r]) = hb[r];
      outp[r * (2 * HID)] = hv[r];          // imm offsets 0/2048/4096/6144 B
    }
    outp += out_stride;
    if (it == T_STEPS - 1) {
      #pragma unroll
      for (int r = 0; r < 4; ++r)
        out[hlast_base + (size_t)(rowbase + q * 4 + r) * HID + colv] = hv[r];
    }
    curoff = nxtoff;
    __syncthreads();
  }
}

// ---------------------------------------------------------------------------
// Phase 2 (safe fallback if ws too small for UT): correct but slow.
// Consumes the SCALED xw, so it applies the same scaling to U and the same
// exp2-domain gate math.
// ---------------------------------------------------------------------------
__global__ __launch_bounds__(1024) void lstm_scan_safe(
    const u16* __restrict__ xw,
    const float* __restrict__ U0, const float* __restrict__ U1,
    float* __restrict__ out)
{
  const int d  = blockIdx.x >> 2;
  const int bt = blockIdx.x & 3;
  const int tid  = threadIdx.x;
  const int w    = tid >> 6;
  const int lane = tid & 63;
  const int q    = lane >> 4;
  const int c15  = lane & 15;
  const float* __restrict__ U = d ? U1 : U0;

  bf16x8 uf[4][8];
  #pragma unroll
  for (int g = 0; g < 4; ++g) {
    const int col2 = g * 256 + w * 16 + c15;
    const float sc = (g == 1) ? L2E2 : L2E;
    #pragma unroll
    for (int kf = 0; kf < 8; ++kf) {
      #pragma unroll
      for (int j = 0; j < 8; ++j)
        uf[g][kf][j] = (short)f2b(sc * U[(size_t)(kf * 32 + q * 8 + j) * G4 + col2]);
    }
  }

  __shared__ __align__(16) u16 hbuf[2][16 * 256];
  for (int i = tid; i < 16 * 256; i += 1024) { hbuf[0][i] = 0; hbuf[1][i] = 0; }
  float cst[4] = {0.f, 0.f, 0.f, 0.f};
  __syncthreads();

  const int rowbase = bt * 16;
  const int col = w * 16 + c15;
  const size_t hlast_base = (size_t)T_STEPS * BATCH * (2 * HID) + (size_t)d * BATCH * HID;

  for (int it = 0; it < T_STEPS; ++it) {
    const int t = d ? (T_STEPS - 1 - it) : it;
    union { int4 v[2]; u16 s[16]; } xv;
    {
      const int4* xwt = (const int4*)(xw + ((((size_t)d * T_STEPS + t) * 4 + bt) * 1024 + tid) * 16);
      xv.v[0] = xwt[0]; xv.v[1] = xwt[1];
    }
    const int cur = it & 1;
    bf16x8 af[8];
    #pragma unroll
    for (int kf = 0; kf < 8; ++kf) {
      int cc = kf * 4 + q;
      int cs = (cc & 16) | ((cc ^ c15) & 15);
      af[kf] = ((const bf16x8*)hbuf[cur])[c15 * 32 + cs];
    }
    f32x4 acc[4];
    #pragma unroll
    for (int g = 0; g < 4; ++g) acc[g] = (f32x4){0.f, 0.f, 0.f, 0.f};
    #pragma unroll
    for (int kf = 0; kf < 8; ++kf)
      #pragma unroll
      for (int g = 0; g < 4; ++g)
        acc[g] = __builtin_amdgcn_mfma_f32_16x16x32_bf16(af[kf], uf[g][kf], acc[g], 0, 0, 0);

    u16 hb[4]; float hv[4];
    #pragma unroll
    for (int r = 0; r < 4; ++r) {
      float zf = acc[0][r] + b2f(xv.s[0 * 4 + r]);
      float zg = acc[1][r] + b2f(xv.s[1 * 4 + r]);
      float zi = acc[2][r] + b2f(xv.s[2 * 4 + r]);
      float zo = acc[3][r] + b2f(xv.s[3 * 4 + r]);
      float ef = __builtin_amdgcn_exp2f(-zf);
      float eg = __builtin_amdgcn_exp2f(-zg);
      float ei = __builtin_amdgcn_exp2f(-zi);
      float eo = __builtin_amdgcn_exp2f(-zo);
      float A = 1.0f + ef, B = 1.0f + eg, C = 1.0f + ei, D = 1.0f - eg;
      float BC  = B * C;
      float num = cst[r] * BC + D * A;
      float cn  = num * __builtin_amdgcn_rcpf(A * BC);
      cst[r] = cn;
      float ec = __builtin_amdgcn_exp2f(fminf(-L2E2 * cn, 30.0f));
      float E = 1.0f + eo, F = 1.0f + ec, G = 1.0f - ec;
      hv[r] = G * __builtin_amdgcn_rcpf(E * F);
      hb[r] = f2b(hv[r]);
    }
    const int nxt = cur ^ 1;
    #pragma unroll
    for (int r = 0; r < 4; ++r) {
      const int row = q * 4 + r;
      int cch = col >> 3;
      int cs = (cch & 16) | ((cch ^ row) & 15);
      hbuf[nxt][(row * 32 + cs) * 8 + (col & 7)] = hb[r];
      out[((size_t)t * BATCH + rowbase + row) * (2 * HID) + (size_t)d * HID + col] = hv[r];
    }
    if (it == T_STEPS - 1) {
      #pragma unroll
      for (int r = 0; r < 4; ++r)
        out[hlast_base + (size_t)(rowbase + q * 4 + r) * HID + col] = hv[r];
    }
    __syncthreads();
  }
}

extern "C" void kernel_launch(void* const* d_in, const int* in_sizes, int n_in,
                              void* d_out, int out_size, void* d_ws, size_t ws_size,
                              hipStream_t stream) {
  const float* x  = (const float*)d_in[0];
  const float* fW = (const float*)d_in[1];
  const float* fU = (const float*)d_in[2];
  const float* fb = (const float*)d_in[3];
  const float* bW = (const float*)d_in[4];
  const float* bU = (const float*)d_in[5];
  const float* bb = (const float*)d_in[6];
  u16*   xwbuf = (u16*)d_ws;
  u16*   UT    = (u16*)d_ws + XW_ELEMS;
  float* out   = (float*)d_out;

  const bool fast = ws_size >= (XW_ELEMS + UT_ELEMS) * sizeof(u16);

  dim3 g1(32, 32);
  xw_gemm<<<g1, 256, 0, stream>>>(x, fW, bW, fb, bb, xwbuf);
  if (fast) {
    build_ut<<<8, 1024, 0, stream>>>(fU, bU, UT);
    hipFuncSetAttribute((const void*)lstm_scan_fast,
                        hipFuncAttributeMaxDynamicSharedMemorySize, 147456);
    lstm_scan_fast<<<8, 1024, 147456, stream>>>(xwbuf, UT, out);
  } else {
    lstm_scan_safe<<<8, 1024, 0, stream>>>(xwbuf, fU, bU, out);
  }
}

// Round 6
// 3977.486 us; speedup vs baseline: 1.9302x; 1.0033x over previous
//
#include <hip/hip_runtime.h>

#define T_STEPS 1024
#define BATCH   64
#define NDIM    256
#define HID     256
#define G4      1024   // 4*H

typedef short bf16x8 __attribute__((ext_vector_type(8)));
typedef float f32x4  __attribute__((ext_vector_type(4)));
typedef unsigned short u16;

#define XW_ELEMS ((size_t)2 * T_STEPS * BATCH * G4)   // 134217728 u16 (256 MiB)
#define UT_ELEMS ((size_t)2 * 4 * 65536)              // 524288 u16 (1 MiB)
#define WT_ELEMS UT_ELEMS                             // W has the same shape as U

__device__ __forceinline__ float b2f(u16 v) {
  union { unsigned u; float f; } c; c.u = ((unsigned)v) << 16; return c.f;
}
__device__ __forceinline__ u16 f2b(float f) {
  union { float f; unsigned u; } c; c.f = f;
  unsigned u = c.u;
  u += 0x7fffu + ((u >> 16) & 1u);   // round-to-nearest-even
  return (u16)(u >> 16);
}
__device__ __forceinline__ float sigm(float x) {
  float e = __expf(-x);
  return __builtin_amdgcn_rcpf(1.0f + e);
}
__device__ __forceinline__ float tanh_f(float x) {
  return 2.0f * sigm(2.0f * x) - 1.0f;
}

// ---------------------------------------------------------------------------
// build_ut: pre-transpose a 256x1024 f32 matrix pair into bf16 MFMA B-fragment
// order. Used for BOTH U (recurrent) and W (input) weights.
// elem idx: ((d*4+g)*65536) + ((w*8+kf)*64 + lane)*8 + j
// ---------------------------------------------------------------------------
__global__ __launch_bounds__(1024) void build_ut(
    const float* __restrict__ U0, const float* __restrict__ U1,
    u16* __restrict__ UT)
{
  const int d = blockIdx.x >> 2;
  const int g = blockIdx.x & 3;
  const float* __restrict__ U = d ? U1 : U0;
  const int w = threadIdx.x >> 6, lane = threadIdx.x & 63;
  const int q = lane >> 4, c15 = lane & 15;
  u16* dst = UT + ((size_t)d * 4 + g) * 65536;
  #pragma unroll
  for (int kf = 0; kf < 8; ++kf) {
    bf16x8 v;
    #pragma unroll
    for (int j = 0; j < 8; ++j)
      v[j] = (short)f2b(U[(size_t)(kf * 32 + q * 8 + j) * G4 + g * 256 + w * 16 + c15]);
    ((bf16x8*)dst)[((w * 8 + kf) << 6) + lane] = v;
  }
}

// ---------------------------------------------------------------------------
// Phase 1 v2: xw = x @ W_d + b_d, bf16, scan-consumption order.
// Block = one t-PAIR x ALL 1024 cols x both d: x is staged ONCE (the old
// kernel re-staged each x tile 32x across (d,n0) blocks -> ~2 GB of L3/HBM
// traffic and 32x redundant f2b VALU; that was ~250us of the ~380us phase).
// W comes pre-converted (WT, bf16 fragment order, 2 MB -> L2-resident).
// Grid 512 x 256 thr, 2 blk/CU, one pass, ONE barrier per block.
// Output bit-identical to xw_gemm (same f2b(W) rounding, same MFMA order).
// ---------------------------------------------------------------------------
__global__ __launch_bounds__(256, 2) void xw_gemm_v2(
    const float* __restrict__ x,
    const u16* __restrict__ WT,
    const float* __restrict__ b0, const float* __restrict__ b1,
    u16* __restrict__ xw)
{
  const int t0   = blockIdx.x * 2;
  const int lane = threadIdx.x & 63;
  const int wv   = threadIdx.x >> 6;
  const int q    = lane >> 4;
  const int c15  = lane & 15;

  __shared__ __align__(16) u16 Alds[2 * 64 * 256];   // 64 KB: two x-tiles

  // stage both t-tiles (f32 -> bf16, swizzled A layout), once per block
  #pragma unroll
  for (int t01 = 0; t01 < 2; ++t01) {
    const float* xt = x + (size_t)(t0 + t01) * BATCH * NDIM;
    #pragma unroll
    for (int i = 0; i < 8; ++i) {
      int g = (int)threadIdx.x + 256 * i;
      int r = g >> 5, c = g & 31;
      const float* src = xt + r * 256 + c * 8;
      bf16x8 v;
      #pragma unroll
      for (int j = 0; j < 8; ++j) v[j] = (short)f2b(src[j]);
      int cs = (c & 16) | ((c ^ (r & 15)) & 15);
      ((bf16x8*)Alds)[t01 * 2048 + r * 32 + cs] = v;
    }
  }
  __syncthreads();

  // A fragments for both t's, this wave's 16 rows (64 VGPRs)
  bf16x8 af2[2][8];
  const int arow = wv * 16 + c15;
  #pragma unroll
  for (int t01 = 0; t01 < 2; ++t01) {
    #pragma unroll
    for (int kf = 0; kf < 8; ++kf) {
      int c = kf * 4 + q;
      int cs = (c & 16) | ((c ^ c15) & 15);
      af2[t01][kf] = ((const bf16x8*)Alds)[t01 * 2048 + arow * 32 + cs];
    }
  }

  for (int iter = 0; iter < 32; ++iter) {
    const int d  = iter >> 4;
    const int n0 = (iter & 15) * 64;
    const float* __restrict__ bias = d ? b1 : b0;

    // W fragments for these 64 cols from L2-resident WT (no f2b needed)
    bf16x8 uf[4][8];
    float bc[4];
    #pragma unroll
    for (int ct = 0; ct < 4; ++ct) {
      const int ncol = n0 + ct * 16;
      const int g2 = ncol >> 8, wcol = (ncol >> 4) & 15;
      const bf16x8* wsrc = (const bf16x8*)(WT + ((size_t)d * 4 + g2) * 65536);
      #pragma unroll
      for (int kf = 0; kf < 8; ++kf)
        uf[ct][kf] = wsrc[((wcol * 8 + kf) << 6) + lane];
      bc[ct] = bias[ncol + c15];
    }

    #pragma unroll
    for (int t01 = 0; t01 < 2; ++t01) {
      f32x4 acc[4];
      #pragma unroll
      for (int ct = 0; ct < 4; ++ct) acc[ct] = (f32x4){0.f, 0.f, 0.f, 0.f};
      #pragma unroll
      for (int kf = 0; kf < 8; ++kf) {
        #pragma unroll
        for (int ct = 0; ct < 4; ++ct)
          acc[ct] = __builtin_amdgcn_mfma_f32_16x16x32_bf16(af2[t01][kf], uf[ct][kf], acc[ct], 0, 0, 0);
      }

      u16* dst = xw + (((size_t)d * T_STEPS + (t0 + t01)) * 4 + wv) * 16384;
      #pragma unroll
      for (int ct = 0; ct < 4; ++ct) {
        int ncol = n0 + ct * 16;
        int g2 = ncol >> 8, w2 = (ncol >> 4) & 15;
        union { u16 s[4]; uint2 v; } pk;
        #pragma unroll
        for (int r = 0; r < 4; ++r) pk.s[r] = f2b(acc[ct][r] + bc[ct]);
        *(uint2*)(dst + (size_t)(w2 * 64 + q * 16 + c15) * 16 + g2 * 4) = pk.v;
      }
    }
  }
}

// ---------------------------------------------------------------------------
// Phase 1 fallback (round-0 kernel): used when ws lacks room for WT.
// ---------------------------------------------------------------------------
__global__ __launch_bounds__(256, 2) void xw_gemm(
    const float* __restrict__ x,
    const float* __restrict__ W0, const float* __restrict__ W1,
    const float* __restrict__ b0, const float* __restrict__ b1,
    u16* __restrict__ xw)
{
  const int d  = blockIdx.y >> 4;
  const int n0 = (blockIdx.y & 15) * 64;
  const int t0 = blockIdx.x * 32;
  const float* __restrict__ W    = d ? W1 : W0;
  const float* __restrict__ bias = d ? b1 : b0;
  const int lane = threadIdx.x & 63;
  const int wv   = threadIdx.x >> 6;
  const int q    = lane >> 4;
  const int c15  = lane & 15;

  bf16x8 uf[4][8];
  #pragma unroll
  for (int ct = 0; ct < 4; ++ct) {
    const int col = n0 + ct * 16 + c15;
    #pragma unroll
    for (int kf = 0; kf < 8; ++kf) {
      #pragma unroll
      for (int j = 0; j < 8; ++j)
        uf[ct][kf][j] = (short)f2b(W[(size_t)(kf * 32 + q * 8 + j) * G4 + col]);
    }
  }
  float bc[4];
  #pragma unroll
  for (int ct = 0; ct < 4; ++ct) bc[ct] = bias[n0 + ct * 16 + c15];

  __shared__ __align__(16) u16 Alds[64 * 256];

  for (int t = t0; t < t0 + 32; ++t) {
    __syncthreads();
    const float* xt = x + (size_t)t * BATCH * NDIM;
    #pragma unroll
    for (int i = 0; i < 8; ++i) {
      int g = (int)threadIdx.x + 256 * i;
      int r = g >> 5, c = g & 31;
      const float* src = xt + r * 256 + c * 8;
      bf16x8 v;
      #pragma unroll
      for (int j = 0; j < 8; ++j) v[j] = (short)f2b(src[j]);
      int cs = (c & 16) | ((c ^ (r & 15)) & 15);
      ((bf16x8*)Alds)[r * 32 + cs] = v;
    }
    __syncthreads();

    bf16x8 af[8];
    const int arow = wv * 16 + c15;
    #pragma unroll
    for (int kf = 0; kf < 8; ++kf) {
      int c = kf * 4 + q;
      int cs = (c & 16) | ((c ^ c15) & 15);
      af[kf] = ((const bf16x8*)Alds)[arow * 32 + cs];
    }

    f32x4 acc[4];
    #pragma unroll
    for (int ct = 0; ct < 4; ++ct) acc[ct] = (f32x4){0.f, 0.f, 0.f, 0.f};
    #pragma unroll
    for (int kf = 0; kf < 8; ++kf) {
      #pragma unroll
      for (int ct = 0; ct < 4; ++ct)
        acc[ct] = __builtin_amdgcn_mfma_f32_16x16x32_bf16(af[kf], uf[ct][kf], acc[ct], 0, 0, 0);
    }

    u16* dst = xw + (((size_t)d * T_STEPS + t) * 4 + wv) * 16384;
    #pragma unroll
    for (int ct = 0; ct < 4; ++ct) {
      int ncol = n0 + ct * 16;
      int g2 = ncol >> 8, w2 = (ncol >> 4) & 15;
      union { u16 s[4]; uint2 v; } pk;
      #pragma unroll
      for (int r = 0; r < 4; ++r) pk.s[r] = f2b(acc[ct][r] + bc[ct]);
      *(uint2*)(dst + (size_t)(w2 * 64 + q * 16 + c15) * 16 + g2 * 4) = pk.v;
    }
  }
}

// ---------------------------------------------------------------------------
// Phase 2 (fast): BYTE-IDENTICAL to the round-0 3537us baseline. Rounds 2-5
// established: (a) the kf-loop/store/barrier schedule is fragile — in-flight
// stores during the kf loop poison counted vmcnt waits (vmcnt is ordered);
// (b) the scan is latency-chain-bound, not VALU-bound — the exp2 gate
// rewrite cut VALU 21% and time got WORSE by 1.3%. Do not touch this kernel.
// Dynamic LDS 147456 B: [0,16384) h ping-pong (8 KB each), [16384,..) U_i.
// ---------------------------------------------------------------------------
__global__ __launch_bounds__(1024) void lstm_scan_fast(
    const u16* __restrict__ xw, const u16* __restrict__ UT,
    float* __restrict__ out)
{
  extern __shared__ __align__(16) u16 dynlds[];
  const int d  = blockIdx.x >> 2;
  const int bt = blockIdx.x & 3;
  const int tid  = threadIdx.x;
  const int w    = tid >> 6;
  const int lane = tid & 63;
  const int q    = lane >> 4;
  const int c15  = lane & 15;

  const u16* __restrict__ UTd = UT + (size_t)d * 4 * 65536;

  // persistent register fragments for gates f(0), g(1)
  bf16x8 uf0[8], uf1[8];
  const bf16x8* UTf = (const bf16x8*)UTd;
  #pragma unroll
  for (int kf = 0; kf < 8; ++kf) {
    uf0[kf] = UTf[       ((w * 8 + kf) << 6) + lane];
    uf1[kf] = UTf[8192 + ((w * 8 + kf) << 6) + lane];
  }

  // stage i-gate into LDS + zero both h buffers
  {
    const int4* src = (const int4*)(UTd + 2 * 65536);
    int4* dstl = (int4*)(dynlds + 8192);
    for (int i = tid; i < 8192; i += 1024) dstl[i] = src[i];
    for (int i = tid; i < 8192; i += 1024) dynlds[i] = 0;
  }

  const int4* __restrict__ Uo4 = (const int4*)(UTd + 3 * 65536);
  const int obase = (w << 9) | lane;
  const char* uib_base = (const char*)(dynlds + 8192) + (size_t)obase * 16;  // +kf*1024 imm

  // precomputed LDS byte offsets; h buffer selected by XOR 8192
  int afo[8];
  #pragma unroll
  for (int kf = 0; kf < 8; ++kf) {
    int cc = kf * 4 + q;
    int cs = (cc & 16) | ((cc ^ c15) & 15);
    afo[kf] = (c15 * 32 + cs) * 16;
  }
  const int colv = w * 16 + c15;
  int hwo[4];
  #pragma unroll
  for (int r = 0; r < 4; ++r) {
    int row = q * 4 + r;
    int cch = colv >> 3;
    int cs = (cch & 16) | ((cch ^ row) & 15);
    hwo[r] = ((row * 32 + cs) * 8 + (colv & 7)) * 2;
  }

  float cst[4] = {0.f, 0.f, 0.f, 0.f};
  __syncthreads();

  const int rowbase = bt * 16;
  const size_t hlast_base = (size_t)T_STEPS * BATCH * (2 * HID) + (size_t)d * BATCH * HID;
  const int t_first = d ? (T_STEPS - 1) : 0;

  // xw walking pointer; prefetch step 0
  const long xw_stride = d ? -(long)(4 * 16384) : (long)(4 * 16384);
  const u16* xwp = xw + (((size_t)d * T_STEPS + t_first) * 4 + bt) * 16384 + (size_t)tid * 16;
  union I4x2 { int4 v[2]; u16 s[16]; };
  I4x2 xn;
  xn.v[0] = ((const int4*)xwp)[0];
  xn.v[1] = ((const int4*)xwp)[1];
  xwp += xw_stride;

  // o-gate rolling L2 stream (persistent across the step boundary)
  int4 ofr[3];
  ofr[0] = Uo4[obase];
  ofr[1] = Uo4[obase + 64];

  // out walking pointer
  float* outp = out + (size_t)(t_first * BATCH + rowbase + q * 4) * (2 * HID)
              + (size_t)d * HID + colv;
  const long out_stride = d ? -(long)(BATCH * 2 * HID) : (long)(BATCH * 2 * HID);

  int curoff = 0;
  for (int it = 0; it < T_STEPS; ++it) {
    // seed accumulators with current step's pre-activations
    f32x4 acc0 = { b2f(xn.s[0]),  b2f(xn.s[1]),  b2f(xn.s[2]),  b2f(xn.s[3])  };
    f32x4 acc1 = { b2f(xn.s[4]),  b2f(xn.s[5]),  b2f(xn.s[6]),  b2f(xn.s[7])  };
    f32x4 acc2 = { b2f(xn.s[8]),  b2f(xn.s[9]),  b2f(xn.s[10]), b2f(xn.s[11]) };
    f32x4 acc3 = { b2f(xn.s[12]), b2f(xn.s[13]), b2f(xn.s[14]), b2f(xn.s[15]) };

    // prefetch next step's xw (hidden under this step's MFMA+gates)
    if (it + 1 < T_STEPS) {
      xn.v[0] = ((const int4*)xwp)[0];
      xn.v[1] = ((const int4*)xwp)[1];
      xwp += xw_stride;
    }

    const char* hcb = (const char*)dynlds + curoff;
    bf16x8 afb[2], uib[2];
    afb[0] = *(const bf16x8*)(hcb + afo[0]);
    uib[0] = *(const bf16x8*)(uib_base);
    #pragma unroll
    for (int kf = 0; kf < 8; ++kf) {
      if (kf < 7) {
        afb[(kf + 1) & 1] = *(const bf16x8*)(hcb + afo[kf + 1]);
        uib[(kf + 1) & 1] = *(const bf16x8*)(uib_base + (kf + 1) * 1024);
      }
      if (kf < 6) ofr[(kf + 2) % 3] = Uo4[obase + ((kf + 2) << 6)];
      bf16x8 af = afb[kf & 1];
      union { int4 v; bf16x8 b; } oc; oc.v = ofr[kf % 3];
      acc0 = __builtin_amdgcn_mfma_f32_16x16x32_bf16(af, uf0[kf],     acc0, 0, 0, 0);
      acc1 = __builtin_amdgcn_mfma_f32_16x16x32_bf16(af, uf1[kf],     acc1, 0, 0, 0);
      acc2 = __builtin_amdgcn_mfma_f32_16x16x32_bf16(af, uib[kf & 1], acc2, 0, 0, 0);
      acc3 = __builtin_amdgcn_mfma_f32_16x16x32_bf16(af, oc.b,        acc3, 0, 0, 0);
    }
    // refill o-stream head for NEXT step now; latency hides under the gates
    ofr[0] = Uo4[obase];
    ofr[1] = Uo4[obase + 64];

    u16 hb[4]; float hv[4];
    #pragma unroll
    for (int r = 0; r < 4; ++r) {
      float fg = sigm(acc0[r]);
      float gg = tanh_f(acc1[r]);
      float ig = sigm(acc2[r]);
      float og = sigm(acc3[r]);
      float cn = cst[r] * fg + gg * ig;
      cst[r] = cn;
      hv[r] = og * tanh_f(cn);
      hb[r] = f2b(hv[r]);
    }

    const int nxtoff = curoff ^ 8192;
    char* hwp = (char*)dynlds + nxtoff;
    #pragma unroll
    for (int r = 0; r < 4; ++r) {
      *(u16*)(hwp + hwo[r]) = hb[r];
      outp[r * (2 * HID)] = hv[r];          // imm offsets 0/2048/4096/6144 B
    }
    outp += out_stride;
    if (it == T_STEPS - 1) {
      #pragma unroll
      for (int r = 0; r < 4; ++r)
        out[hlast_base + (size_t)(rowbase + q * 4 + r) * HID + colv] = hv[r];
    }
    curoff = nxtoff;
    __syncthreads();
  }
}

// ---------------------------------------------------------------------------
// Phase 2 (safe fallback if ws too small for UT): correct but slow.
// ---------------------------------------------------------------------------
__global__ __launch_bounds__(1024) void lstm_scan_safe(
    const u16* __restrict__ xw,
    const float* __restrict__ U0, const float* __restrict__ U1,
    float* __restrict__ out)
{
  const int d  = blockIdx.x >> 2;
  const int bt = blockIdx.x & 3;
  const int tid  = threadIdx.x;
  const int w    = tid >> 6;
  const int lane = tid & 63;
  const int q    = lane >> 4;
  const int c15  = lane & 15;
  const float* __restrict__ U = d ? U1 : U0;

  bf16x8 uf[4][8];
  #pragma unroll
  for (int g = 0; g < 4; ++g) {
    const int col2 = g * 256 + w * 16 + c15;
    #pragma unroll
    for (int kf = 0; kf < 8; ++kf) {
      #pragma unroll
      for (int j = 0; j < 8; ++j)
        uf[g][kf][j] = (short)f2b(U[(size_t)(kf * 32 + q * 8 + j) * G4 + col2]);
    }
  }

  __shared__ __align__(16) u16 hbuf[2][16 * 256];
  for (int i = tid; i < 16 * 256; i += 1024) { hbuf[0][i] = 0; hbuf[1][i] = 0; }
  float cst[4] = {0.f, 0.f, 0.f, 0.f};
  __syncthreads();

  const int rowbase = bt * 16;
  const int col = w * 16 + c15;
  const size_t hlast_base = (size_t)T_STEPS * BATCH * (2 * HID) + (size_t)d * BATCH * HID;

  for (int it = 0; it < T_STEPS; ++it) {
    const int t = d ? (T_STEPS - 1 - it) : it;
    union { int4 v[2]; u16 s[16]; } xv;
    {
      const int4* xwt = (const int4*)(xw + ((((size_t)d * T_STEPS + t) * 4 + bt) * 1024 + tid) * 16);
      xv.v[0] = xwt[0]; xv.v[1] = xwt[1];
    }
    const int cur = it & 1;
    bf16x8 af[8];
    #pragma unroll
    for (int kf = 0; kf < 8; ++kf) {
      int cc = kf * 4 + q;
      int cs = (cc & 16) | ((cc ^ c15) & 15);
      af[kf] = ((const bf16x8*)hbuf[cur])[c15 * 32 + cs];
    }
    f32x4 acc[4];
    #pragma unroll
    for (int g = 0; g < 4; ++g) acc[g] = (f32x4){0.f, 0.f, 0.f, 0.f};
    #pragma unroll
    for (int kf = 0; kf < 8; ++kf)
      #pragma unroll
      for (int g = 0; g < 4; ++g)
        acc[g] = __builtin_amdgcn_mfma_f32_16x16x32_bf16(af[kf], uf[g][kf], acc[g], 0, 0, 0);

    u16 hb[4]; float hv[4];
    #pragma unroll
    for (int r = 0; r < 4; ++r) {
      float zf = acc[0][r] + b2f(xv.s[0 * 4 + r]);
      float zg = acc[1][r] + b2f(xv.s[1 * 4 + r]);
      float zi = acc[2][r] + b2f(xv.s[2 * 4 + r]);
      float zo = acc[3][r] + b2f(xv.s[3 * 4 + r]);
      float fg = sigm(zf), gg = tanh_f(zg), ig = sigm(zi), og = sigm(zo);
      float cn = cst[r] * fg + gg * ig;
      cst[r] = cn;
      hv[r] = og * tanh_f(cn);
      hb[r] = f2b(hv[r]);
    }
    const int nxt = cur ^ 1;
    #pragma unroll
    for (int r = 0; r < 4; ++r) {
      const int row = q * 4 + r;
      int cch = col >> 3;
      int cs = (cch & 16) | ((cch ^ row) & 15);
      hbuf[nxt][(row * 32 + cs) * 8 + (col & 7)] = hb[r];
      out[((size_t)t * BATCH + rowbase + row) * (2 * HID) + (size_t)d * HID + col] = hv[r];
    }
    if (it == T_STEPS - 1) {
      #pragma unroll
      for (int r = 0; r < 4; ++r)
        out[hlast_base + (size_t)(rowbase + q * 4 + r) * HID + col] = hv[r];
    }
    __syncthreads();
  }
}

extern "C" void kernel_launch(void* const* d_in, const int* in_sizes, int n_in,
                              void* d_out, int out_size, void* d_ws, size_t ws_size,
                              hipStream_t stream) {
  const float* x  = (const float*)d_in[0];
  const float* fW = (const float*)d_in[1];
  const float* fU = (const float*)d_in[2];
  const float* fb = (const float*)d_in[3];
  const float* bW = (const float*)d_in[4];
  const float* bU = (const float*)d_in[5];
  const float* bb = (const float*)d_in[6];
  u16*   xwbuf = (u16*)d_ws;
  u16*   UT    = (u16*)d_ws + XW_ELEMS;
  u16*   WT    = (u16*)d_ws + XW_ELEMS + UT_ELEMS;
  float* out   = (float*)d_out;

  const bool fast   = ws_size >= (XW_ELEMS + UT_ELEMS) * sizeof(u16);
  const bool use_v2 = ws_size >= (XW_ELEMS + UT_ELEMS + WT_ELEMS) * sizeof(u16);

  if (use_v2) {
    build_ut<<<8, 1024, 0, stream>>>(fW, bW, WT);
    xw_gemm_v2<<<512, 256, 0, stream>>>(x, WT, fb, bb, xwbuf);
  } else {
    dim3 g1(32, 32);
    xw_gemm<<<g1, 256, 0, stream>>>(x, fW, bW, fb, bb, xwbuf);
  }
  if (fast) {
    build_ut<<<8, 1024, 0, stream>>>(fU, bU, UT);
    hipFuncSetAttribute((const void*)lstm_scan_fast,
                        hipFuncAttributeMaxDynamicSharedMemorySize, 147456);
    lstm_scan_fast<<<8, 1024, 147456, stream>>>(xwbuf, UT, out);
  } else {
    lstm_scan_safe<<<8, 1024, 0, stream>>>(xwbuf, fU, bU, out);
  }
}

// Round 7
// 3870.932 us; speedup vs baseline: 1.9834x; 1.0275x over previous
//
#include <hip/hip_runtime.h>

#define T_STEPS 1024
#define BATCH   64
#define NDIM    256
#define HID     256
#define G4      1024   // 4*H

typedef short bf16x8 __attribute__((ext_vector_type(8)));
typedef float f32x4  __attribute__((ext_vector_type(4)));
typedef unsigned short u16;

#define XW_ELEMS  ((size_t)2 * T_STEPS * BATCH * G4)   // 134217728 u16 (256 MiB)
#define UT_ELEMS  ((size_t)2 * 4 * 65536)              // 524288 u16 (1 MiB)
#define XBF_ELEMS ((size_t)T_STEPS * BATCH * NDIM)     // 16777216 u16 (32 MiB)

__device__ __forceinline__ float b2f(u16 v) {
  union { unsigned u; float f; } c; c.u = ((unsigned)v) << 16; return c.f;
}
__device__ __forceinline__ u16 f2b(float f) {
  union { float f; unsigned u; } c; c.f = f;
  unsigned u = c.u;
  u += 0x7fffu + ((u >> 16) & 1u);   // round-to-nearest-even
  return (u16)(u >> 16);
}
__device__ __forceinline__ float sigm(float x) {
  float e = __expf(-x);
  return __builtin_amdgcn_rcpf(1.0f + e);
}
__device__ __forceinline__ float tanh_f(float x) {
  return 2.0f * sigm(2.0f * x) - 1.0f;
}

// ---------------------------------------------------------------------------
// build_ut: pre-transpose U (f32) into bf16 MFMA B-fragment order.
// elem idx: ((d*4+g)*65536) + ((w*8+kf)*64 + lane)*8 + j
// ---------------------------------------------------------------------------
__global__ __launch_bounds__(1024) void build_ut(
    const float* __restrict__ U0, const float* __restrict__ U1,
    u16* __restrict__ UT)
{
  const int d = blockIdx.x >> 2;
  const int g = blockIdx.x & 3;
  const float* __restrict__ U = d ? U1 : U0;
  const int w = threadIdx.x >> 6, lane = threadIdx.x & 63;
  const int q = lane >> 4, c15 = lane & 15;
  u16* dst = UT + ((size_t)d * 4 + g) * 65536;
  #pragma unroll
  for (int kf = 0; kf < 8; ++kf) {
    bf16x8 v;
    #pragma unroll
    for (int j = 0; j < 8; ++j)
      v[j] = (short)f2b(U[(size_t)(kf * 32 + q * 8 + j) * G4 + g * 256 + w * 16 + c15]);
    ((bf16x8*)dst)[((w * 8 + kf) << 6) + lane] = v;
  }
}

// ---------------------------------------------------------------------------
// x_to_frag: convert x (f32) ONCE into bf16 MFMA A-fragment order.
// Reuses the round-0 staging code verbatim (same f2b rounding, same swizzle)
// so downstream fragments are BIT-IDENTICAL to the original xw_gemm's af.
// Fragment idx (bf16x8 units): ((t*4 + wv)*8 + kf)*64 + lane
// One block per t; coalesced f32 reads, coalesced 16B/lane writes.
// ---------------------------------------------------------------------------
__global__ __launch_bounds__(256) void x_to_frag(
    const float* __restrict__ x, u16* __restrict__ xbf)
{
  const int t   = blockIdx.x;
  const int tid = threadIdx.x;
  const int wv  = tid >> 6, lane = tid & 63;
  const int q   = lane >> 4, c15 = lane & 15;
  __shared__ __align__(16) u16 Alds[64 * 256];

  const float* xt = x + (size_t)t * BATCH * NDIM;
  #pragma unroll
  for (int i = 0; i < 8; ++i) {
    int g = tid + 256 * i;
    int r = g >> 5, c = g & 31;
    const float* src = xt + r * 256 + c * 8;
    bf16x8 v;
    #pragma unroll
    for (int j = 0; j < 8; ++j) v[j] = (short)f2b(src[j]);
    int cs = (c & 16) | ((c ^ (r & 15)) & 15);
    ((bf16x8*)Alds)[r * 32 + cs] = v;
  }
  __syncthreads();

  const int arow = wv * 16 + c15;
  #pragma unroll
  for (int kf = 0; kf < 8; ++kf) {
    int c = kf * 4 + q;
    int cs = (c & 16) | ((c ^ c15) & 15);
    bf16x8 v = ((const bf16x8*)Alds)[arow * 32 + cs];
    ((bf16x8*)xbf)[(((size_t)t * 4 + wv) * 8 + kf) * 64 + lane] = v;
  }
}

// ---------------------------------------------------------------------------
// Phase 1 v3: xw = x @ W_d + b_d from PRE-FRAGMENTED x (xbf).
// Structure: W in registers (round-0 style, loaded once per block), x streamed
// 128 B/thread/iter (vs v2's 512 B W-stream that regressed). No LDS, no
// barriers, no per-t staging VALU. Explicit 2-buffer prefetch: af loads for
// t+1 are issued BEFORE the MFMAs of t, and stores come LAST, so the counted
// vmcnt wait for a buffer never has to drain stores (vmcnt is ordered).
// x traffic: 1 GB bf16 from L3 (was 2 GB f32). Output bit-identical.
// ---------------------------------------------------------------------------
__global__ __launch_bounds__(256, 2) void xw_gemm_v3(
    const u16* __restrict__ xbf,
    const float* __restrict__ W0, const float* __restrict__ W1,
    const float* __restrict__ b0, const float* __restrict__ b1,
    u16* __restrict__ xw)
{
  const int d  = blockIdx.y >> 4;
  const int n0 = (blockIdx.y & 15) * 64;
  const int t0 = blockIdx.x * 32;
  const float* __restrict__ W    = d ? W1 : W0;
  const float* __restrict__ bias = d ? b1 : b0;
  const int lane = threadIdx.x & 63;
  const int wv   = threadIdx.x >> 6;
  const int q    = lane >> 4;
  const int c15  = lane & 15;

  bf16x8 uf[4][8];
  #pragma unroll
  for (int ct = 0; ct < 4; ++ct) {
    const int col = n0 + ct * 16 + c15;
    #pragma unroll
    for (int kf = 0; kf < 8; ++kf) {
      #pragma unroll
      for (int j = 0; j < 8; ++j)
        uf[ct][kf][j] = (short)f2b(W[(size_t)(kf * 32 + q * 8 + j) * G4 + col]);
    }
  }
  float bc[4];
  #pragma unroll
  for (int ct = 0; ct < 4; ++ct) bc[ct] = bias[n0 + ct * 16 + c15];

  const bf16x8* __restrict__ xb = (const bf16x8*)xbf;
  // af fragment index for (t, kf): ((t*4 + wv)*8 + kf)*64 + lane
  const size_t wvl = (size_t)wv * 8 * 64 + lane;
  #define AFIDX(t, kf) (((size_t)(t) * 32 + (kf)) * 64 + wvl)

  bf16x8 afA[8], afB[8];
  #pragma unroll
  for (int kf = 0; kf < 8; ++kf) afA[kf] = xb[AFIDX(t0, kf)];

  for (int tt = t0; tt < t0 + 32; tt += 2) {
    // issue NEXT buffer loads first (prefetch distance = 1 t)
    #pragma unroll
    for (int kf = 0; kf < 8; ++kf) afB[kf] = xb[AFIDX(tt + 1, kf)];

    {
      f32x4 acc[4];
      #pragma unroll
      for (int ct = 0; ct < 4; ++ct) acc[ct] = (f32x4){0.f, 0.f, 0.f, 0.f};
      #pragma unroll
      for (int kf = 0; kf < 8; ++kf) {
        #pragma unroll
        for (int ct = 0; ct < 4; ++ct)
          acc[ct] = __builtin_amdgcn_mfma_f32_16x16x32_bf16(afA[kf], uf[ct][kf], acc[ct], 0, 0, 0);
      }
      u16* dst = xw + (((size_t)d * T_STEPS + tt) * 4 + wv) * 16384;
      #pragma unroll
      for (int ct = 0; ct < 4; ++ct) {
        int ncol = n0 + ct * 16;
        int g2 = ncol >> 8, w2 = (ncol >> 4) & 15;
        union { u16 s[4]; uint2 v; } pk;
        #pragma unroll
        for (int r = 0; r < 4; ++r) pk.s[r] = f2b(acc[ct][r] + bc[ct]);
        *(uint2*)(dst + (size_t)(w2 * 64 + q * 16 + c15) * 16 + g2 * 4) = pk.v;
      }
    }

    if (tt + 2 < t0 + 32) {
      #pragma unroll
      for (int kf = 0; kf < 8; ++kf) afA[kf] = xb[AFIDX(tt + 2, kf)];
    }

    {
      f32x4 acc[4];
      #pragma unroll
      for (int ct = 0; ct < 4; ++ct) acc[ct] = (f32x4){0.f, 0.f, 0.f, 0.f};
      #pragma unroll
      for (int kf = 0; kf < 8; ++kf) {
        #pragma unroll
        for (int ct = 0; ct < 4; ++ct)
          acc[ct] = __builtin_amdgcn_mfma_f32_16x16x32_bf16(afB[kf], uf[ct][kf], acc[ct], 0, 0, 0);
      }
      u16* dst = xw + (((size_t)d * T_STEPS + (tt + 1)) * 4 + wv) * 16384;
      #pragma unroll
      for (int ct = 0; ct < 4; ++ct) {
        int ncol = n0 + ct * 16;
        int g2 = ncol >> 8, w2 = (ncol >> 4) & 15;
        union { u16 s[4]; uint2 v; } pk;
        #pragma unroll
        for (int r = 0; r < 4; ++r) pk.s[r] = f2b(acc[ct][r] + bc[ct]);
        *(uint2*)(dst + (size_t)(w2 * 64 + q * 16 + c15) * 16 + g2 * 4) = pk.v;
      }
    }
  }
  #undef AFIDX
}

// ---------------------------------------------------------------------------
// Phase 1 fallback (round-0 kernel): used when ws lacks room for XBF.
// ---------------------------------------------------------------------------
__global__ __launch_bounds__(256, 2) void xw_gemm(
    const float* __restrict__ x,
    const float* __restrict__ W0, const float* __restrict__ W1,
    const float* __restrict__ b0, const float* __restrict__ b1,
    u16* __restrict__ xw)
{
  const int d  = blockIdx.y >> 4;
  const int n0 = (blockIdx.y & 15) * 64;
  const int t0 = blockIdx.x * 32;
  const float* __restrict__ W    = d ? W1 : W0;
  const float* __restrict__ bias = d ? b1 : b0;
  const int lane = threadIdx.x & 63;
  const int wv   = threadIdx.x >> 6;
  const int q    = lane >> 4;
  const int c15  = lane & 15;

  bf16x8 uf[4][8];
  #pragma unroll
  for (int ct = 0; ct < 4; ++ct) {
    const int col = n0 + ct * 16 + c15;
    #pragma unroll
    for (int kf = 0; kf < 8; ++kf) {
      #pragma unroll
      for (int j = 0; j < 8; ++j)
        uf[ct][kf][j] = (short)f2b(W[(size_t)(kf * 32 + q * 8 + j) * G4 + col]);
    }
  }
  float bc[4];
  #pragma unroll
  for (int ct = 0; ct < 4; ++ct) bc[ct] = bias[n0 + ct * 16 + c15];

  __shared__ __align__(16) u16 Alds[64 * 256];

  for (int t = t0; t < t0 + 32; ++t) {
    __syncthreads();
    const float* xt = x + (size_t)t * BATCH * NDIM;
    #pragma unroll
    for (int i = 0; i < 8; ++i) {
      int g = (int)threadIdx.x + 256 * i;
      int r = g >> 5, c = g & 31;
      const float* src = xt + r * 256 + c * 8;
      bf16x8 v;
      #pragma unroll
      for (int j = 0; j < 8; ++j) v[j] = (short)f2b(src[j]);
      int cs = (c & 16) | ((c ^ (r & 15)) & 15);
      ((bf16x8*)Alds)[r * 32 + cs] = v;
    }
    __syncthreads();

    bf16x8 af[8];
    const int arow = wv * 16 + c15;
    #pragma unroll
    for (int kf = 0; kf < 8; ++kf) {
      int c = kf * 4 + q;
      int cs = (c & 16) | ((c ^ c15) & 15);
      af[kf] = ((const bf16x8*)Alds)[arow * 32 + cs];
    }

    f32x4 acc[4];
    #pragma unroll
    for (int ct = 0; ct < 4; ++ct) acc[ct] = (f32x4){0.f, 0.f, 0.f, 0.f};
    #pragma unroll
    for (int kf = 0; kf < 8; ++kf) {
      #pragma unroll
      for (int ct = 0; ct < 4; ++ct)
        acc[ct] = __builtin_amdgcn_mfma_f32_16x16x32_bf16(af[kf], uf[ct][kf], acc[ct], 0, 0, 0);
    }

    u16* dst = xw + (((size_t)d * T_STEPS + t) * 4 + wv) * 16384;
    #pragma unroll
    for (int ct = 0; ct < 4; ++ct) {
      int ncol = n0 + ct * 16;
      int g2 = ncol >> 8, w2 = (ncol >> 4) & 15;
      union { u16 s[4]; uint2 v; } pk;
      #pragma unroll
      for (int r = 0; r < 4; ++r) pk.s[r] = f2b(acc[ct][r] + bc[ct]);
      *(uint2*)(dst + (size_t)(w2 * 64 + q * 16 + c15) * 16 + g2 * 4) = pk.v;
    }
  }
}

// ---------------------------------------------------------------------------
// Phase 2 (fast): BYTE-IDENTICAL to the round-0 3537us baseline. Rounds 2-5
// established: (a) the kf-loop/store/barrier schedule is fragile — in-flight
// stores during the kf loop poison counted vmcnt waits (vmcnt is ordered);
// (b) the scan is latency-chain-bound, not VALU-bound — the exp2 gate
// rewrite cut VALU 21% and time got WORSE by 1.3%. Do not touch this kernel.
// Dynamic LDS 147456 B: [0,16384) h ping-pong (8 KB each), [16384,..) U_i.
// ---------------------------------------------------------------------------
__global__ __launch_bounds__(1024) void lstm_scan_fast(
    const u16* __restrict__ xw, const u16* __restrict__ UT,
    float* __restrict__ out)
{
  extern __shared__ __align__(16) u16 dynlds[];
  const int d  = blockIdx.x >> 2;
  const int bt = blockIdx.x & 3;
  const int tid  = threadIdx.x;
  const int w    = tid >> 6;
  const int lane = tid & 63;
  const int q    = lane >> 4;
  const int c15  = lane & 15;

  const u16* __restrict__ UTd = UT + (size_t)d * 4 * 65536;

  // persistent register fragments for gates f(0), g(1)
  bf16x8 uf0[8], uf1[8];
  const bf16x8* UTf = (const bf16x8*)UTd;
  #pragma unroll
  for (int kf = 0; kf < 8; ++kf) {
    uf0[kf] = UTf[       ((w * 8 + kf) << 6) + lane];
    uf1[kf] = UTf[8192 + ((w * 8 + kf) << 6) + lane];
  }

  // stage i-gate into LDS + zero both h buffers
  {
    const int4* src = (const int4*)(UTd + 2 * 65536);
    int4* dstl = (int4*)(dynlds + 8192);
    for (int i = tid; i < 8192; i += 1024) dstl[i] = src[i];
    for (int i = tid; i < 8192; i += 1024) dynlds[i] = 0;
  }

  const int4* __restrict__ Uo4 = (const int4*)(UTd + 3 * 65536);
  const int obase = (w << 9) | lane;
  const char* uib_base = (const char*)(dynlds + 8192) + (size_t)obase * 16;  // +kf*1024 imm

  // precomputed LDS byte offsets; h buffer selected by XOR 8192
  int afo[8];
  #pragma unroll
  for (int kf = 0; kf < 8; ++kf) {
    int cc = kf * 4 + q;
    int cs = (cc & 16) | ((cc ^ c15) & 15);
    afo[kf] = (c15 * 32 + cs) * 16;
  }
  const int colv = w * 16 + c15;
  int hwo[4];
  #pragma unroll
  for (int r = 0; r < 4; ++r) {
    int row = q * 4 + r;
    int cch = colv >> 3;
    int cs = (cch & 16) | ((cch ^ row) & 15);
    hwo[r] = ((row * 32 + cs) * 8 + (colv & 7)) * 2;
  }

  float cst[4] = {0.f, 0.f, 0.f, 0.f};
  __syncthreads();

  const int rowbase = bt * 16;
  const size_t hlast_base = (size_t)T_STEPS * BATCH * (2 * HID) + (size_t)d * BATCH * HID;
  const int t_first = d ? (T_STEPS - 1) : 0;

  // xw walking pointer; prefetch step 0
  const long xw_stride = d ? -(long)(4 * 16384) : (long)(4 * 16384);
  const u16* xwp = xw + (((size_t)d * T_STEPS + t_first) * 4 + bt) * 16384 + (size_t)tid * 16;
  union I4x2 { int4 v[2]; u16 s[16]; };
  I4x2 xn;
  xn.v[0] = ((const int4*)xwp)[0];
  xn.v[1] = ((const int4*)xwp)[1];
  xwp += xw_stride;

  // o-gate rolling L2 stream (persistent across the step boundary)
  int4 ofr[3];
  ofr[0] = Uo4[obase];
  ofr[1] = Uo4[obase + 64];

  // out walking pointer
  float* outp = out + (size_t)(t_first * BATCH + rowbase + q * 4) * (2 * HID)
              + (size_t)d * HID + colv;
  const long out_stride = d ? -(long)(BATCH * 2 * HID) : (long)(BATCH * 2 * HID);

  int curoff = 0;
  for (int it = 0; it < T_STEPS; ++it) {
    // seed accumulators with current step's pre-activations
    f32x4 acc0 = { b2f(xn.s[0]),  b2f(xn.s[1]),  b2f(xn.s[2]),  b2f(xn.s[3])  };
    f32x4 acc1 = { b2f(xn.s[4]),  b2f(xn.s[5]),  b2f(xn.s[6]),  b2f(xn.s[7])  };
    f32x4 acc2 = { b2f(xn.s[8]),  b2f(xn.s[9]),  b2f(xn.s[10]), b2f(xn.s[11]) };
    f32x4 acc3 = { b2f(xn.s[12]), b2f(xn.s[13]), b2f(xn.s[14]), b2f(xn.s[15]) };

    // prefetch next step's xw (hidden under this step's MFMA+gates)
    if (it + 1 < T_STEPS) {
      xn.v[0] = ((const int4*)xwp)[0];
      xn.v[1] = ((const int4*)xwp)[1];
      xwp += xw_stride;
    }

    const char* hcb = (const char*)dynlds + curoff;
    bf16x8 afb[2], uib[2];
    afb[0] = *(const bf16x8*)(hcb + afo[0]);
    uib[0] = *(const bf16x8*)(uib_base);
    #pragma unroll
    for (int kf = 0; kf < 8; ++kf) {
      if (kf < 7) {
        afb[(kf + 1) & 1] = *(const bf16x8*)(hcb + afo[kf + 1]);
        uib[(kf + 1) & 1] = *(const bf16x8*)(uib_base + (kf + 1) * 1024);
      }
      if (kf < 6) ofr[(kf + 2) % 3] = Uo4[obase + ((kf + 2) << 6)];
      bf16x8 af = afb[kf & 1];
      union { int4 v; bf16x8 b; } oc; oc.v = ofr[kf % 3];
      acc0 = __builtin_amdgcn_mfma_f32_16x16x32_bf16(af, uf0[kf],     acc0, 0, 0, 0);
      acc1 = __builtin_amdgcn_mfma_f32_16x16x32_bf16(af, uf1[kf],     acc1, 0, 0, 0);
      acc2 = __builtin_amdgcn_mfma_f32_16x16x32_bf16(af, uib[kf & 1], acc2, 0, 0, 0);
      acc3 = __builtin_amdgcn_mfma_f32_16x16x32_bf16(af, oc.b,        acc3, 0, 0, 0);
    }
    // refill o-stream head for NEXT step now; latency hides under the gates
    ofr[0] = Uo4[obase];
    ofr[1] = Uo4[obase + 64];

    u16 hb[4]; float hv[4];
    #pragma unroll
    for (int r = 0; r < 4; ++r) {
      float fg = sigm(acc0[r]);
      float gg = tanh_f(acc1[r]);
      float ig = sigm(acc2[r]);
      float og = sigm(acc3[r]);
      float cn = cst[r] * fg + gg * ig;
      cst[r] = cn;
      hv[r] = og * tanh_f(cn);
      hb[r] = f2b(hv[r]);
    }

    const int nxtoff = curoff ^ 8192;
    char* hwp = (char*)dynlds + nxtoff;
    #pragma unroll
    for (int r = 0; r < 4; ++r) {
      *(u16*)(hwp + hwo[r]) = hb[r];
      outp[r * (2 * HID)] = hv[r];          // imm offsets 0/2048/4096/6144 B
    }
    outp += out_stride;
    if (it == T_STEPS - 1) {
      #pragma unroll
      for (int r = 0; r < 4; ++r)
        out[hlast_base + (size_t)(rowbase + q * 4 + r) * HID + colv] = hv[r];
    }
    curoff = nxtoff;
    __syncthreads();
  }
}

// ---------------------------------------------------------------------------
// Phase 2 (safe fallback if ws too small for UT): correct but slow.
// ---------------------------------------------------------------------------
__global__ __launch_bounds__(1024) void lstm_scan_safe(
    const u16* __restrict__ xw,
    const float* __restrict__ U0, const float* __restrict__ U1,
    float* __restrict__ out)
{
  const int d  = blockIdx.x >> 2;
  const int bt = blockIdx.x & 3;
  const int tid  = threadIdx.x;
  const int w    = tid >> 6;
  const int lane = tid & 63;
  const int q    = lane >> 4;
  const int c15  = lane & 15;
  const float* __restrict__ U = d ? U1 : U0;

  bf16x8 uf[4][8];
  #pragma unroll
  for (int g = 0; g < 4; ++g) {
    const int col2 = g * 256 + w * 16 + c15;
    #pragma unroll
    for (int kf = 0; kf < 8; ++kf) {
      #pragma unroll
      for (int j = 0; j < 8; ++j)
        uf[g][kf][j] = (short)f2b(U[(size_t)(kf * 32 + q * 8 + j) * G4 + col2]);
    }
  }

  __shared__ __align__(16) u16 hbuf[2][16 * 256];
  for (int i = tid; i < 16 * 256; i += 1024) { hbuf[0][i] = 0; hbuf[1][i] = 0; }
  float cst[4] = {0.f, 0.f, 0.f, 0.f};
  __syncthreads();

  const int rowbase = bt * 16;
  const int col = w * 16 + c15;
  const size_t hlast_base = (size_t)T_STEPS * BATCH * (2 * HID) + (size_t)d * BATCH * HID;

  for (int it = 0; it < T_STEPS; ++it) {
    const int t = d ? (T_STEPS - 1 - it) : it;
    union { int4 v[2]; u16 s[16]; } xv;
    {
      const int4* xwt = (const int4*)(xw + ((((size_t)d * T_STEPS + t) * 4 + bt) * 1024 + tid) * 16);
      xv.v[0] = xwt[0]; xv.v[1] = xwt[1];
    }
    const int cur = it & 1;
    bf16x8 af[8];
    #pragma unroll
    for (int kf = 0; kf < 8; ++kf) {
      int cc = kf * 4 + q;
      int cs = (cc & 16) | ((cc ^ c15) & 15);
      af[kf] = ((const bf16x8*)hbuf[cur])[c15 * 32 + cs];
    }
    f32x4 acc[4];
    #pragma unroll
    for (int g = 0; g < 4; ++g) acc[g] = (f32x4){0.f, 0.f, 0.f, 0.f};
    #pragma unroll
    for (int kf = 0; kf < 8; ++kf)
      #pragma unroll
      for (int g = 0; g < 4; ++g)
        acc[g] = __builtin_amdgcn_mfma_f32_16x16x32_bf16(af[kf], uf[g][kf], acc[g], 0, 0, 0);

    u16 hb[4]; float hv[4];
    #pragma unroll
    for (int r = 0; r < 4; ++r) {
      float zf = acc[0][r] + b2f(xv.s[0 * 4 + r]);
      float zg = acc[1][r] + b2f(xv.s[1 * 4 + r]);
      float zi = acc[2][r] + b2f(xv.s[2 * 4 + r]);
      float zo = acc[3][r] + b2f(xv.s[3 * 4 + r]);
      float fg = sigm(zf), gg = tanh_f(zg), ig = sigm(zi), og = sigm(zo);
      float cn = cst[r] * fg + gg * ig;
      cst[r] = cn;
      hv[r] = og * tanh_f(cn);
      hb[r] = f2b(hv[r]);
    }
    const int nxt = cur ^ 1;
    #pragma unroll
    for (int r = 0; r < 4; ++r) {
      const int row = q * 4 + r;
      int cch = col >> 3;
      int cs = (cch & 16) | ((cch ^ row) & 15);
      hbuf[nxt][(row * 32 + cs) * 8 + (col & 7)] = hb[r];
      out[((size_t)t * BATCH + rowbase + row) * (2 * HID) + (size_t)d * HID + col] = hv[r];
    }
    if (it == T_STEPS - 1) {
      #pragma unroll
      for (int r = 0; r < 4; ++r)
        out[hlast_base + (size_t)(rowbase + q * 4 + r) * HID + col] = hv[r];
    }
    __syncthreads();
  }
}

extern "C" void kernel_launch(void* const* d_in, const int* in_sizes, int n_in,
                              void* d_out, int out_size, void* d_ws, size_t ws_size,
                              hipStream_t stream) {
  const float* x  = (const float*)d_in[0];
  const float* fW = (const float*)d_in[1];
  const float* fU = (const float*)d_in[2];
  const float* fb = (const float*)d_in[3];
  const float* bW = (const float*)d_in[4];
  const float* bU = (const float*)d_in[5];
  const float* bb = (const float*)d_in[6];
  u16*   xwbuf = (u16*)d_ws;
  u16*   UT    = (u16*)d_ws + XW_ELEMS;
  u16*   XBF   = (u16*)d_ws + XW_ELEMS + UT_ELEMS;
  float* out   = (float*)d_out;

  const bool fast   = ws_size >= (XW_ELEMS + UT_ELEMS) * sizeof(u16);
  const bool use_v3 = ws_size >= (XW_ELEMS + UT_ELEMS + XBF_ELEMS) * sizeof(u16);

  if (use_v3) {
    x_to_frag<<<1024, 256, 0, stream>>>(x, XBF);
    dim3 g1(32, 32);
    xw_gemm_v3<<<g1, 256, 0, stream>>>(XBF, fW, bW, fb, bb, xwbuf);
  } else {
    dim3 g1(32, 32);
    xw_gemm<<<g1, 256, 0, stream>>>(x, fW, bW, fb, bb, xwbuf);
  }
  if (fast) {
    build_ut<<<8, 1024, 0, stream>>>(fU, bU, UT);
    hipFuncSetAttribute((const void*)lstm_scan_fast,
                        hipFuncAttributeMaxDynamicSharedMemorySize, 147456);
    lstm_scan_fast<<<8, 1024, 147456, stream>>>(xwbuf, UT, out);
  } else {
    lstm_scan_safe<<<8, 1024, 0, stream>>>(xwbuf, fU, bU, out);
  }
}

// Round 8
// 3784.937 us; speedup vs baseline: 2.0284x; 1.0227x over previous
//
#include <hip/hip_runtime.h>

#define T_STEPS 1024
#define BATCH   64
#define NDIM    256
#define HID     256
#define G4      1024   // 4*H

typedef short bf16x8 __attribute__((ext_vector_type(8)));
typedef float f32x4  __attribute__((ext_vector_type(4)));
typedef unsigned short u16;

#define XW_ELEMS  ((size_t)2 * T_STEPS * BATCH * G4)   // 134217728 u16 (256 MiB)
#define UT_ELEMS  ((size_t)2 * 4 * 65536)              // 524288 u16 (1 MiB)
#define XBF_ELEMS ((size_t)T_STEPS * BATCH * NDIM)     // 16777216 u16 (32 MiB)

__device__ __forceinline__ float b2f(u16 v) {
  union { unsigned u; float f; } c; c.u = ((unsigned)v) << 16; return c.f;
}
__device__ __forceinline__ u16 f2b(float f) {
  union { float f; unsigned u; } c; c.f = f;
  unsigned u = c.u;
  u += 0x7fffu + ((u >> 16) & 1u);   // round-to-nearest-even
  return (u16)(u >> 16);
}
__device__ __forceinline__ float sigm(float x) {
  float e = __expf(-x);
  return __builtin_amdgcn_rcpf(1.0f + e);
}
__device__ __forceinline__ float tanh_f(float x) {
  return 2.0f * sigm(2.0f * x) - 1.0f;
}

// ---------------------------------------------------------------------------
// build_ut: pre-transpose U (f32) into bf16 MFMA B-fragment order.
// elem idx: ((d*4+g)*65536) + ((w*8+kf)*64 + lane)*8 + j
// ---------------------------------------------------------------------------
__global__ __launch_bounds__(1024) void build_ut(
    const float* __restrict__ U0, const float* __restrict__ U1,
    u16* __restrict__ UT)
{
  const int d = blockIdx.x >> 2;
  const int g = blockIdx.x & 3;
  const float* __restrict__ U = d ? U1 : U0;
  const int w = threadIdx.x >> 6, lane = threadIdx.x & 63;
  const int q = lane >> 4, c15 = lane & 15;
  u16* dst = UT + ((size_t)d * 4 + g) * 65536;
  #pragma unroll
  for (int kf = 0; kf < 8; ++kf) {
    bf16x8 v;
    #pragma unroll
    for (int j = 0; j < 8; ++j)
      v[j] = (short)f2b(U[(size_t)(kf * 32 + q * 8 + j) * G4 + g * 256 + w * 16 + c15]);
    ((bf16x8*)dst)[((w * 8 + kf) << 6) + lane] = v;
  }
}

// ---------------------------------------------------------------------------
// x_to_frag: convert x (f32) ONCE into bf16 MFMA A-fragment order.
// Reuses the round-0 staging code verbatim (same f2b rounding, same swizzle)
// so downstream fragments are BIT-IDENTICAL to the original xw_gemm's af.
// Fragment idx (bf16x8 units): ((t*4 + wv)*8 + kf)*64 + lane
// ---------------------------------------------------------------------------
__global__ __launch_bounds__(256) void x_to_frag(
    const float* __restrict__ x, u16* __restrict__ xbf)
{
  const int t   = blockIdx.x;
  const int tid = threadIdx.x;
  const int wv  = tid >> 6, lane = tid & 63;
  const int q   = lane >> 4, c15 = lane & 15;
  __shared__ __align__(16) u16 Alds[64 * 256];

  const float* xt = x + (size_t)t * BATCH * NDIM;
  #pragma unroll
  for (int i = 0; i < 8; ++i) {
    int g = tid + 256 * i;
    int r = g >> 5, c = g & 31;
    const float* src = xt + r * 256 + c * 8;
    bf16x8 v;
    #pragma unroll
    for (int j = 0; j < 8; ++j) v[j] = (short)f2b(src[j]);
    int cs = (c & 16) | ((c ^ (r & 15)) & 15);
    ((bf16x8*)Alds)[r * 32 + cs] = v;
  }
  __syncthreads();

  const int arow = wv * 16 + c15;
  #pragma unroll
  for (int kf = 0; kf < 8; ++kf) {
    int c = kf * 4 + q;
    int cs = (c & 16) | ((c ^ c15) & 15);
    bf16x8 v = ((const bf16x8*)Alds)[arow * 32 + cs];
    ((bf16x8*)xbf)[(((size_t)t * 4 + wv) * 8 + kf) * 64 + lane] = v;
  }
}

// ---------------------------------------------------------------------------
// Phase 1 v4: xw = x @ W_d + b_d from PRE-FRAGMENTED x (xbf), GATE-MAJOR
// column tiling for COALESCED stores.
// Round-7 diagnosis: v2/v3/round-0 all plateaued at ~330-370us because each
// thread stored 4x 8B at 32B stride, and the 4 gates of one 32B unit were
// produced by 4 DIFFERENT blocks (different XCDs) -> no L2 merge -> ~4x HBM
// write amplification on the 268MB xw buffer. Fix: ct indexes the GATE
// (cols ct*256 + hw*16 + c15), so each thread produces its full 16-u16
// [gate][r] unit -> two dense 16B stores; a wave writes 2KB contiguous.
// Same MFMA chains on same operands -> output BIT-IDENTICAL.
// W in registers; x streamed with 2-buffer prefetch (loads first, stores
// last so counted vmcnt waits never drain stores).
// ---------------------------------------------------------------------------
__global__ __launch_bounds__(256, 2) void xw_gemm_v4(
    const u16* __restrict__ xbf,
    const float* __restrict__ W0, const float* __restrict__ W1,
    const float* __restrict__ b0, const float* __restrict__ b1,
    u16* __restrict__ xw)
{
  const int d  = blockIdx.y >> 4;
  const int hw = blockIdx.y & 15;          // h-col window [hw*16, hw*16+16)
  const int t0 = blockIdx.x * 32;
  const float* __restrict__ W    = d ? W1 : W0;
  const float* __restrict__ bias = d ? b1 : b0;
  const int lane = threadIdx.x & 63;
  const int wv   = threadIdx.x >> 6;
  const int q    = lane >> 4;
  const int c15  = lane & 15;

  // uf[ct] = gate ct's 16-col W tile for this h-window (128 VGPRs)
  bf16x8 uf[4][8];
  float bc[4];
  #pragma unroll
  for (int ct = 0; ct < 4; ++ct) {
    const int col = ct * 256 + hw * 16 + c15;
    #pragma unroll
    for (int kf = 0; kf < 8; ++kf) {
      #pragma unroll
      for (int j = 0; j < 8; ++j)
        uf[ct][kf][j] = (short)f2b(W[(size_t)(kf * 32 + q * 8 + j) * G4 + col]);
    }
    bc[ct] = bias[col];
  }

  const bf16x8* __restrict__ xb = (const bf16x8*)xbf;
  const size_t wvl = (size_t)wv * 8 * 64 + lane;
  #define AFIDX(t, kf) (((size_t)(t) * 32 + (kf)) * 64 + wvl)
  // store unit (16 u16 = 32B) index: ((d*T+t)*4 + wv)*1024 + hw*64 + q*16 + c15
  const size_t sunit = (size_t)hw * 64 + q * 16 + c15;

  bf16x8 afA[8], afB[8];
  #pragma unroll
  for (int kf = 0; kf < 8; ++kf) afA[kf] = xb[AFIDX(t0, kf)];

  for (int tt = t0; tt < t0 + 32; tt += 2) {
    // issue NEXT buffer loads first (prefetch distance = 1 t)
    #pragma unroll
    for (int kf = 0; kf < 8; ++kf) afB[kf] = xb[AFIDX(tt + 1, kf)];

    {
      f32x4 acc[4];
      #pragma unroll
      for (int ct = 0; ct < 4; ++ct) acc[ct] = (f32x4){0.f, 0.f, 0.f, 0.f};
      #pragma unroll
      for (int kf = 0; kf < 8; ++kf) {
        #pragma unroll
        for (int ct = 0; ct < 4; ++ct)
          acc[ct] = __builtin_amdgcn_mfma_f32_16x16x32_bf16(afA[kf], uf[ct][kf], acc[ct], 0, 0, 0);
      }
      union { u16 s[16]; int4 v4[2]; } pk;
      #pragma unroll
      for (int ct = 0; ct < 4; ++ct)
        #pragma unroll
        for (int r = 0; r < 4; ++r) pk.s[ct * 4 + r] = f2b(acc[ct][r] + bc[ct]);
      u16* dst = xw + ((((size_t)d * T_STEPS + tt) * 4 + wv) * 1024 + sunit) * 16;
      ((int4*)dst)[0] = pk.v4[0];
      ((int4*)dst)[1] = pk.v4[1];
    }

    if (tt + 2 < t0 + 32) {
      #pragma unroll
      for (int kf = 0; kf < 8; ++kf) afA[kf] = xb[AFIDX(tt + 2, kf)];
    }

    {
      f32x4 acc[4];
      #pragma unroll
      for (int ct = 0; ct < 4; ++ct) acc[ct] = (f32x4){0.f, 0.f, 0.f, 0.f};
      #pragma unroll
      for (int kf = 0; kf < 8; ++kf) {
        #pragma unroll
        for (int ct = 0; ct < 4; ++ct)
          acc[ct] = __builtin_amdgcn_mfma_f32_16x16x32_bf16(afB[kf], uf[ct][kf], acc[ct], 0, 0, 0);
      }
      union { u16 s[16]; int4 v4[2]; } pk;
      #pragma unroll
      for (int ct = 0; ct < 4; ++ct)
        #pragma unroll
        for (int r = 0; r < 4; ++r) pk.s[ct * 4 + r] = f2b(acc[ct][r] + bc[ct]);
      u16* dst = xw + ((((size_t)d * T_STEPS + (tt + 1)) * 4 + wv) * 1024 + sunit) * 16;
      ((int4*)dst)[0] = pk.v4[0];
      ((int4*)dst)[1] = pk.v4[1];
    }
  }
  #undef AFIDX
}

// ---------------------------------------------------------------------------
// Phase 1 fallback (round-0 kernel): used when ws lacks room for XBF.
// ---------------------------------------------------------------------------
__global__ __launch_bounds__(256, 2) void xw_gemm(
    const float* __restrict__ x,
    const float* __restrict__ W0, const float* __restrict__ W1,
    const float* __restrict__ b0, const float* __restrict__ b1,
    u16* __restrict__ xw)
{
  const int d  = blockIdx.y >> 4;
  const int n0 = (blockIdx.y & 15) * 64;
  const int t0 = blockIdx.x * 32;
  const float* __restrict__ W    = d ? W1 : W0;
  const float* __restrict__ bias = d ? b1 : b0;
  const int lane = threadIdx.x & 63;
  const int wv   = threadIdx.x >> 6;
  const int q    = lane >> 4;
  const int c15  = lane & 15;

  bf16x8 uf[4][8];
  #pragma unroll
  for (int ct = 0; ct < 4; ++ct) {
    const int col = n0 + ct * 16 + c15;
    #pragma unroll
    for (int kf = 0; kf < 8; ++kf) {
      #pragma unroll
      for (int j = 0; j < 8; ++j)
        uf[ct][kf][j] = (short)f2b(W[(size_t)(kf * 32 + q * 8 + j) * G4 + col]);
    }
  }
  float bc[4];
  #pragma unroll
  for (int ct = 0; ct < 4; ++ct) bc[ct] = bias[n0 + ct * 16 + c15];

  __shared__ __align__(16) u16 Alds[64 * 256];

  for (int t = t0; t < t0 + 32; ++t) {
    __syncthreads();
    const float* xt = x + (size_t)t * BATCH * NDIM;
    #pragma unroll
    for (int i = 0; i < 8; ++i) {
      int g = (int)threadIdx.x + 256 * i;
      int r = g >> 5, c = g & 31;
      const float* src = xt + r * 256 + c * 8;
      bf16x8 v;
      #pragma unroll
      for (int j = 0; j < 8; ++j) v[j] = (short)f2b(src[j]);
      int cs = (c & 16) | ((c ^ (r & 15)) & 15);
      ((bf16x8*)Alds)[r * 32 + cs] = v;
    }
    __syncthreads();

    bf16x8 af[8];
    const int arow = wv * 16 + c15;
    #pragma unroll
    for (int kf = 0; kf < 8; ++kf) {
      int c = kf * 4 + q;
      int cs = (c & 16) | ((c ^ c15) & 15);
      af[kf] = ((const bf16x8*)Alds)[arow * 32 + cs];
    }

    f32x4 acc[4];
    #pragma unroll
    for (int ct = 0; ct < 4; ++ct) acc[ct] = (f32x4){0.f, 0.f, 0.f, 0.f};
    #pragma unroll
    for (int kf = 0; kf < 8; ++kf) {
      #pragma unroll
      for (int ct = 0; ct < 4; ++ct)
        acc[ct] = __builtin_amdgcn_mfma_f32_16x16x32_bf16(af[kf], uf[ct][kf], acc[ct], 0, 0, 0);
    }

    u16* dst = xw + (((size_t)d * T_STEPS + t) * 4 + wv) * 16384;
    #pragma unroll
    for (int ct = 0; ct < 4; ++ct) {
      int ncol = n0 + ct * 16;
      int g2 = ncol >> 8, w2 = (ncol >> 4) & 15;
      union { u16 s[4]; uint2 v; } pk;
      #pragma unroll
      for (int r = 0; r < 4; ++r) pk.s[r] = f2b(acc[ct][r] + bc[ct]);
      *(uint2*)(dst + (size_t)(w2 * 64 + q * 16 + c15) * 16 + g2 * 4) = pk.v;
    }
  }
}

// ---------------------------------------------------------------------------
// Phase 2 (fast): BYTE-IDENTICAL to the round-0 3537us baseline. Rounds 2-5
// established: (a) the kf-loop/store/barrier schedule is fragile — in-flight
// stores during the kf loop poison counted vmcnt waits (vmcnt is ordered);
// (b) the scan is latency-chain-bound, not VALU-bound — the exp2 gate
// rewrite cut VALU 21% and time got WORSE by 1.3%. Do not touch this kernel.
// Dynamic LDS 147456 B: [0,16384) h ping-pong (8 KB each), [16384,..) U_i.
// ---------------------------------------------------------------------------
__global__ __launch_bounds__(1024) void lstm_scan_fast(
    const u16* __restrict__ xw, const u16* __restrict__ UT,
    float* __restrict__ out)
{
  extern __shared__ __align__(16) u16 dynlds[];
  const int d  = blockIdx.x >> 2;
  const int bt = blockIdx.x & 3;
  const int tid  = threadIdx.x;
  const int w    = tid >> 6;
  const int lane = tid & 63;
  const int q    = lane >> 4;
  const int c15  = lane & 15;

  const u16* __restrict__ UTd = UT + (size_t)d * 4 * 65536;

  // persistent register fragments for gates f(0), g(1)
  bf16x8 uf0[8], uf1[8];
  const bf16x8* UTf = (const bf16x8*)UTd;
  #pragma unroll
  for (int kf = 0; kf < 8; ++kf) {
    uf0[kf] = UTf[       ((w * 8 + kf) << 6) + lane];
    uf1[kf] = UTf[8192 + ((w * 8 + kf) << 6) + lane];
  }

  // stage i-gate into LDS + zero both h buffers
  {
    const int4* src = (const int4*)(UTd + 2 * 65536);
    int4* dstl = (int4*)(dynlds + 8192);
    for (int i = tid; i < 8192; i += 1024) dstl[i] = src[i];
    for (int i = tid; i < 8192; i += 1024) dynlds[i] = 0;
  }

  const int4* __restrict__ Uo4 = (const int4*)(UTd + 3 * 65536);
  const int obase = (w << 9) | lane;
  const char* uib_base = (const char*)(dynlds + 8192) + (size_t)obase * 16;  // +kf*1024 imm

  // precomputed LDS byte offsets; h buffer selected by XOR 8192
  int afo[8];
  #pragma unroll
  for (int kf = 0; kf < 8; ++kf) {
    int cc = kf * 4 + q;
    int cs = (cc & 16) | ((cc ^ c15) & 15);
    afo[kf] = (c15 * 32 + cs) * 16;
  }
  const int colv = w * 16 + c15;
  int hwo[4];
  #pragma unroll
  for (int r = 0; r < 4; ++r) {
    int row = q * 4 + r;
    int cch = colv >> 3;
    int cs = (cch & 16) | ((cch ^ row) & 15);
    hwo[r] = ((row * 32 + cs) * 8 + (colv & 7)) * 2;
  }

  float cst[4] = {0.f, 0.f, 0.f, 0.f};
  __syncthreads();

  const int rowbase = bt * 16;
  const size_t hlast_base = (size_t)T_STEPS * BATCH * (2 * HID) + (size_t)d * BATCH * HID;
  const int t_first = d ? (T_STEPS - 1) : 0;

  // xw walking pointer; prefetch step 0
  const long xw_stride = d ? -(long)(4 * 16384) : (long)(4 * 16384);
  const u16* xwp = xw + (((size_t)d * T_STEPS + t_first) * 4 + bt) * 16384 + (size_t)tid * 16;
  union I4x2 { int4 v[2]; u16 s[16]; };
  I4x2 xn;
  xn.v[0] = ((const int4*)xwp)[0];
  xn.v[1] = ((const int4*)xwp)[1];
  xwp += xw_stride;

  // o-gate rolling L2 stream (persistent across the step boundary)
  int4 ofr[3];
  ofr[0] = Uo4[obase];
  ofr[1] = Uo4[obase + 64];

  // out walking pointer
  float* outp = out + (size_t)(t_first * BATCH + rowbase + q * 4) * (2 * HID)
              + (size_t)d * HID + colv;
  const long out_stride = d ? -(long)(BATCH * 2 * HID) : (long)(BATCH * 2 * HID);

  int curoff = 0;
  for (int it = 0; it < T_STEPS; ++it) {
    // seed accumulators with current step's pre-activations
    f32x4 acc0 = { b2f(xn.s[0]),  b2f(xn.s[1]),  b2f(xn.s[2]),  b2f(xn.s[3])  };
    f32x4 acc1 = { b2f(xn.s[4]),  b2f(xn.s[5]),  b2f(xn.s[6]),  b2f(xn.s[7])  };
    f32x4 acc2 = { b2f(xn.s[8]),  b2f(xn.s[9]),  b2f(xn.s[10]), b2f(xn.s[11]) };
    f32x4 acc3 = { b2f(xn.s[12]), b2f(xn.s[13]), b2f(xn.s[14]), b2f(xn.s[15]) };

    // prefetch next step's xw (hidden under this step's MFMA+gates)
    if (it + 1 < T_STEPS) {
      xn.v[0] = ((const int4*)xwp)[0];
      xn.v[1] = ((const int4*)xwp)[1];
      xwp += xw_stride;
    }

    const char* hcb = (const char*)dynlds + curoff;
    bf16x8 afb[2], uib[2];
    afb[0] = *(const bf16x8*)(hcb + afo[0]);
    uib[0] = *(const bf16x8*)(uib_base);
    #pragma unroll
    for (int kf = 0; kf < 8; ++kf) {
      if (kf < 7) {
        afb[(kf + 1) & 1] = *(const bf16x8*)(hcb + afo[kf + 1]);
        uib[(kf + 1) & 1] = *(const bf16x8*)(uib_base + (kf + 1) * 1024);
      }
      if (kf < 6) ofr[(kf + 2) % 3] = Uo4[obase + ((kf + 2) << 6)];
      bf16x8 af = afb[kf & 1];
      union { int4 v; bf16x8 b; } oc; oc.v = ofr[kf % 3];
      acc0 = __builtin_amdgcn_mfma_f32_16x16x32_bf16(af, uf0[kf],     acc0, 0, 0, 0);
      acc1 = __builtin_amdgcn_mfma_f32_16x16x32_bf16(af, uf1[kf],     acc1, 0, 0, 0);
      acc2 = __builtin_amdgcn_mfma_f32_16x16x32_bf16(af, uib[kf & 1], acc2, 0, 0, 0);
      acc3 = __builtin_amdgcn_mfma_f32_16x16x32_bf16(af, oc.b,        acc3, 0, 0, 0);
    }
    // refill o-stream head for NEXT step now; latency hides under the gates
    ofr[0] = Uo4[obase];
    ofr[1] = Uo4[obase + 64];

    u16 hb[4]; float hv[4];
    #pragma unroll
    for (int r = 0; r < 4; ++r) {
      float fg = sigm(acc0[r]);
      float gg = tanh_f(acc1[r]);
      float ig = sigm(acc2[r]);
      float og = sigm(acc3[r]);
      float cn = cst[r] * fg + gg * ig;
      cst[r] = cn;
      hv[r] = og * tanh_f(cn);
      hb[r] = f2b(hv[r]);
    }

    const int nxtoff = curoff ^ 8192;
    char* hwp = (char*)dynlds + nxtoff;
    #pragma unroll
    for (int r = 0; r < 4; ++r) {
      *(u16*)(hwp + hwo[r]) = hb[r];
      outp[r * (2 * HID)] = hv[r];          // imm offsets 0/2048/4096/6144 B
    }
    outp += out_stride;
    if (it == T_STEPS - 1) {
      #pragma unroll
      for (int r = 0; r < 4; ++r)
        out[hlast_base + (size_t)(rowbase + q * 4 + r) * HID + colv] = hv[r];
    }
    curoff = nxtoff;
    __syncthreads();
  }
}

// ---------------------------------------------------------------------------
// Phase 2 (safe fallback if ws too small for UT): correct but slow.
// ---------------------------------------------------------------------------
__global__ __launch_bounds__(1024) void lstm_scan_safe(
    const u16* __restrict__ xw,
    const float* __restrict__ U0, const float* __restrict__ U1,
    float* __restrict__ out)
{
  const int d  = blockIdx.x >> 2;
  const int bt = blockIdx.x & 3;
  const int tid  = threadIdx.x;
  const int w    = tid >> 6;
  const int lane = tid & 63;
  const int q    = lane >> 4;
  const int c15  = lane & 15;
  const float* __restrict__ U = d ? U1 : U0;

  bf16x8 uf[4][8];
  #pragma unroll
  for (int g = 0; g < 4; ++g) {
    const int col2 = g * 256 + w * 16 + c15;
    #pragma unroll
    for (int kf = 0; kf < 8; ++kf) {
      #pragma unroll
      for (int j = 0; j < 8; ++j)
        uf[g][kf][j] = (short)f2b(U[(size_t)(kf * 32 + q * 8 + j) * G4 + col2]);
    }
  }

  __shared__ __align__(16) u16 hbuf[2][16 * 256];
  for (int i = tid; i < 16 * 256; i += 1024) { hbuf[0][i] = 0; hbuf[1][i] = 0; }
  float cst[4] = {0.f, 0.f, 0.f, 0.f};
  __syncthreads();

  const int rowbase = bt * 16;
  const int col = w * 16 + c15;
  const size_t hlast_base = (size_t)T_STEPS * BATCH * (2 * HID) + (size_t)d * BATCH * HID;

  for (int it = 0; it < T_STEPS; ++it) {
    const int t = d ? (T_STEPS - 1 - it) : it;
    union { int4 v[2]; u16 s[16]; } xv;
    {
      const int4* xwt = (const int4*)(xw + ((((size_t)d * T_STEPS + t) * 4 + bt) * 1024 + tid) * 16);
      xv.v[0] = xwt[0]; xv.v[1] = xwt[1];
    }
    const int cur = it & 1;
    bf16x8 af[8];
    #pragma unroll
    for (int kf = 0; kf < 8; ++kf) {
      int cc = kf * 4 + q;
      int cs = (cc & 16) | ((cc ^ c15) & 15);
      af[kf] = ((const bf16x8*)hbuf[cur])[c15 * 32 + cs];
    }
    f32x4 acc[4];
    #pragma unroll
    for (int g = 0; g < 4; ++g) acc[g] = (f32x4){0.f, 0.f, 0.f, 0.f};
    #pragma unroll
    for (int kf = 0; kf < 8; ++kf)
      #pragma unroll
      for (int g = 0; g < 4; ++g)
        acc[g] = __builtin_amdgcn_mfma_f32_16x16x32_bf16(af[kf], uf[g][kf], acc[g], 0, 0, 0);

    u16 hb[4]; float hv[4];
    #pragma unroll
    for (int r = 0; r < 4; ++r) {
      float zf = acc[0][r] + b2f(xv.s[0 * 4 + r]);
      float zg = acc[1][r] + b2f(xv.s[1 * 4 + r]);
      float zi = acc[2][r] + b2f(xv.s[2 * 4 + r]);
      float zo = acc[3][r] + b2f(xv.s[3 * 4 + r]);
      float fg = sigm(zf), gg = tanh_f(zg), ig = sigm(zi), og = sigm(zo);
      float cn = cst[r] * fg + gg * ig;
      cst[r] = cn;
      hv[r] = og * tanh_f(cn);
      hb[r] = f2b(hv[r]);
    }
    const int nxt = cur ^ 1;
    #pragma unroll
    for (int r = 0; r < 4; ++r) {
      const int row = q * 4 + r;
      int cch = col >> 3;
      int cs = (cch & 16) | ((cch ^ row) & 15);
      hbuf[nxt][(row * 32 + cs) * 8 + (col & 7)] = hb[r];
      out[((size_t)t * BATCH + rowbase + row) * (2 * HID) + (size_t)d * HID + col] = hv[r];
    }
    if (it == T_STEPS - 1) {
      #pragma unroll
      for (int r = 0; r < 4; ++r)
        out[hlast_base + (size_t)(rowbase + q * 4 + r) * HID + col] = hv[r];
    }
    __syncthreads();
  }
}

extern "C" void kernel_launch(void* const* d_in, const int* in_sizes, int n_in,
                              void* d_out, int out_size, void* d_ws, size_t ws_size,
                              hipStream_t stream) {
  const float* x  = (const float*)d_in[0];
  const float* fW = (const float*)d_in[1];
  const float* fU = (const float*)d_in[2];
  const float* fb = (const float*)d_in[3];
  const float* bW = (const float*)d_in[4];
  const float* bU = (const float*)d_in[5];
  const float* bb = (const float*)d_in[6];
  u16*   xwbuf = (u16*)d_ws;
  u16*   UT    = (u16*)d_ws + XW_ELEMS;
  u16*   XBF   = (u16*)d_ws + XW_ELEMS + UT_ELEMS;
  float* out   = (float*)d_out;

  const bool fast   = ws_size >= (XW_ELEMS + UT_ELEMS) * sizeof(u16);
  const bool use_v4 = ws_size >= (XW_ELEMS + UT_ELEMS + XBF_ELEMS) * sizeof(u16);

  if (use_v4) {
    x_to_frag<<<1024, 256, 0, stream>>>(x, XBF);
    dim3 g1(32, 32);
    xw_gemm_v4<<<g1, 256, 0, stream>>>(XBF, fW, bW, fb, bb, xwbuf);
  } else {
    dim3 g1(32, 32);
    xw_gemm<<<g1, 256, 0, stream>>>(x, fW, bW, fb, bb, xwbuf);
  }
  if (fast) {
    build_ut<<<8, 1024, 0, stream>>>(fU, bU, UT);
    hipFuncSetAttribute((const void*)lstm_scan_fast,
                        hipFuncAttributeMaxDynamicSharedMemorySize, 147456);
    lstm_scan_fast<<<8, 1024, 147456, stream>>>(xwbuf, UT, out);
  } else {
    lstm_scan_safe<<<8, 1024, 0, stream>>>(xwbuf, fU, bU, out);
  }
}

// Round 9
// 3355.330 us; speedup vs baseline: 2.2881x; 1.1280x over previous
//
#include <hip/hip_runtime.h>

#define T_STEPS 1024
#define BATCH   64
#define NDIM    256
#define HID     256
#define G4      1024   // 4*H

typedef short bf16x8 __attribute__((ext_vector_type(8)));
typedef float f32x4  __attribute__((ext_vector_type(4)));
typedef unsigned short u16;

#define XW_ELEMS  ((size_t)2 * T_STEPS * BATCH * G4)   // 134217728 u16 (256 MiB)
#define UT_ELEMS  ((size_t)2 * 4 * 65536)              // 524288 u16 (1 MiB)
#define XBF_ELEMS ((size_t)T_STEPS * BATCH * NDIM)     // 16777216 u16 (32 MiB)

__device__ __forceinline__ float b2f(u16 v) {
  union { unsigned u; float f; } c; c.u = ((unsigned)v) << 16; return c.f;
}
__device__ __forceinline__ u16 f2b(float f) {
  union { float f; unsigned u; } c; c.f = f;
  unsigned u = c.u;
  u += 0x7fffu + ((u >> 16) & 1u);   // round-to-nearest-even
  return (u16)(u >> 16);
}
__device__ __forceinline__ float sigm(float x) {
  float e = __expf(-x);
  return __builtin_amdgcn_rcpf(1.0f + e);
}
__device__ __forceinline__ float tanh_f(float x) {
  return 2.0f * sigm(2.0f * x) - 1.0f;
}

// ---------------------------------------------------------------------------
// build_ut: pre-transpose U (f32) into bf16 MFMA B-fragment order.
// elem idx: ((d*4+g)*65536) + ((w*8+kf)*64 + lane)*8 + j
// ---------------------------------------------------------------------------
__global__ __launch_bounds__(1024) void build_ut(
    const float* __restrict__ U0, const float* __restrict__ U1,
    u16* __restrict__ UT)
{
  const int d = blockIdx.x >> 2;
  const int g = blockIdx.x & 3;
  const float* __restrict__ U = d ? U1 : U0;
  const int w = threadIdx.x >> 6, lane = threadIdx.x & 63;
  const int q = lane >> 4, c15 = lane & 15;
  u16* dst = UT + ((size_t)d * 4 + g) * 65536;
  #pragma unroll
  for (int kf = 0; kf < 8; ++kf) {
    bf16x8 v;
    #pragma unroll
    for (int j = 0; j < 8; ++j)
      v[j] = (short)f2b(U[(size_t)(kf * 32 + q * 8 + j) * G4 + g * 256 + w * 16 + c15]);
    ((bf16x8*)dst)[((w * 8 + kf) << 6) + lane] = v;
  }
}

// ---------------------------------------------------------------------------
// x_to_frag: convert x (f32) ONCE into bf16 MFMA A-fragment order.
// Fragment idx (bf16x8 units): ((t*4 + wv)*8 + kf)*64 + lane
// ---------------------------------------------------------------------------
__global__ __launch_bounds__(256) void x_to_frag(
    const float* __restrict__ x, u16* __restrict__ xbf)
{
  const int t   = blockIdx.x;
  const int tid = threadIdx.x;
  const int wv  = tid >> 6, lane = tid & 63;
  const int q   = lane >> 4, c15 = lane & 15;
  __shared__ __align__(16) u16 Alds[64 * 256];

  const float* xt = x + (size_t)t * BATCH * NDIM;
  #pragma unroll
  for (int i = 0; i < 8; ++i) {
    int g = tid + 256 * i;
    int r = g >> 5, c = g & 31;
    const float* src = xt + r * 256 + c * 8;
    bf16x8 v;
    #pragma unroll
    for (int j = 0; j < 8; ++j) v[j] = (short)f2b(src[j]);
    int cs = (c & 16) | ((c ^ (r & 15)) & 15);
    ((bf16x8*)Alds)[r * 32 + cs] = v;
  }
  __syncthreads();

  const int arow = wv * 16 + c15;
  #pragma unroll
  for (int kf = 0; kf < 8; ++kf) {
    int c = kf * 4 + q;
    int cs = (c & 16) | ((c ^ c15) & 15);
    bf16x8 v = ((const bf16x8*)Alds)[arow * 32 + cs];
    ((bf16x8*)xbf)[(((size_t)t * 4 + wv) * 8 + kf) * 64 + lane] = v;
  }
}

// ---------------------------------------------------------------------------
// Phase 1 v4: xw = x @ W_d + b_d from PRE-FRAGMENTED x (xbf), GATE-MAJOR
// column tiling -> each thread stores its full 32B [gate][r] unit (coalesced).
// W in registers; x streamed with 2-buffer prefetch. Output bit-identical.
// ---------------------------------------------------------------------------
__global__ __launch_bounds__(256, 2) void xw_gemm_v4(
    const u16* __restrict__ xbf,
    const float* __restrict__ W0, const float* __restrict__ W1,
    const float* __restrict__ b0, const float* __restrict__ b1,
    u16* __restrict__ xw)
{
  const int d  = blockIdx.y >> 4;
  const int hw = blockIdx.y & 15;          // h-col window [hw*16, hw*16+16)
  const int t0 = blockIdx.x * 32;
  const float* __restrict__ W    = d ? W1 : W0;
  const float* __restrict__ bias = d ? b1 : b0;
  const int lane = threadIdx.x & 63;
  const int wv   = threadIdx.x >> 6;
  const int q    = lane >> 4;
  const int c15  = lane & 15;

  bf16x8 uf[4][8];
  float bc[4];
  #pragma unroll
  for (int ct = 0; ct < 4; ++ct) {
    const int col = ct * 256 + hw * 16 + c15;
    #pragma unroll
    for (int kf = 0; kf < 8; ++kf) {
      #pragma unroll
      for (int j = 0; j < 8; ++j)
        uf[ct][kf][j] = (short)f2b(W[(size_t)(kf * 32 + q * 8 + j) * G4 + col]);
    }
    bc[ct] = bias[col];
  }

  const bf16x8* __restrict__ xb = (const bf16x8*)xbf;
  const size_t wvl = (size_t)wv * 8 * 64 + lane;
  #define AFIDX(t, kf) (((size_t)(t) * 32 + (kf)) * 64 + wvl)
  const size_t sunit = (size_t)hw * 64 + q * 16 + c15;

  bf16x8 afA[8], afB[8];
  #pragma unroll
  for (int kf = 0; kf < 8; ++kf) afA[kf] = xb[AFIDX(t0, kf)];

  for (int tt = t0; tt < t0 + 32; tt += 2) {
    #pragma unroll
    for (int kf = 0; kf < 8; ++kf) afB[kf] = xb[AFIDX(tt + 1, kf)];

    {
      f32x4 acc[4];
      #pragma unroll
      for (int ct = 0; ct < 4; ++ct) acc[ct] = (f32x4){0.f, 0.f, 0.f, 0.f};
      #pragma unroll
      for (int kf = 0; kf < 8; ++kf) {
        #pragma unroll
        for (int ct = 0; ct < 4; ++ct)
          acc[ct] = __builtin_amdgcn_mfma_f32_16x16x32_bf16(afA[kf], uf[ct][kf], acc[ct], 0, 0, 0);
      }
      union { u16 s[16]; int4 v4[2]; } pk;
      #pragma unroll
      for (int ct = 0; ct < 4; ++ct)
        #pragma unroll
        for (int r = 0; r < 4; ++r) pk.s[ct * 4 + r] = f2b(acc[ct][r] + bc[ct]);
      u16* dst = xw + ((((size_t)d * T_STEPS + tt) * 4 + wv) * 1024 + sunit) * 16;
      ((int4*)dst)[0] = pk.v4[0];
      ((int4*)dst)[1] = pk.v4[1];
    }

    if (tt + 2 < t0 + 32) {
      #pragma unroll
      for (int kf = 0; kf < 8; ++kf) afA[kf] = xb[AFIDX(tt + 2, kf)];
    }

    {
      f32x4 acc[4];
      #pragma unroll
      for (int ct = 0; ct < 4; ++ct) acc[ct] = (f32x4){0.f, 0.f, 0.f, 0.f};
      #pragma unroll
      for (int kf = 0; kf < 8; ++kf) {
        #pragma unroll
        for (int ct = 0; ct < 4; ++ct)
          acc[ct] = __builtin_amdgcn_mfma_f32_16x16x32_bf16(afB[kf], uf[ct][kf], acc[ct], 0, 0, 0);
      }
      union { u16 s[16]; int4 v4[2]; } pk;
      #pragma unroll
      for (int ct = 0; ct < 4; ++ct)
        #pragma unroll
        for (int r = 0; r < 4; ++r) pk.s[ct * 4 + r] = f2b(acc[ct][r] + bc[ct]);
      u16* dst = xw + ((((size_t)d * T_STEPS + (tt + 1)) * 4 + wv) * 1024 + sunit) * 16;
      ((int4*)dst)[0] = pk.v4[0];
      ((int4*)dst)[1] = pk.v4[1];
    }
  }
  #undef AFIDX
}

// ---------------------------------------------------------------------------
// Phase 1 fallback (round-0 kernel): used when ws lacks room for XBF.
// ---------------------------------------------------------------------------
__global__ __launch_bounds__(256, 2) void xw_gemm(
    const float* __restrict__ x,
    const float* __restrict__ W0, const float* __restrict__ W1,
    const float* __restrict__ b0, const float* __restrict__ b1,
    u16* __restrict__ xw)
{
  const int d  = blockIdx.y >> 4;
  const int n0 = (blockIdx.y & 15) * 64;
  const int t0 = blockIdx.x * 32;
  const float* __restrict__ W    = d ? W1 : W0;
  const float* __restrict__ bias = d ? b1 : b0;
  const int lane = threadIdx.x & 63;
  const int wv   = threadIdx.x >> 6;
  const int q    = lane >> 4;
  const int c15  = lane & 15;

  bf16x8 uf[4][8];
  #pragma unroll
  for (int ct = 0; ct < 4; ++ct) {
    const int col = n0 + ct * 16 + c15;
    #pragma unroll
    for (int kf = 0; kf < 8; ++kf) {
      #pragma unroll
      for (int j = 0; j < 8; ++j)
        uf[ct][kf][j] = (short)f2b(W[(size_t)(kf * 32 + q * 8 + j) * G4 + col]);
    }
  }
  float bc[4];
  #pragma unroll
  for (int ct = 0; ct < 4; ++ct) bc[ct] = bias[n0 + ct * 16 + c15];

  __shared__ __align__(16) u16 Alds[64 * 256];

  for (int t = t0; t < t0 + 32; ++t) {
    __syncthreads();
    const float* xt = x + (size_t)t * BATCH * NDIM;
    #pragma unroll
    for (int i = 0; i < 8; ++i) {
      int g = (int)threadIdx.x + 256 * i;
      int r = g >> 5, c = g & 31;
      const float* src = xt + r * 256 + c * 8;
      bf16x8 v;
      #pragma unroll
      for (int j = 0; j < 8; ++j) v[j] = (short)f2b(src[j]);
      int cs = (c & 16) | ((c ^ (r & 15)) & 15);
      ((bf16x8*)Alds)[r * 32 + cs] = v;
    }
    __syncthreads();

    bf16x8 af[8];
    const int arow = wv * 16 + c15;
    #pragma unroll
    for (int kf = 0; kf < 8; ++kf) {
      int c = kf * 4 + q;
      int cs = (c & 16) | ((c ^ c15) & 15);
      af[kf] = ((const bf16x8*)Alds)[arow * 32 + cs];
    }

    f32x4 acc[4];
    #pragma unroll
    for (int ct = 0; ct < 4; ++ct) acc[ct] = (f32x4){0.f, 0.f, 0.f, 0.f};
    #pragma unroll
    for (int kf = 0; kf < 8; ++kf) {
      #pragma unroll
      for (int ct = 0; ct < 4; ++ct)
        acc[ct] = __builtin_amdgcn_mfma_f32_16x16x32_bf16(af[kf], uf[ct][kf], acc[ct], 0, 0, 0);
    }

    u16* dst = xw + (((size_t)d * T_STEPS + t) * 4 + wv) * 16384;
    #pragma unroll
    for (int ct = 0; ct < 4; ++ct) {
      int ncol = n0 + ct * 16;
      int g2 = ncol >> 8, w2 = (ncol >> 4) & 15;
      union { u16 s[4]; uint2 v; } pk;
      #pragma unroll
      for (int r = 0; r < 4; ++r) pk.s[r] = f2b(acc[ct][r] + bc[ct]);
      *(uint2*)(dst + (size_t)(w2 * 64 + q * 16 + c15) * 16 + g2 * 4) = pk.v;
    }
  }
}

// ---------------------------------------------------------------------------
// Phase 2 (fast). Model (validated against rounds 0-5): the step is bound by
// the CU's vector-memory (L1) return path: o-stream 128 B + xw 32 B per
// thread per step = 160 KB/block/step ~ 2560 cyc at 64 B/cyc, matching the
// measured step (2740 cyc) and the VALU/MFMA busy fractions (42%/25%).
// THIS ROUND'S SINGLE CHANGE (B6): U_o's kf=0 fragment (constant, 16 KB) is
// staged once into the free LDS tail and read per-step like uib[0] -> the
// L2->L1 o-stream drops 1/8 (16 B/thread/step) and one tail refill is gone.
// All other code (kf>=1 rolling pattern, stores, barrier) byte-identical.
// Dynamic LDS 163840 B: [0,16384) h ping-pong, [16384,147456) U_i,
// [147456,163840) U_o kf=0 (one 16B slot per thread).
// ---------------------------------------------------------------------------
__global__ __launch_bounds__(1024) void lstm_scan_fast(
    const u16* __restrict__ xw, const u16* __restrict__ UT,
    float* __restrict__ out)
{
  extern __shared__ __align__(16) u16 dynlds[];
  const int d  = blockIdx.x >> 2;
  const int bt = blockIdx.x & 3;
  const int tid  = threadIdx.x;
  const int w    = tid >> 6;
  const int lane = tid & 63;
  const int q    = lane >> 4;
  const int c15  = lane & 15;

  const u16* __restrict__ UTd = UT + (size_t)d * 4 * 65536;
  const int4* __restrict__ Uo4 = (const int4*)(UTd + 3 * 65536);
  const int obase = (w << 9) | lane;

  // persistent register fragments for gates f(0), g(1)
  bf16x8 uf0[8], uf1[8];
  const bf16x8* UTf = (const bf16x8*)UTd;
  #pragma unroll
  for (int kf = 0; kf < 8; ++kf) {
    uf0[kf] = UTf[       ((w * 8 + kf) << 6) + lane];
    uf1[kf] = UTf[8192 + ((w * 8 + kf) << 6) + lane];
  }

  // stage i-gate into LDS + zero both h buffers + stage U_o kf=0 fragment
  {
    const int4* src = (const int4*)(UTd + 2 * 65536);
    int4* dstl = (int4*)(dynlds + 8192);
    for (int i = tid; i < 8192; i += 1024) dstl[i] = src[i];
    for (int i = tid; i < 8192; i += 1024) dynlds[i] = 0;
    ((int4*)(dynlds + 73728))[tid] = Uo4[obase];   // byte offset 147456
  }

  const char* uib_base = (const char*)(dynlds + 8192) + (size_t)obase * 16;  // +kf*1024 imm
  const char* o0_base  = (const char*)dynlds + 147456 + (size_t)tid * 16;

  // precomputed LDS byte offsets; h buffer selected by XOR 8192
  int afo[8];
  #pragma unroll
  for (int kf = 0; kf < 8; ++kf) {
    int cc = kf * 4 + q;
    int cs = (cc & 16) | ((cc ^ c15) & 15);
    afo[kf] = (c15 * 32 + cs) * 16;
  }
  const int colv = w * 16 + c15;
  int hwo[4];
  #pragma unroll
  for (int r = 0; r < 4; ++r) {
    int row = q * 4 + r;
    int cch = colv >> 3;
    int cs = (cch & 16) | ((cch ^ row) & 15);
    hwo[r] = ((row * 32 + cs) * 8 + (colv & 7)) * 2;
  }

  float cst[4] = {0.f, 0.f, 0.f, 0.f};
  __syncthreads();

  const int rowbase = bt * 16;
  const size_t hlast_base = (size_t)T_STEPS * BATCH * (2 * HID) + (size_t)d * BATCH * HID;
  const int t_first = d ? (T_STEPS - 1) : 0;

  // xw walking pointer; prefetch step 0
  const long xw_stride = d ? -(long)(4 * 16384) : (long)(4 * 16384);
  const u16* xwp = xw + (((size_t)d * T_STEPS + t_first) * 4 + bt) * 16384 + (size_t)tid * 16;
  union I4x2 { int4 v[2]; u16 s[16]; };
  I4x2 xn;
  xn.v[0] = ((const int4*)xwp)[0];
  xn.v[1] = ((const int4*)xwp)[1];
  xwp += xw_stride;

  // o-gate rolling L2 stream for kf>=1 (kf=0 comes from LDS)
  int4 ofr[3];
  ofr[1] = Uo4[obase + 64];

  // out walking pointer
  float* outp = out + (size_t)(t_first * BATCH + rowbase + q * 4) * (2 * HID)
              + (size_t)d * HID + colv;
  const long out_stride = d ? -(long)(BATCH * 2 * HID) : (long)(BATCH * 2 * HID);

  int curoff = 0;
  for (int it = 0; it < T_STEPS; ++it) {
    // seed accumulators with current step's pre-activations
    f32x4 acc0 = { b2f(xn.s[0]),  b2f(xn.s[1]),  b2f(xn.s[2]),  b2f(xn.s[3])  };
    f32x4 acc1 = { b2f(xn.s[4]),  b2f(xn.s[5]),  b2f(xn.s[6]),  b2f(xn.s[7])  };
    f32x4 acc2 = { b2f(xn.s[8]),  b2f(xn.s[9]),  b2f(xn.s[10]), b2f(xn.s[11]) };
    f32x4 acc3 = { b2f(xn.s[12]), b2f(xn.s[13]), b2f(xn.s[14]), b2f(xn.s[15]) };

    // prefetch next step's xw (hidden under this step's MFMA+gates)
    if (it + 1 < T_STEPS) {
      xn.v[0] = ((const int4*)xwp)[0];
      xn.v[1] = ((const int4*)xwp)[1];
      xwp += xw_stride;
    }

    const char* hcb = (const char*)dynlds + curoff;
    bf16x8 afb[2], uib[2], oc0;
    afb[0] = *(const bf16x8*)(hcb + afo[0]);
    uib[0] = *(const bf16x8*)(uib_base);
    oc0    = *(const bf16x8*)(o0_base);
    #pragma unroll
    for (int kf = 0; kf < 8; ++kf) {
      if (kf < 7) {
        afb[(kf + 1) & 1] = *(const bf16x8*)(hcb + afo[kf + 1]);
        uib[(kf + 1) & 1] = *(const bf16x8*)(uib_base + (kf + 1) * 1024);
      }
      if (kf < 6) ofr[(kf + 2) % 3] = Uo4[obase + ((kf + 2) << 6)];
      bf16x8 af = afb[kf & 1];
      bf16x8 ob;
      if (kf == 0) {
        ob = oc0;
      } else {
        union { int4 v; bf16x8 b; } oc; oc.v = ofr[kf % 3];
        ob = oc.b;
      }
      acc0 = __builtin_amdgcn_mfma_f32_16x16x32_bf16(af, uf0[kf],     acc0, 0, 0, 0);
      acc1 = __builtin_amdgcn_mfma_f32_16x16x32_bf16(af, uf1[kf],     acc1, 0, 0, 0);
      acc2 = __builtin_amdgcn_mfma_f32_16x16x32_bf16(af, uib[kf & 1], acc2, 0, 0, 0);
      acc3 = __builtin_amdgcn_mfma_f32_16x16x32_bf16(af, ob,          acc3, 0, 0, 0);
    }
    // refill o-stream kf=1 slot for NEXT step (kf=0 now served from LDS)
    ofr[1] = Uo4[obase + 64];

    u16 hb[4]; float hv[4];
    #pragma unroll
    for (int r = 0; r < 4; ++r) {
      float fg = sigm(acc0[r]);
      float gg = tanh_f(acc1[r]);
      float ig = sigm(acc2[r]);
      float og = sigm(acc3[r]);
      float cn = cst[r] * fg + gg * ig;
      cst[r] = cn;
      hv[r] = og * tanh_f(cn);
      hb[r] = f2b(hv[r]);
    }

    const int nxtoff = curoff ^ 8192;
    char* hwp = (char*)dynlds + nxtoff;
    #pragma unroll
    for (int r = 0; r < 4; ++r) {
      *(u16*)(hwp + hwo[r]) = hb[r];
      outp[r * (2 * HID)] = hv[r];          // imm offsets 0/2048/4096/6144 B
    }
    outp += out_stride;
    if (it == T_STEPS - 1) {
      #pragma unroll
      for (int r = 0; r < 4; ++r)
        out[hlast_base + (size_t)(rowbase + q * 4 + r) * HID + colv] = hv[r];
    }
    curoff = nxtoff;
    __syncthreads();
  }
}

// ---------------------------------------------------------------------------
// Phase 2 (safe fallback if ws too small for UT): correct but slow.
// ---------------------------------------------------------------------------
__global__ __launch_bounds__(1024) void lstm_scan_safe(
    const u16* __restrict__ xw,
    const float* __restrict__ U0, const float* __restrict__ U1,
    float* __restrict__ out)
{
  const int d  = blockIdx.x >> 2;
  const int bt = blockIdx.x & 3;
  const int tid  = threadIdx.x;
  const int w    = tid >> 6;
  const int lane = tid & 63;
  const int q    = lane >> 4;
  const int c15  = lane & 15;
  const float* __restrict__ U = d ? U1 : U0;

  bf16x8 uf[4][8];
  #pragma unroll
  for (int g = 0; g < 4; ++g) {
    const int col2 = g * 256 + w * 16 + c15;
    #pragma unroll
    for (int kf = 0; kf < 8; ++kf) {
      #pragma unroll
      for (int j = 0; j < 8; ++j)
        uf[g][kf][j] = (short)f2b(U[(size_t)(kf * 32 + q * 8 + j) * G4 + col2]);
    }
  }

  __shared__ __align__(16) u16 hbuf[2][16 * 256];
  for (int i = tid; i < 16 * 256; i += 1024) { hbuf[0][i] = 0; hbuf[1][i] = 0; }
  float cst[4] = {0.f, 0.f, 0.f, 0.f};
  __syncthreads();

  const int rowbase = bt * 16;
  const int col = w * 16 + c15;
  const size_t hlast_base = (size_t)T_STEPS * BATCH * (2 * HID) + (size_t)d * BATCH * HID;

  for (int it = 0; it < T_STEPS; ++it) {
    const int t = d ? (T_STEPS - 1 - it) : it;
    union { int4 v[2]; u16 s[16]; } xv;
    {
      const int4* xwt = (const int4*)(xw + ((((size_t)d * T_STEPS + t) * 4 + bt) * 1024 + tid) * 16);
      xv.v[0] = xwt[0]; xv.v[1] = xwt[1];
    }
    const int cur = it & 1;
    bf16x8 af[8];
    #pragma unroll
    for (int kf = 0; kf < 8; ++kf) {
      int cc = kf * 4 + q;
      int cs = (cc & 16) | ((cc ^ c15) & 15);
      af[kf] = ((const bf16x8*)hbuf[cur])[c15 * 32 + cs];
    }
    f32x4 acc[4];
    #pragma unroll
    for (int g = 0; g < 4; ++g) acc[g] = (f32x4){0.f, 0.f, 0.f, 0.f};
    #pragma unroll
    for (int kf = 0; kf < 8; ++kf)
      #pragma unroll
      for (int g = 0; g < 4; ++g)
        acc[g] = __builtin_amdgcn_mfma_f32_16x16x32_bf16(af[kf], uf[g][kf], acc[g], 0, 0, 0);

    u16 hb[4]; float hv[4];
    #pragma unroll
    for (int r = 0; r < 4; ++r) {
      float zf = acc[0][r] + b2f(xv.s[0 * 4 + r]);
      float zg = acc[1][r] + b2f(xv.s[1 * 4 + r]);
      float zi = acc[2][r] + b2f(xv.s[2 * 4 + r]);
      float zo = acc[3][r] + b2f(xv.s[3 * 4 + r]);
      float fg = sigm(zf), gg = tanh_f(zg), ig = sigm(zi), og = sigm(zo);
      float cn = cst[r] * fg + gg * ig;
      cst[r] = cn;
      hv[r] = og * tanh_f(cn);
      hb[r] = f2b(hv[r]);
    }
    const int nxt = cur ^ 1;
    #pragma unroll
    for (int r = 0; r < 4; ++r) {
      const int row = q * 4 + r;
      int cch = col >> 3;
      int cs = (cch & 16) | ((cch ^ row) & 15);
      hbuf[nxt][(row * 32 + cs) * 8 + (col & 7)] = hb[r];
      out[((size_t)t * BATCH + rowbase + row) * (2 * HID) + (size_t)d * HID + col] = hv[r];
    }
    if (it == T_STEPS - 1) {
      #pragma unroll
      for (int r = 0; r < 4; ++r)
        out[hlast_base + (size_t)(rowbase + q * 4 + r) * HID + col] = hv[r];
    }
    __syncthreads();
  }
}

extern "C" void kernel_launch(void* const* d_in, const int* in_sizes, int n_in,
                              void* d_out, int out_size, void* d_ws, size_t ws_size,
                              hipStream_t stream) {
  const float* x  = (const float*)d_in[0];
  const float* fW = (const float*)d_in[1];
  const float* fU = (const float*)d_in[2];
  const float* fb = (const float*)d_in[3];
  const float* bW = (const float*)d_in[4];
  const float* bU = (const float*)d_in[5];
  const float* bb = (const float*)d_in[6];
  u16*   xwbuf = (u16*)d_ws;
  u16*   UT    = (u16*)d_ws + XW_ELEMS;
  u16*   XBF   = (u16*)d_ws + XW_ELEMS + UT_ELEMS;
  float* out   = (float*)d_out;

  const bool fast   = ws_size >= (XW_ELEMS + UT_ELEMS) * sizeof(u16);
  const bool use_v4 = ws_size >= (XW_ELEMS + UT_ELEMS + XBF_ELEMS) * sizeof(u16);

  if (use_v4) {
    x_to_frag<<<1024, 256, 0, stream>>>(x, XBF);
    dim3 g1(32, 32);
    xw_gemm_v4<<<g1, 256, 0, stream>>>(XBF, fW, bW, fb, bb, xwbuf);
  } else {
    dim3 g1(32, 32);
    xw_gemm<<<g1, 256, 0, stream>>>(x, fW, bW, fb, bb, xwbuf);
  }
  if (fast) {
    build_ut<<<8, 1024, 0, stream>>>(fU, bU, UT);
    hipFuncSetAttribute((const void*)lstm_scan_fast,
                        hipFuncAttributeMaxDynamicSharedMemorySize, 163840);
    lstm_scan_fast<<<8, 1024, 163840, stream>>>(xwbuf, UT, out);
  } else {
    lstm_scan_safe<<<8, 1024, 0, stream>>>(xwbuf, fU, bU, out);
  }
}

// Round 11
// 3353.193 us; speedup vs baseline: 2.2896x; 1.0006x over previous
//
#include <hip/hip_runtime.h>

#define T_STEPS 1024
#define BATCH   64
#define NDIM    256
#define HID     256
#define G4      1024   // 4*H

typedef short bf16x8 __attribute__((ext_vector_type(8)));
typedef float f32x4  __attribute__((ext_vector_type(4)));
typedef unsigned short u16;

#define XW_ELEMS  ((size_t)2 * T_STEPS * BATCH * G4)   // 134217728 u16 (256 MiB)
#define UT_ELEMS  ((size_t)2 * 4 * 65536)              // 524288 u16 (1 MiB)
#define XBF_ELEMS ((size_t)T_STEPS * BATCH * NDIM)     // 16777216 u16 (32 MiB)

__device__ __forceinline__ float b2f(u16 v) {
  union { unsigned u; float f; } c; c.u = ((unsigned)v) << 16; return c.f;
}
__device__ __forceinline__ u16 f2b(float f) {
  union { float f; unsigned u; } c; c.f = f;
  unsigned u = c.u;
  u += 0x7fffu + ((u >> 16) & 1u);   // round-to-nearest-even
  return (u16)(u >> 16);
}
__device__ __forceinline__ float sigm(float x) {
  float e = __expf(-x);
  return __builtin_amdgcn_rcpf(1.0f + e);
}
__device__ __forceinline__ float tanh_f(float x) {
  return 2.0f * sigm(2.0f * x) - 1.0f;
}

// ---------------------------------------------------------------------------
// build_ut: pre-transpose U (f32) into bf16 MFMA B-fragment order.
// elem idx: ((d*4+g)*65536) + ((w*8+kf)*64 + lane)*8 + j
// ---------------------------------------------------------------------------
__global__ __launch_bounds__(1024) void build_ut(
    const float* __restrict__ U0, const float* __restrict__ U1,
    u16* __restrict__ UT)
{
  const int d = blockIdx.x >> 2;
  const int g = blockIdx.x & 3;
  const float* __restrict__ U = d ? U1 : U0;
  const int w = threadIdx.x >> 6, lane = threadIdx.x & 63;
  const int q = lane >> 4, c15 = lane & 15;
  u16* dst = UT + ((size_t)d * 4 + g) * 65536;
  #pragma unroll
  for (int kf = 0; kf < 8; ++kf) {
    bf16x8 v;
    #pragma unroll
    for (int j = 0; j < 8; ++j)
      v[j] = (short)f2b(U[(size_t)(kf * 32 + q * 8 + j) * G4 + g * 256 + w * 16 + c15]);
    ((bf16x8*)dst)[((w * 8 + kf) << 6) + lane] = v;
  }
}

// ---------------------------------------------------------------------------
// x_to_frag: convert x (f32) ONCE into bf16 MFMA A-fragment order.
// Fragment idx (bf16x8 units): ((t*4 + wv)*8 + kf)*64 + lane
// ---------------------------------------------------------------------------
__global__ __launch_bounds__(256) void x_to_frag(
    const float* __restrict__ x, u16* __restrict__ xbf)
{
  const int t   = blockIdx.x;
  const int tid = threadIdx.x;
  const int wv  = tid >> 6, lane = tid & 63;
  const int q   = lane >> 4, c15 = lane & 15;
  __shared__ __align__(16) u16 Alds[64 * 256];

  const float* xt = x + (size_t)t * BATCH * NDIM;
  #pragma unroll
  for (int i = 0; i < 8; ++i) {
    int g = tid + 256 * i;
    int r = g >> 5, c = g & 31;
    const float* src = xt + r * 256 + c * 8;
    bf16x8 v;
    #pragma unroll
    for (int j = 0; j < 8; ++j) v[j] = (short)f2b(src[j]);
    int cs = (c & 16) | ((c ^ (r & 15)) & 15);
    ((bf16x8*)Alds)[r * 32 + cs] = v;
  }
  __syncthreads();

  const int arow = wv * 16 + c15;
  #pragma unroll
  for (int kf = 0; kf < 8; ++kf) {
    int c = kf * 4 + q;
    int cs = (c & 16) | ((c ^ c15) & 15);
    bf16x8 v = ((const bf16x8*)Alds)[arow * 32 + cs];
    ((bf16x8*)xbf)[(((size_t)t * 4 + wv) * 8 + kf) * 64 + lane] = v;
  }
}

// ---------------------------------------------------------------------------
// Phase 1 v4: xw = x @ W_d + b_d from PRE-FRAGMENTED x (xbf), GATE-MAJOR
// column tiling -> each thread stores its full 32B [gate][r] unit (coalesced).
// W in registers; x streamed with 2-buffer prefetch.
// ROUND-10 CHANGE (single): block-index mapping transposed. Previously
// blockIdx.x (the fast dispatch axis) was the t-chunk, so the 16 blocks
// sharing one 1-MB XBF t-slice were dispatched 32 apart -> per-XCD L2
// thrash; the 512 MB of XBF re-reads came from L3. Now blockIdx.x = (d,hw)
// and blockIdx.y = t-chunk: consecutive blocks share the same XBF slice ->
// each XCD pulls it once and serves its resident blocks from L2.
// Output bit-identical (same per-block work, same addresses).
// ---------------------------------------------------------------------------
__global__ __launch_bounds__(256, 2) void xw_gemm_v4(
    const u16* __restrict__ xbf,
    const float* __restrict__ W0, const float* __restrict__ W1,
    const float* __restrict__ b0, const float* __restrict__ b1,
    u16* __restrict__ xw)
{
  const int d  = blockIdx.x >> 4;          // transposed: x = (d,hw)
  const int hw = blockIdx.x & 15;          // h-col window [hw*16, hw*16+16)
  const int t0 = blockIdx.y * 32;          // transposed: y = t-chunk
  const float* __restrict__ W    = d ? W1 : W0;
  const float* __restrict__ bias = d ? b1 : b0;
  const int lane = threadIdx.x & 63;
  const int wv   = threadIdx.x >> 6;
  const int q    = lane >> 4;
  const int c15  = lane & 15;

  bf16x8 uf[4][8];
  float bc[4];
  #pragma unroll
  for (int ct = 0; ct < 4; ++ct) {
    const int col = ct * 256 + hw * 16 + c15;
    #pragma unroll
    for (int kf = 0; kf < 8; ++kf) {
      #pragma unroll
      for (int j = 0; j < 8; ++j)
        uf[ct][kf][j] = (short)f2b(W[(size_t)(kf * 32 + q * 8 + j) * G4 + col]);
    }
    bc[ct] = bias[col];
  }

  const bf16x8* __restrict__ xb = (const bf16x8*)xbf;
  const size_t wvl = (size_t)wv * 8 * 64 + lane;
  #define AFIDX(t, kf) (((size_t)(t) * 32 + (kf)) * 64 + wvl)
  const size_t sunit = (size_t)hw * 64 + q * 16 + c15;

  bf16x8 afA[8], afB[8];
  #pragma unroll
  for (int kf = 0; kf < 8; ++kf) afA[kf] = xb[AFIDX(t0, kf)];

  for (int tt = t0; tt < t0 + 32; tt += 2) {
    #pragma unroll
    for (int kf = 0; kf < 8; ++kf) afB[kf] = xb[AFIDX(tt + 1, kf)];

    {
      f32x4 acc[4];
      #pragma unroll
      for (int ct = 0; ct < 4; ++ct) acc[ct] = (f32x4){0.f, 0.f, 0.f, 0.f};
      #pragma unroll
      for (int kf = 0; kf < 8; ++kf) {
        #pragma unroll
        for (int ct = 0; ct < 4; ++ct)
          acc[ct] = __builtin_amdgcn_mfma_f32_16x16x32_bf16(afA[kf], uf[ct][kf], acc[ct], 0, 0, 0);
      }
      union { u16 s[16]; int4 v4[2]; } pk;
      #pragma unroll
      for (int ct = 0; ct < 4; ++ct)
        #pragma unroll
        for (int r = 0; r < 4; ++r) pk.s[ct * 4 + r] = f2b(acc[ct][r] + bc[ct]);
      u16* dst = xw + ((((size_t)d * T_STEPS + tt) * 4 + wv) * 1024 + sunit) * 16;
      ((int4*)dst)[0] = pk.v4[0];
      ((int4*)dst)[1] = pk.v4[1];
    }

    if (tt + 2 < t0 + 32) {
      #pragma unroll
      for (int kf = 0; kf < 8; ++kf) afA[kf] = xb[AFIDX(tt + 2, kf)];
    }

    {
      f32x4 acc[4];
      #pragma unroll
      for (int ct = 0; ct < 4; ++ct) acc[ct] = (f32x4){0.f, 0.f, 0.f, 0.f};
      #pragma unroll
      for (int kf = 0; kf < 8; ++kf) {
        #pragma unroll
        for (int ct = 0; ct < 4; ++ct)
          acc[ct] = __builtin_amdgcn_mfma_f32_16x16x32_bf16(afB[kf], uf[ct][kf], acc[ct], 0, 0, 0);
      }
      union { u16 s[16]; int4 v4[2]; } pk;
      #pragma unroll
      for (int ct = 0; ct < 4; ++ct)
        #pragma unroll
        for (int r = 0; r < 4; ++r) pk.s[ct * 4 + r] = f2b(acc[ct][r] + bc[ct]);
      u16* dst = xw + ((((size_t)d * T_STEPS + (tt + 1)) * 4 + wv) * 1024 + sunit) * 16;
      ((int4*)dst)[0] = pk.v4[0];
      ((int4*)dst)[1] = pk.v4[1];
    }
  }
  #undef AFIDX
}

// ---------------------------------------------------------------------------
// Phase 1 fallback (round-0 kernel): used when ws lacks room for XBF.
// ---------------------------------------------------------------------------
__global__ __launch_bounds__(256, 2) void xw_gemm(
    const float* __restrict__ x,
    const float* __restrict__ W0, const float* __restrict__ W1,
    const float* __restrict__ b0, const float* __restrict__ b1,
    u16* __restrict__ xw)
{
  const int d  = blockIdx.y >> 4;
  const int n0 = (blockIdx.y & 15) * 64;
  const int t0 = blockIdx.x * 32;
  const float* __restrict__ W    = d ? W1 : W0;
  const float* __restrict__ bias = d ? b1 : b0;
  const int lane = threadIdx.x & 63;
  const int wv   = threadIdx.x >> 6;
  const int q    = lane >> 4;
  const int c15  = lane & 15;

  bf16x8 uf[4][8];
  #pragma unroll
  for (int ct = 0; ct < 4; ++ct) {
    const int col = n0 + ct * 16 + c15;
    #pragma unroll
    for (int kf = 0; kf < 8; ++kf) {
      #pragma unroll
      for (int j = 0; j < 8; ++j)
        uf[ct][kf][j] = (short)f2b(W[(size_t)(kf * 32 + q * 8 + j) * G4 + col]);
    }
  }
  float bc[4];
  #pragma unroll
  for (int ct = 0; ct < 4; ++ct) bc[ct] = bias[n0 + ct * 16 + c15];

  __shared__ __align__(16) u16 Alds[64 * 256];

  for (int t = t0; t < t0 + 32; ++t) {
    __syncthreads();
    const float* xt = x + (size_t)t * BATCH * NDIM;
    #pragma unroll
    for (int i = 0; i < 8; ++i) {
      int g = (int)threadIdx.x + 256 * i;
      int r = g >> 5, c = g & 31;
      const float* src = xt + r * 256 + c * 8;
      bf16x8 v;
      #pragma unroll
      for (int j = 0; j < 8; ++j) v[j] = (short)f2b(src[j]);
      int cs = (c & 16) | ((c ^ (r & 15)) & 15);
      ((bf16x8*)Alds)[r * 32 + cs] = v;
    }
    __syncthreads();

    bf16x8 af[8];
    const int arow = wv * 16 + c15;
    #pragma unroll
    for (int kf = 0; kf < 8; ++kf) {
      int c = kf * 4 + q;
      int cs = (c & 16) | ((c ^ c15) & 15);
      af[kf] = ((const bf16x8*)Alds)[arow * 32 + cs];
    }

    f32x4 acc[4];
    #pragma unroll
    for (int ct = 0; ct < 4; ++ct) acc[ct] = (f32x4){0.f, 0.f, 0.f, 0.f};
    #pragma unroll
    for (int kf = 0; kf < 8; ++kf) {
      #pragma unroll
      for (int ct = 0; ct < 4; ++ct)
        acc[ct] = __builtin_amdgcn_mfma_f32_16x16x32_bf16(af[kf], uf[ct][kf], acc[ct], 0, 0, 0);
    }

    u16* dst = xw + (((size_t)d * T_STEPS + t) * 4 + wv) * 16384;
    #pragma unroll
    for (int ct = 0; ct < 4; ++ct) {
      int ncol = n0 + ct * 16;
      int g2 = ncol >> 8, w2 = (ncol >> 4) & 15;
      union { u16 s[4]; uint2 v; } pk;
      #pragma unroll
      for (int r = 0; r < 4; ++r) pk.s[r] = f2b(acc[ct][r] + bc[ct]);
      *(uint2*)(dst + (size_t)(w2 * 64 + q * 16 + c15) * 16 + g2 * 4) = pk.v;
    }
  }
}

// ---------------------------------------------------------------------------
// Phase 2 (fast). Validated model: step bound by the CU's L1 return path
// (144 B/thread/step = o-stream kf1..7 112 B + xw 32 B -> 2304 cyc at
// 64 B/cyc; measured 2418, 95%). B6 (U_o kf=0 in LDS) gave the predicted
// -12%. On-chip storage now exhausted (LDS 160 KB full, regs at 128/wave
// cap) -> scan at its safe structural limit. DO NOT TOUCH.
// Dynamic LDS 163840 B: [0,16384) h ping-pong, [16384,147456) U_i,
// [147456,163840) U_o kf=0 (one 16B slot per thread).
// ---------------------------------------------------------------------------
__global__ __launch_bounds__(1024) void lstm_scan_fast(
    const u16* __restrict__ xw, const u16* __restrict__ UT,
    float* __restrict__ out)
{
  extern __shared__ __align__(16) u16 dynlds[];
  const int d  = blockIdx.x >> 2;
  const int bt = blockIdx.x & 3;
  const int tid  = threadIdx.x;
  const int w    = tid >> 6;
  const int lane = tid & 63;
  const int q    = lane >> 4;
  const int c15  = lane & 15;

  const u16* __restrict__ UTd = UT + (size_t)d * 4 * 65536;
  const int4* __restrict__ Uo4 = (const int4*)(UTd + 3 * 65536);
  const int obase = (w << 9) | lane;

  // persistent register fragments for gates f(0), g(1)
  bf16x8 uf0[8], uf1[8];
  const bf16x8* UTf = (const bf16x8*)UTd;
  #pragma unroll
  for (int kf = 0; kf < 8; ++kf) {
    uf0[kf] = UTf[       ((w * 8 + kf) << 6) + lane];
    uf1[kf] = UTf[8192 + ((w * 8 + kf) << 6) + lane];
  }

  // stage i-gate into LDS + zero both h buffers + stage U_o kf=0 fragment
  {
    const int4* src = (const int4*)(UTd + 2 * 65536);
    int4* dstl = (int4*)(dynlds + 8192);
    for (int i = tid; i < 8192; i += 1024) dstl[i] = src[i];
    for (int i = tid; i < 8192; i += 1024) dynlds[i] = 0;
    ((int4*)(dynlds + 73728))[tid] = Uo4[obase];   // byte offset 147456
  }

  const char* uib_base = (const char*)(dynlds + 8192) + (size_t)obase * 16;  // +kf*1024 imm
  const char* o0_base  = (const char*)dynlds + 147456 + (size_t)tid * 16;

  // precomputed LDS byte offsets; h buffer selected by XOR 8192
  int afo[8];
  #pragma unroll
  for (int kf = 0; kf < 8; ++kf) {
    int cc = kf * 4 + q;
    int cs = (cc & 16) | ((cc ^ c15) & 15);
    afo[kf] = (c15 * 32 + cs) * 16;
  }
  const int colv = w * 16 + c15;
  int hwo[4];
  #pragma unroll
  for (int r = 0; r < 4; ++r) {
    int row = q * 4 + r;
    int cch = colv >> 3;
    int cs = (cch & 16) | ((cch ^ row) & 15);
    hwo[r] = ((row * 32 + cs) * 8 + (colv & 7)) * 2;
  }

  float cst[4] = {0.f, 0.f, 0.f, 0.f};
  __syncthreads();

  const int rowbase = bt * 16;
  const size_t hlast_base = (size_t)T_STEPS * BATCH * (2 * HID) + (size_t)d * BATCH * HID;
  const int t_first = d ? (T_STEPS - 1) : 0;

  // xw walking pointer; prefetch step 0
  const long xw_stride = d ? -(long)(4 * 16384) : (long)(4 * 16384);
  const u16* xwp = xw + (((size_t)d * T_STEPS + t_first) * 4 + bt) * 16384 + (size_t)tid * 16;
  union I4x2 { int4 v[2]; u16 s[16]; };
  I4x2 xn;
  xn.v[0] = ((const int4*)xwp)[0];
  xn.v[1] = ((const int4*)xwp)[1];
  xwp += xw_stride;

  // o-gate rolling L2 stream for kf>=1 (kf=0 comes from LDS)
  int4 ofr[3];
  ofr[1] = Uo4[obase + 64];

  // out walking pointer
  float* outp = out + (size_t)(t_first * BATCH + rowbase + q * 4) * (2 * HID)
              + (size_t)d * HID + colv;
  const long out_stride = d ? -(long)(BATCH * 2 * HID) : (long)(BATCH * 2 * HID);

  int curoff = 0;
  for (int it = 0; it < T_STEPS; ++it) {
    // seed accumulators with current step's pre-activations
    f32x4 acc0 = { b2f(xn.s[0]),  b2f(xn.s[1]),  b2f(xn.s[2]),  b2f(xn.s[3])  };
    f32x4 acc1 = { b2f(xn.s[4]),  b2f(xn.s[5]),  b2f(xn.s[6]),  b2f(xn.s[7])  };
    f32x4 acc2 = { b2f(xn.s[8]),  b2f(xn.s[9]),  b2f(xn.s[10]), b2f(xn.s[11]) };
    f32x4 acc3 = { b2f(xn.s[12]), b2f(xn.s[13]), b2f(xn.s[14]), b2f(xn.s[15]) };

    // prefetch next step's xw (hidden under this step's MFMA+gates)
    if (it + 1 < T_STEPS) {
      xn.v[0] = ((const int4*)xwp)[0];
      xn.v[1] = ((const int4*)xwp)[1];
      xwp += xw_stride;
    }

    const char* hcb = (const char*)dynlds + curoff;
    bf16x8 afb[2], uib[2], oc0;
    afb[0] = *(const bf16x8*)(hcb + afo[0]);
    uib[0] = *(const bf16x8*)(uib_base);
    oc0    = *(const bf16x8*)(o0_base);
    #pragma unroll
    for (int kf = 0; kf < 8; ++kf) {
      if (kf < 7) {
        afb[(kf + 1) & 1] = *(const bf16x8*)(hcb + afo[kf + 1]);
        uib[(kf + 1) & 1] = *(const bf16x8*)(uib_base + (kf + 1) * 1024);
      }
      if (kf < 6) ofr[(kf + 2) % 3] = Uo4[obase + ((kf + 2) << 6)];
      bf16x8 af = afb[kf & 1];
      bf16x8 ob;
      if (kf == 0) {
        ob = oc0;
      } else {
        union { int4 v; bf16x8 b; } oc; oc.v = ofr[kf % 3];
        ob = oc.b;
      }
      acc0 = __builtin_amdgcn_mfma_f32_16x16x32_bf16(af, uf0[kf],     acc0, 0, 0, 0);
      acc1 = __builtin_amdgcn_mfma_f32_16x16x32_bf16(af, uf1[kf],     acc1, 0, 0, 0);
      acc2 = __builtin_amdgcn_mfma_f32_16x16x32_bf16(af, uib[kf & 1], acc2, 0, 0, 0);
      acc3 = __builtin_amdgcn_mfma_f32_16x16x32_bf16(af, ob,          acc3, 0, 0, 0);
    }
    // refill o-stream kf=1 slot for NEXT step (kf=0 now served from LDS)
    ofr[1] = Uo4[obase + 64];

    u16 hb[4]; float hv[4];
    #pragma unroll
    for (int r = 0; r < 4; ++r) {
      float fg = sigm(acc0[r]);
      float gg = tanh_f(acc1[r]);
      float ig = sigm(acc2[r]);
      float og = sigm(acc3[r]);
      float cn = cst[r] * fg + gg * ig;
      cst[r] = cn;
      hv[r] = og * tanh_f(cn);
      hb[r] = f2b(hv[r]);
    }

    const int nxtoff = curoff ^ 8192;
    char* hwp = (char*)dynlds + nxtoff;
    #pragma unroll
    for (int r = 0; r < 4; ++r) {
      *(u16*)(hwp + hwo[r]) = hb[r];
      outp[r * (2 * HID)] = hv[r];          // imm offsets 0/2048/4096/6144 B
    }
    outp += out_stride;
    if (it == T_STEPS - 1) {
      #pragma unroll
      for (int r = 0; r < 4; ++r)
        out[hlast_base + (size_t)(rowbase + q * 4 + r) * HID + colv] = hv[r];
    }
    curoff = nxtoff;
    __syncthreads();
  }
}

// ---------------------------------------------------------------------------
// Phase 2 (safe fallback if ws too small for UT): correct but slow.
// ---------------------------------------------------------------------------
__global__ __launch_bounds__(1024) void lstm_scan_safe(
    const u16* __restrict__ xw,
    const float* __restrict__ U0, const float* __restrict__ U1,
    float* __restrict__ out)
{
  const int d  = blockIdx.x >> 2;
  const int bt = blockIdx.x & 3;
  const int tid  = threadIdx.x;
  const int w    = tid >> 6;
  const int lane = tid & 63;
  const int q    = lane >> 4;
  const int c15  = lane & 15;
  const float* __restrict__ U = d ? U1 : U0;

  bf16x8 uf[4][8];
  #pragma unroll
  for (int g = 0; g < 4; ++g) {
    const int col2 = g * 256 + w * 16 + c15;
    #pragma unroll
    for (int kf = 0; kf < 8; ++kf) {
      #pragma unroll
      for (int j = 0; j < 8; ++j)
        uf[g][kf][j] = (short)f2b(U[(size_t)(kf * 32 + q * 8 + j) * G4 + col2]);
    }
  }

  __shared__ __align__(16) u16 hbuf[2][16 * 256];
  for (int i = tid; i < 16 * 256; i += 1024) { hbuf[0][i] = 0; hbuf[1][i] = 0; }
  float cst[4] = {0.f, 0.f, 0.f, 0.f};
  __syncthreads();

  const int rowbase = bt * 16;
  const int col = w * 16 + c15;
  const size_t hlast_base = (size_t)T_STEPS * BATCH * (2 * HID) + (size_t)d * BATCH * HID;

  for (int it = 0; it < T_STEPS; ++it) {
    const int t = d ? (T_STEPS - 1 - it) : it;
    union { int4 v[2]; u16 s[16]; } xv;
    {
      const int4* xwt = (const int4*)(xw + ((((size_t)d * T_STEPS + t) * 4 + bt) * 1024 + tid) * 16);
      xv.v[0] = xwt[0]; xv.v[1] = xwt[1];
    }
    const int cur = it & 1;
    bf16x8 af[8];
    #pragma unroll
    for (int kf = 0; kf < 8; ++kf) {
      int cc = kf * 4 + q;
      int cs = (cc & 16) | ((cc ^ c15) & 15);
      af[kf] = ((const bf16x8*)hbuf[cur])[c15 * 32 + cs];
    }
    f32x4 acc[4];
    #pragma unroll
    for (int g = 0; g < 4; ++g) acc[g] = (f32x4){0.f, 0.f, 0.f, 0.f};
    #pragma unroll
    for (int kf = 0; kf < 8; ++kf)
      #pragma unroll
      for (int g = 0; g < 4; ++g)
        acc[g] = __builtin_amdgcn_mfma_f32_16x16x32_bf16(af[kf], uf[g][kf], acc[g], 0, 0, 0);

    u16 hb[4]; float hv[4];
    #pragma unroll
    for (int r = 0; r < 4; ++r) {
      float zf = acc[0][r] + b2f(xv.s[0 * 4 + r]);
      float zg = acc[1][r] + b2f(xv.s[1 * 4 + r]);
      float zi = acc[2][r] + b2f(xv.s[2 * 4 + r]);
      float zo = acc[3][r] + b2f(xv.s[3 * 4 + r]);
      float fg = sigm(zf), gg = tanh_f(zg), ig = sigm(zi), og = sigm(zo);
      float cn = cst[r] * fg + gg * ig;
      cst[r] = cn;
      hv[r] = og * tanh_f(cn);
      hb[r] = f2b(hv[r]);
    }
    const int nxt = cur ^ 1;
    #pragma unroll
    for (int r = 0; r < 4; ++r) {
      const int row = q * 4 + r;
      int cch = col >> 3;
      int cs = (cch & 16) | ((cch ^ row) & 15);
      hbuf[nxt][(row * 32 + cs) * 8 + (col & 7)] = hb[r];
      out[((size_t)t * BATCH + rowbase + row) * (2 * HID) + (size_t)d * HID + col] = hv[r];
    }
    if (it == T_STEPS - 1) {
      #pragma unroll
      for (int r = 0; r < 4; ++r)
        out[hlast_base + (size_t)(rowbase + q * 4 + r) * HID + col] = hv[r];
    }
    __syncthreads();
  }
}

extern "C" void kernel_launch(void* const* d_in, const int* in_sizes, int n_in,
                              void* d_out, int out_size, void* d_ws, size_t ws_size,
                              hipStream_t stream) {
  const float* x  = (const float*)d_in[0];
  const float* fW = (const float*)d_in[1];
  const float* fU = (const float*)d_in[2];
  const float* fb = (const float*)d_in[3];
  const float* bW = (const float*)d_in[4];
  const float* bU = (const float*)d_in[5];
  const float* bb = (const float*)d_in[6];
  u16*   xwbuf = (u16*)d_ws;
  u16*   UT    = (u16*)d_ws + XW_ELEMS;
  u16*   XBF   = (u16*)d_ws + XW_ELEMS + UT_ELEMS;
  float* out   = (float*)d_out;

  const bool fast   = ws_size >= (XW_ELEMS + UT_ELEMS) * sizeof(u16);
  const bool use_v4 = ws_size >= (XW_ELEMS + UT_ELEMS + XBF_ELEMS) * sizeof(u16);

  if (use_v4) {
    x_to_frag<<<1024, 256, 0, stream>>>(x, XBF);
    dim3 g1(32, 32);
    xw_gemm_v4<<<g1, 256, 0, stream>>>(XBF, fW, bW, fb, bb, xwbuf);
  } else {
    dim3 g1(32, 32);
    xw_gemm<<<g1, 256, 0, stream>>>(x, fW, bW, fb, bb, xwbuf);
  }
  if (fast) {
    build_ut<<<8, 1024, 0, stream>>>(fU, bU, UT);
    hipFuncSetAttribute((const void*)lstm_scan_fast,
                        hipFuncAttributeMaxDynamicSharedMemorySize, 163840);
    lstm_scan_fast<<<8, 1024, 163840, stream>>>(xwbuf, UT, out);
  } else {
    lstm_scan_safe<<<8, 1024, 0, stream>>>(xwbuf, fU, bU, out);
  }
}

// Round 12
// 3258.377 us; speedup vs baseline: 2.3562x; 1.0291x over previous
//
#include <hip/hip_runtime.h>

#define T_STEPS 1024
#define BATCH   64
#define NDIM    256
#define HID     256
#define G4      1024   // 4*H

typedef short bf16x8 __attribute__((ext_vector_type(8)));
typedef float f32x4  __attribute__((ext_vector_type(4)));
typedef unsigned short u16;

#define XW_ELEMS  ((size_t)2 * T_STEPS * BATCH * G4)   // 134217728 u16 (256 MiB)
#define UT_ELEMS  ((size_t)2 * 4 * 65536)              // 524288 u16 (1 MiB)
#define XBF_ELEMS ((size_t)T_STEPS * BATCH * NDIM)     // 16777216 u16 (32 MiB)

__device__ __forceinline__ float b2f(u16 v) {
  union { unsigned u; float f; } c; c.u = ((unsigned)v) << 16; return c.f;
}
__device__ __forceinline__ u16 f2b(float f) {
  union { float f; unsigned u; } c; c.f = f;
  unsigned u = c.u;
  u += 0x7fffu + ((u >> 16) & 1u);   // round-to-nearest-even
  return (u16)(u >> 16);
}
__device__ __forceinline__ float sigm(float x) {
  float e = __expf(-x);
  return __builtin_amdgcn_rcpf(1.0f + e);
}
__device__ __forceinline__ float tanh_f(float x) {
  return 2.0f * sigm(2.0f * x) - 1.0f;
}

// ---------------------------------------------------------------------------
// build_ut: pre-transpose U (f32) into bf16 MFMA B-fragment order.
// elem idx: ((d*4+g)*65536) + ((w*8+kf)*64 + lane)*8 + j
// ---------------------------------------------------------------------------
__global__ __launch_bounds__(1024) void build_ut(
    const float* __restrict__ U0, const float* __restrict__ U1,
    u16* __restrict__ UT)
{
  const int d = blockIdx.x >> 2;
  const int g = blockIdx.x & 3;
  const float* __restrict__ U = d ? U1 : U0;
  const int w = threadIdx.x >> 6, lane = threadIdx.x & 63;
  const int q = lane >> 4, c15 = lane & 15;
  u16* dst = UT + ((size_t)d * 4 + g) * 65536;
  #pragma unroll
  for (int kf = 0; kf < 8; ++kf) {
    bf16x8 v;
    #pragma unroll
    for (int j = 0; j < 8; ++j)
      v[j] = (short)f2b(U[(size_t)(kf * 32 + q * 8 + j) * G4 + g * 256 + w * 16 + c15]);
    ((bf16x8*)dst)[((w * 8 + kf) << 6) + lane] = v;
  }
}

// ---------------------------------------------------------------------------
// x_to_frag: convert x (f32) ONCE into bf16 MFMA A-fragment order.
// Fragment idx (bf16x8 units): ((t*4 + wv)*8 + kf)*64 + lane
// ---------------------------------------------------------------------------
__global__ __launch_bounds__(256) void x_to_frag(
    const float* __restrict__ x, u16* __restrict__ xbf)
{
  const int t   = blockIdx.x;
  const int tid = threadIdx.x;
  const int wv  = tid >> 6, lane = tid & 63;
  const int q   = lane >> 4, c15 = lane & 15;
  __shared__ __align__(16) u16 Alds[64 * 256];

  const float* xt = x + (size_t)t * BATCH * NDIM;
  #pragma unroll
  for (int i = 0; i < 8; ++i) {
    int g = tid + 256 * i;
    int r = g >> 5, c = g & 31;
    const float* src = xt + r * 256 + c * 8;
    bf16x8 v;
    #pragma unroll
    for (int j = 0; j < 8; ++j) v[j] = (short)f2b(src[j]);
    int cs = (c & 16) | ((c ^ (r & 15)) & 15);
    ((bf16x8*)Alds)[r * 32 + cs] = v;
  }
  __syncthreads();

  const int arow = wv * 16 + c15;
  #pragma unroll
  for (int kf = 0; kf < 8; ++kf) {
    int c = kf * 4 + q;
    int cs = (c & 16) | ((c ^ c15) & 15);
    bf16x8 v = ((const bf16x8*)Alds)[arow * 32 + cs];
    ((bf16x8*)xbf)[(((size_t)t * 4 + wv) * 8 + kf) * 64 + lane] = v;
  }
}

// ---------------------------------------------------------------------------
// Phase 1 v5: xw = x @ W_d + b_d from PRE-FRAGMENTED x (xbf), gate-major
// stores (v4), with XCD-WINDOWED WORK PARTITION.
// Round-11 diagnosis: with 512 resident blocks, each XCD's ~64 concurrent
// blocks spanned 16+ XBF t-slices (>> 4MB L2) -> L2 thrashed to L3 no matter
// the dispatch-index order (that's why the transpose was neutral). Fix is
// PARTITIONING: using the round-robin bid%8 -> XCD placement heuristic,
// XCD x exclusively processes t in [x*128, x*128+128): its 4MB XBF window
// fits L2 exactly, fetched from L3 once (32MB total, was ~512MB); re-reads
// served at L2 BW. Block: xcd=bid&7, fixed (d,hw) [W-frags loaded once],
// 64 contiguous t's; 2 blocks/CU for TLP. Inner body identical to v4 ->
// output BIT-IDENTICAL. Worst case (placement heuristic wrong): degrades
// to v4's locality, never worse.
// ---------------------------------------------------------------------------
__global__ __launch_bounds__(256, 2) void xw_gemm_v5(
    const u16* __restrict__ xbf,
    const float* __restrict__ W0, const float* __restrict__ W1,
    const float* __restrict__ b0, const float* __restrict__ b1,
    u16* __restrict__ xw)
{
  const int bid  = blockIdx.x;
  const int xcd  = bid & 7;
  const int rr   = bid >> 3;          // 0..63
  const int dhw  = rr >> 1;           // 0..31
  const int half = rr & 1;
  const int d    = dhw >> 4;
  const int hw   = dhw & 15;          // h-col window [hw*16, hw*16+16)
  const int t0   = xcd * 128 + half * 64;   // 64 t's in this XCD's window
  const float* __restrict__ W    = d ? W1 : W0;
  const float* __restrict__ bias = d ? b1 : b0;
  const int lane = threadIdx.x & 63;
  const int wv   = threadIdx.x >> 6;
  const int q    = lane >> 4;
  const int c15  = lane & 15;

  // uf[ct] = gate ct's 16-col W tile for this h-window (128 VGPRs)
  bf16x8 uf[4][8];
  float bc[4];
  #pragma unroll
  for (int ct = 0; ct < 4; ++ct) {
    const int col = ct * 256 + hw * 16 + c15;
    #pragma unroll
    for (int kf = 0; kf < 8; ++kf) {
      #pragma unroll
      for (int j = 0; j < 8; ++j)
        uf[ct][kf][j] = (short)f2b(W[(size_t)(kf * 32 + q * 8 + j) * G4 + col]);
    }
    bc[ct] = bias[col];
  }

  const bf16x8* __restrict__ xb = (const bf16x8*)xbf;
  const size_t wvl = (size_t)wv * 8 * 64 + lane;
  #define AFIDX(t, kf) (((size_t)(t) * 32 + (kf)) * 64 + wvl)
  const size_t sunit = (size_t)hw * 64 + q * 16 + c15;

  bf16x8 afA[8], afB[8];
  #pragma unroll
  for (int kf = 0; kf < 8; ++kf) afA[kf] = xb[AFIDX(t0, kf)];

  for (int tt = t0; tt < t0 + 64; tt += 2) {
    #pragma unroll
    for (int kf = 0; kf < 8; ++kf) afB[kf] = xb[AFIDX(tt + 1, kf)];

    {
      f32x4 acc[4];
      #pragma unroll
      for (int ct = 0; ct < 4; ++ct) acc[ct] = (f32x4){0.f, 0.f, 0.f, 0.f};
      #pragma unroll
      for (int kf = 0; kf < 8; ++kf) {
        #pragma unroll
        for (int ct = 0; ct < 4; ++ct)
          acc[ct] = __builtin_amdgcn_mfma_f32_16x16x32_bf16(afA[kf], uf[ct][kf], acc[ct], 0, 0, 0);
      }
      union { u16 s[16]; int4 v4[2]; } pk;
      #pragma unroll
      for (int ct = 0; ct < 4; ++ct)
        #pragma unroll
        for (int r = 0; r < 4; ++r) pk.s[ct * 4 + r] = f2b(acc[ct][r] + bc[ct]);
      u16* dst = xw + ((((size_t)d * T_STEPS + tt) * 4 + wv) * 1024 + sunit) * 16;
      ((int4*)dst)[0] = pk.v4[0];
      ((int4*)dst)[1] = pk.v4[1];
    }

    if (tt + 2 < t0 + 64) {
      #pragma unroll
      for (int kf = 0; kf < 8; ++kf) afA[kf] = xb[AFIDX(tt + 2, kf)];
    }

    {
      f32x4 acc[4];
      #pragma unroll
      for (int ct = 0; ct < 4; ++ct) acc[ct] = (f32x4){0.f, 0.f, 0.f, 0.f};
      #pragma unroll
      for (int kf = 0; kf < 8; ++kf) {
        #pragma unroll
        for (int ct = 0; ct < 4; ++ct)
          acc[ct] = __builtin_amdgcn_mfma_f32_16x16x32_bf16(afB[kf], uf[ct][kf], acc[ct], 0, 0, 0);
      }
      union { u16 s[16]; int4 v4[2]; } pk;
      #pragma unroll
      for (int ct = 0; ct < 4; ++ct)
        #pragma unroll
        for (int r = 0; r < 4; ++r) pk.s[ct * 4 + r] = f2b(acc[ct][r] + bc[ct]);
      u16* dst = xw + ((((size_t)d * T_STEPS + (tt + 1)) * 4 + wv) * 1024 + sunit) * 16;
      ((int4*)dst)[0] = pk.v4[0];
      ((int4*)dst)[1] = pk.v4[1];
    }
  }
  #undef AFIDX
}

// ---------------------------------------------------------------------------
// Phase 1 fallback (round-0 kernel): used when ws lacks room for XBF.
// ---------------------------------------------------------------------------
__global__ __launch_bounds__(256, 2) void xw_gemm(
    const float* __restrict__ x,
    const float* __restrict__ W0, const float* __restrict__ W1,
    const float* __restrict__ b0, const float* __restrict__ b1,
    u16* __restrict__ xw)
{
  const int d  = blockIdx.y >> 4;
  const int n0 = (blockIdx.y & 15) * 64;
  const int t0 = blockIdx.x * 32;
  const float* __restrict__ W    = d ? W1 : W0;
  const float* __restrict__ bias = d ? b1 : b0;
  const int lane = threadIdx.x & 63;
  const int wv   = threadIdx.x >> 6;
  const int q    = lane >> 4;
  const int c15  = lane & 15;

  bf16x8 uf[4][8];
  #pragma unroll
  for (int ct = 0; ct < 4; ++ct) {
    const int col = n0 + ct * 16 + c15;
    #pragma unroll
    for (int kf = 0; kf < 8; ++kf) {
      #pragma unroll
      for (int j = 0; j < 8; ++j)
        uf[ct][kf][j] = (short)f2b(W[(size_t)(kf * 32 + q * 8 + j) * G4 + col]);
    }
  }
  float bc[4];
  #pragma unroll
  for (int ct = 0; ct < 4; ++ct) bc[ct] = bias[n0 + ct * 16 + c15];

  __shared__ __align__(16) u16 Alds[64 * 256];

  for (int t = t0; t < t0 + 32; ++t) {
    __syncthreads();
    const float* xt = x + (size_t)t * BATCH * NDIM;
    #pragma unroll
    for (int i = 0; i < 8; ++i) {
      int g = (int)threadIdx.x + 256 * i;
      int r = g >> 5, c = g & 31;
      const float* src = xt + r * 256 + c * 8;
      bf16x8 v;
      #pragma unroll
      for (int j = 0; j < 8; ++j) v[j] = (short)f2b(src[j]);
      int cs = (c & 16) | ((c ^ (r & 15)) & 15);
      ((bf16x8*)Alds)[r * 32 + cs] = v;
    }
    __syncthreads();

    bf16x8 af[8];
    const int arow = wv * 16 + c15;
    #pragma unroll
    for (int kf = 0; kf < 8; ++kf) {
      int c = kf * 4 + q;
      int cs = (c & 16) | ((c ^ c15) & 15);
      af[kf] = ((const bf16x8*)Alds)[arow * 32 + cs];
    }

    f32x4 acc[4];
    #pragma unroll
    for (int ct = 0; ct < 4; ++ct) acc[ct] = (f32x4){0.f, 0.f, 0.f, 0.f};
    #pragma unroll
    for (int kf = 0; kf < 8; ++kf) {
      #pragma unroll
      for (int ct = 0; ct < 4; ++ct)
        acc[ct] = __builtin_amdgcn_mfma_f32_16x16x32_bf16(af[kf], uf[ct][kf], acc[ct], 0, 0, 0);
    }

    u16* dst = xw + (((size_t)d * T_STEPS + t) * 4 + wv) * 16384;
    #pragma unroll
    for (int ct = 0; ct < 4; ++ct) {
      int ncol = n0 + ct * 16;
      int g2 = ncol >> 8, w2 = (ncol >> 4) & 15;
      union { u16 s[4]; uint2 v; } pk;
      #pragma unroll
      for (int r = 0; r < 4; ++r) pk.s[r] = f2b(acc[ct][r] + bc[ct]);
      *(uint2*)(dst + (size_t)(w2 * 64 + q * 16 + c15) * 16 + g2 * 4) = pk.v;
    }
  }
}

// ---------------------------------------------------------------------------
// Phase 2 (fast). Validated model: step bound by the CU's L1 return path
// (144 B/thread/step = o-stream kf1..7 112 B + xw 32 B -> 2304 cyc at
// 64 B/cyc; measured 2418, 95%). B6 (U_o kf=0 in LDS) gave the predicted
// -12%. On-chip storage now exhausted (LDS 160 KB full, regs at 128/wave
// cap) -> scan at its safe structural limit. DO NOT TOUCH.
// Dynamic LDS 163840 B: [0,16384) h ping-pong, [16384,147456) U_i,
// [147456,163840) U_o kf=0 (one 16B slot per thread).
// ---------------------------------------------------------------------------
__global__ __launch_bounds__(1024) void lstm_scan_fast(
    const u16* __restrict__ xw, const u16* __restrict__ UT,
    float* __restrict__ out)
{
  extern __shared__ __align__(16) u16 dynlds[];
  const int d  = blockIdx.x >> 2;
  const int bt = blockIdx.x & 3;
  const int tid  = threadIdx.x;
  const int w    = tid >> 6;
  const int lane = tid & 63;
  const int q    = lane >> 4;
  const int c15  = lane & 15;

  const u16* __restrict__ UTd = UT + (size_t)d * 4 * 65536;
  const int4* __restrict__ Uo4 = (const int4*)(UTd + 3 * 65536);
  const int obase = (w << 9) | lane;

  // persistent register fragments for gates f(0), g(1)
  bf16x8 uf0[8], uf1[8];
  const bf16x8* UTf = (const bf16x8*)UTd;
  #pragma unroll
  for (int kf = 0; kf < 8; ++kf) {
    uf0[kf] = UTf[       ((w * 8 + kf) << 6) + lane];
    uf1[kf] = UTf[8192 + ((w * 8 + kf) << 6) + lane];
  }

  // stage i-gate into LDS + zero both h buffers + stage U_o kf=0 fragment
  {
    const int4* src = (const int4*)(UTd + 2 * 65536);
    int4* dstl = (int4*)(dynlds + 8192);
    for (int i = tid; i < 8192; i += 1024) dstl[i] = src[i];
    for (int i = tid; i < 8192; i += 1024) dynlds[i] = 0;
    ((int4*)(dynlds + 73728))[tid] = Uo4[obase];   // byte offset 147456
  }

  const char* uib_base = (const char*)(dynlds + 8192) + (size_t)obase * 16;  // +kf*1024 imm
  const char* o0_base  = (const char*)dynlds + 147456 + (size_t)tid * 16;

  // precomputed LDS byte offsets; h buffer selected by XOR 8192
  int afo[8];
  #pragma unroll
  for (int kf = 0; kf < 8; ++kf) {
    int cc = kf * 4 + q;
    int cs = (cc & 16) | ((cc ^ c15) & 15);
    afo[kf] = (c15 * 32 + cs) * 16;
  }
  const int colv = w * 16 + c15;
  int hwo[4];
  #pragma unroll
  for (int r = 0; r < 4; ++r) {
    int row = q * 4 + r;
    int cch = colv >> 3;
    int cs = (cch & 16) | ((cch ^ row) & 15);
    hwo[r] = ((row * 32 + cs) * 8 + (colv & 7)) * 2;
  }

  float cst[4] = {0.f, 0.f, 0.f, 0.f};
  __syncthreads();

  const int rowbase = bt * 16;
  const size_t hlast_base = (size_t)T_STEPS * BATCH * (2 * HID) + (size_t)d * BATCH * HID;
  const int t_first = d ? (T_STEPS - 1) : 0;

  // xw walking pointer; prefetch step 0
  const long xw_stride = d ? -(long)(4 * 16384) : (long)(4 * 16384);
  const u16* xwp = xw + (((size_t)d * T_STEPS + t_first) * 4 + bt) * 16384 + (size_t)tid * 16;
  union I4x2 { int4 v[2]; u16 s[16]; };
  I4x2 xn;
  xn.v[0] = ((const int4*)xwp)[0];
  xn.v[1] = ((const int4*)xwp)[1];
  xwp += xw_stride;

  // o-gate rolling L2 stream for kf>=1 (kf=0 comes from LDS)
  int4 ofr[3];
  ofr[1] = Uo4[obase + 64];

  // out walking pointer
  float* outp = out + (size_t)(t_first * BATCH + rowbase + q * 4) * (2 * HID)
              + (size_t)d * HID + colv;
  const long out_stride = d ? -(long)(BATCH * 2 * HID) : (long)(BATCH * 2 * HID);

  int curoff = 0;
  for (int it = 0; it < T_STEPS; ++it) {
    // seed accumulators with current step's pre-activations
    f32x4 acc0 = { b2f(xn.s[0]),  b2f(xn.s[1]),  b2f(xn.s[2]),  b2f(xn.s[3])  };
    f32x4 acc1 = { b2f(xn.s[4]),  b2f(xn.s[5]),  b2f(xn.s[6]),  b2f(xn.s[7])  };
    f32x4 acc2 = { b2f(xn.s[8]),  b2f(xn.s[9]),  b2f(xn.s[10]), b2f(xn.s[11]) };
    f32x4 acc3 = { b2f(xn.s[12]), b2f(xn.s[13]), b2f(xn.s[14]), b2f(xn.s[15]) };

    // prefetch next step's xw (hidden under this step's MFMA+gates)
    if (it + 1 < T_STEPS) {
      xn.v[0] = ((const int4*)xwp)[0];
      xn.v[1] = ((const int4*)xwp)[1];
      xwp += xw_stride;
    }

    const char* hcb = (const char*)dynlds + curoff;
    bf16x8 afb[2], uib[2], oc0;
    afb[0] = *(const bf16x8*)(hcb + afo[0]);
    uib[0] = *(const bf16x8*)(uib_base);
    oc0    = *(const bf16x8*)(o0_base);
    #pragma unroll
    for (int kf = 0; kf < 8; ++kf) {
      if (kf < 7) {
        afb[(kf + 1) & 1] = *(const bf16x8*)(hcb + afo[kf + 1]);
        uib[(kf + 1) & 1] = *(const bf16x8*)(uib_base + (kf + 1) * 1024);
      }
      if (kf < 6) ofr[(kf + 2) % 3] = Uo4[obase + ((kf + 2) << 6)];
      bf16x8 af = afb[kf & 1];
      bf16x8 ob;
      if (kf == 0) {
        ob = oc0;
      } else {
        union { int4 v; bf16x8 b; } oc; oc.v = ofr[kf % 3];
        ob = oc.b;
      }
      acc0 = __builtin_amdgcn_mfma_f32_16x16x32_bf16(af, uf0[kf],     acc0, 0, 0, 0);
      acc1 = __builtin_amdgcn_mfma_f32_16x16x32_bf16(af, uf1[kf],     acc1, 0, 0, 0);
      acc2 = __builtin_amdgcn_mfma_f32_16x16x32_bf16(af, uib[kf & 1], acc2, 0, 0, 0);
      acc3 = __builtin_amdgcn_mfma_f32_16x16x32_bf16(af, ob,          acc3, 0, 0, 0);
    }
    // refill o-stream kf=1 slot for NEXT step (kf=0 now served from LDS)
    ofr[1] = Uo4[obase + 64];

    u16 hb[4]; float hv[4];
    #pragma unroll
    for (int r = 0; r < 4; ++r) {
      float fg = sigm(acc0[r]);
      float gg = tanh_f(acc1[r]);
      float ig = sigm(acc2[r]);
      float og = sigm(acc3[r]);
      float cn = cst[r] * fg + gg * ig;
      cst[r] = cn;
      hv[r] = og * tanh_f(cn);
      hb[r] = f2b(hv[r]);
    }

    const int nxtoff = curoff ^ 8192;
    char* hwp = (char*)dynlds + nxtoff;
    #pragma unroll
    for (int r = 0; r < 4; ++r) {
      *(u16*)(hwp + hwo[r]) = hb[r];
      outp[r * (2 * HID)] = hv[r];          // imm offsets 0/2048/4096/6144 B
    }
    outp += out_stride;
    if (it == T_STEPS - 1) {
      #pragma unroll
      for (int r = 0; r < 4; ++r)
        out[hlast_base + (size_t)(rowbase + q * 4 + r) * HID + colv] = hv[r];
    }
    curoff = nxtoff;
    __syncthreads();
  }
}

// ---------------------------------------------------------------------------
// Phase 2 (safe fallback if ws too small for UT): correct but slow.
// ---------------------------------------------------------------------------
__global__ __launch_bounds__(1024) void lstm_scan_safe(
    const u16* __restrict__ xw,
    const float* __restrict__ U0, const float* __restrict__ U1,
    float* __restrict__ out)
{
  const int d  = blockIdx.x >> 2;
  const int bt = blockIdx.x & 3;
  const int tid  = threadIdx.x;
  const int w    = tid >> 6;
  const int lane = tid & 63;
  const int q    = lane >> 4;
  const int c15  = lane & 15;
  const float* __restrict__ U = d ? U1 : U0;

  bf16x8 uf[4][8];
  #pragma unroll
  for (int g = 0; g < 4; ++g) {
    const int col2 = g * 256 + w * 16 + c15;
    #pragma unroll
    for (int kf = 0; kf < 8; ++kf) {
      #pragma unroll
      for (int j = 0; j < 8; ++j)
        uf[g][kf][j] = (short)f2b(U[(size_t)(kf * 32 + q * 8 + j) * G4 + col2]);
    }
  }

  __shared__ __align__(16) u16 hbuf[2][16 * 256];
  for (int i = tid; i < 16 * 256; i += 1024) { hbuf[0][i] = 0; hbuf[1][i] = 0; }
  float cst[4] = {0.f, 0.f, 0.f, 0.f};
  __syncthreads();

  const int rowbase = bt * 16;
  const int col = w * 16 + c15;
  const size_t hlast_base = (size_t)T_STEPS * BATCH * (2 * HID) + (size_t)d * BATCH * HID;

  for (int it = 0; it < T_STEPS; ++it) {
    const int t = d ? (T_STEPS - 1 - it) : it;
    union { int4 v[2]; u16 s[16]; } xv;
    {
      const int4* xwt = (const int4*)(xw + ((((size_t)d * T_STEPS + t) * 4 + bt) * 1024 + tid) * 16);
      xv.v[0] = xwt[0]; xv.v[1] = xwt[1];
    }
    const int cur = it & 1;
    bf16x8 af[8];
    #pragma unroll
    for (int kf = 0; kf < 8; ++kf) {
      int cc = kf * 4 + q;
      int cs = (cc & 16) | ((cc ^ c15) & 15);
      af[kf] = ((const bf16x8*)hbuf[cur])[c15 * 32 + cs];
    }
    f32x4 acc[4];
    #pragma unroll
    for (int g = 0; g < 4; ++g) acc[g] = (f32x4){0.f, 0.f, 0.f, 0.f};
    #pragma unroll
    for (int kf = 0; kf < 8; ++kf)
      #pragma unroll
      for (int g = 0; g < 4; ++g)
        acc[g] = __builtin_amdgcn_mfma_f32_16x16x32_bf16(af[kf], uf[g][kf], acc[g], 0, 0, 0);

    u16 hb[4]; float hv[4];
    #pragma unroll
    for (int r = 0; r < 4; ++r) {
      float zf = acc[0][r] + b2f(xv.s[0 * 4 + r]);
      float zg = acc[1][r] + b2f(xv.s[1 * 4 + r]);
      float zi = acc[2][r] + b2f(xv.s[2 * 4 + r]);
      float zo = acc[3][r] + b2f(xv.s[3 * 4 + r]);
      float fg = sigm(zf), gg = tanh_f(zg), ig = sigm(zi), og = sigm(zo);
      float cn = cst[r] * fg + gg * ig;
      cst[r] = cn;
      hv[r] = og * tanh_f(cn);
      hb[r] = f2b(hv[r]);
    }
    const int nxt = cur ^ 1;
    #pragma unroll
    for (int r = 0; r < 4; ++r) {
      const int row = q * 4 + r;
      int cch = col >> 3;
      int cs = (cch & 16) | ((cch ^ row) & 15);
      hbuf[nxt][(row * 32 + cs) * 8 + (col & 7)] = hb[r];
      out[((size_t)t * BATCH + rowbase + row) * (2 * HID) + (size_t)d * HID + col] = hv[r];
    }
    if (it == T_STEPS - 1) {
      #pragma unroll
      for (int r = 0; r < 4; ++r)
        out[hlast_base + (size_t)(rowbase + q * 4 + r) * HID + col] = hv[r];
    }
    __syncthreads();
  }
}

extern "C" void kernel_launch(void* const* d_in, const int* in_sizes, int n_in,
                              void* d_out, int out_size, void* d_ws, size_t ws_size,
                              hipStream_t stream) {
  const float* x  = (const float*)d_in[0];
  const float* fW = (const float*)d_in[1];
  const float* fU = (const float*)d_in[2];
  const float* fb = (const float*)d_in[3];
  const float* bW = (const float*)d_in[4];
  const float* bU = (const float*)d_in[5];
  const float* bb = (const float*)d_in[6];
  u16*   xwbuf = (u16*)d_ws;
  u16*   UT    = (u16*)d_ws + XW_ELEMS;
  u16*   XBF   = (u16*)d_ws + XW_ELEMS + UT_ELEMS;
  float* out   = (float*)d_out;

  const bool fast   = ws_size >= (XW_ELEMS + UT_ELEMS) * sizeof(u16);
  const bool use_v5 = ws_size >= (XW_ELEMS + UT_ELEMS + XBF_ELEMS) * sizeof(u16);

  if (use_v5) {
    x_to_frag<<<1024, 256, 0, stream>>>(x, XBF);
    xw_gemm_v5<<<512, 256, 0, stream>>>(XBF, fW, bW, fb, bb, xwbuf);
  } else {
    dim3 g1(32, 32);
    xw_gemm<<<g1, 256, 0, stream>>>(x, fW, bW, fb, bb, xwbuf);
  }
  if (fast) {
    build_ut<<<8, 1024, 0, stream>>>(fU, bU, UT);
    hipFuncSetAttribute((const void*)lstm_scan_fast,
                        hipFuncAttributeMaxDynamicSharedMemorySize, 163840);
    lstm_scan_fast<<<8, 1024, 163840, stream>>>(xwbuf, UT, out);
  } else {
    lstm_scan_safe<<<8, 1024, 0, stream>>>(xwbuf, fU, bU, out);
  }
}